// Round 5
// baseline (290.236 us; speedup 1.0000x reference)
//
#include <hip/hip_runtime.h>
#include <math.h>

#define B_ 2
#define T_ 2
#define H_ 28
#define W_ 28
#define S_ (H_*W_)      /* 784  */
#define L_ (T_*S_)      /* 1568 */
#define C_ 768
#define NH_ 12
#define HD_ 64
#define LN_EPS 1e-5f
#define LOG2E 1.4426950408889634f
#define SCALE_K (0.125f * LOG2E)   /* hd^-0.5 * log2e folded into K' */
#define DP_ 176                     /* augmented head dim: 64 + 2*2*28 */

typedef unsigned int uint_;
typedef unsigned int u32x4 __attribute__((ext_vector_type(4)));
typedef __bf16 bf16x8 __attribute__((ext_vector_type(8)));
typedef float f32x4 __attribute__((ext_vector_type(4)));
typedef float f32x16 __attribute__((ext_vector_type(16)));

#define BC8(x) __builtin_bit_cast(bf16x8, (x))

__device__ __forceinline__ unsigned short f2bf(float f) {
  uint_ u = __builtin_bit_cast(uint_, f);
  u += 0x7FFFu + ((u >> 16) & 1u);
  return (unsigned short)(u >> 16);
}
__device__ __forceinline__ float bf2f(unsigned short h) {
  return __builtin_bit_cast(float, ((uint_)h) << 16);
}
__device__ __forceinline__ float bflo(uint_ u) {
  return __builtin_bit_cast(float, u << 16);
}
__device__ __forceinline__ float bfhi(uint_ u) {
  return __builtin_bit_cast(float, u & 0xFFFF0000u);
}
__device__ __forceinline__ uint_ cvtpk(float a, float b) {
  uint_ r;
  asm("v_cvt_pk_bf16_f32 %0, %1, %2" : "=v"(r) : "v"(a), "v"(b));
  return r;
}
__device__ __forceinline__ void gload16(const void* g, void* l) {
  __builtin_amdgcn_global_load_lds(
      (const __attribute__((address_space(1))) unsigned int*)g,
      (__attribute__((address_space(3))) unsigned int*)l, 16, 0, 0);
}

// ---------------------------------------------------------------------------
// f32 -> bf16 convert, zero-pad tail
// ---------------------------------------------------------------------------
__global__ __launch_bounds__(256) void cvt_bf16(
    const float* __restrict__ src, unsigned short* __restrict__ dst,
    int n_src, int n_total) {
  const int i = (blockIdx.x * 256 + threadIdx.x) * 8;
  if (i >= n_total) return;
  u32x4 o;
  if (i < n_src) {
    float4 a = *(const float4*)(src + i);
    float4 b = *(const float4*)(src + i + 4);
    o.x = cvtpk(a.x, a.y); o.y = cvtpk(a.z, a.w);
    o.z = cvtpk(b.x, b.y); o.w = cvtpk(b.z, b.w);
  } else {
    o.x = 0; o.y = 0; o.z = 0; o.w = 0;
  }
  *(u32x4*)(dst + i) = o;
}

// ---------------------------------------------------------------------------
// Static one-hot table for K' dims 64..175: OH[kr][112], 1.0 at t*56+x, t*56+28+y
// ---------------------------------------------------------------------------
__global__ __launch_bounds__(256) void build_onehot(unsigned short* __restrict__ OH) {
  const int e = blockIdx.x * 256 + threadIdx.x;
  if (e >= L_ * 112) return;
  const int col = e % 112, kr = e / 112;
  const int t = (kr >= S_) ? 1 : 0;
  const int sk = kr - t * S_;
  const int x = sk / W_, y = sk % W_;
  unsigned short v = 0;
  if (col == t * 56 + x || col == t * 56 + 28 + y) v = 0x3F80;
  OH[e] = v;
}

// ---------------------------------------------------------------------------
// bf16 MFMA GEMM core: C = A * B^T, 128x128 tile, BK=32, 4 waves
// ---------------------------------------------------------------------------
__device__ __forceinline__ void gemm_core(
    const unsigned short* __restrict__ A, const unsigned short* __restrict__ Bm,
    int K, int m0, int n0, f32x4 (&acc)[4][4]) {
  __shared__ __align__(16) unsigned short As[128 * 32];
  __shared__ __align__(16) unsigned short Bs[128 * 32];
  const int tid = threadIdx.x;
  const int lane = tid & 63;
  const int wv = tid >> 6;
  const int wm = wv >> 1, wn = wv & 1;
  const int srow = tid >> 2, scol = (tid & 3) * 8;
  const int fr = lane & 15, fk = (lane >> 4) * 8;
  const unsigned short* ag = A + (size_t)(m0 + srow) * K + scol;
  const unsigned short* bg = Bm + (size_t)(n0 + srow) * K + scol;
  unsigned short* asd = As + tid * 8;
  unsigned short* bsd = Bs + tid * 8;
  const int arow = wm * 64 + fr;
  const int brow = wn * 64 + fr;
  for (int k0 = 0; k0 < K; k0 += 32) {
    __syncthreads();
    gload16(ag + k0, asd);
    gload16(ag + (size_t)64 * K + k0, asd + 2048);
    gload16(bg + k0, bsd);
    gload16(bg + (size_t)64 * K + k0, bsd + 2048);
    __syncthreads();
    bf16x8 af[4], bfr[4];
    #pragma unroll
    for (int m = 0; m < 4; ++m)
      af[m] = *(const bf16x8*)(As + (arow + m * 16) * 32 + fk);
    #pragma unroll
    for (int n = 0; n < 4; ++n)
      bfr[n] = *(const bf16x8*)(Bs + (brow + n * 16) * 32 + fk);
    #pragma unroll
    for (int m = 0; m < 4; ++m)
      #pragma unroll
      for (int n = 0; n < 4; ++n)
        acc[m][n] = __builtin_amdgcn_mfma_f32_16x16x32_bf16(af[m], bfr[n], acc[m][n], 0, 0, 0);
  }
}

// ---------------------------------------------------------------------------
// QKV GEMM: Xbf[3200][768] * Wbf[2304][768]^T -> scatter f32 q/k/v [B,NH,L,HD]
// ---------------------------------------------------------------------------
__global__ __launch_bounds__(256) void qkv_gemm_mfma(
    const unsigned short* __restrict__ Xbf, const unsigned short* __restrict__ Wbf,
    float* __restrict__ q_raw, float* __restrict__ k_raw, float* __restrict__ v_raw) {
  f32x4 acc[4][4] = {};
  const int m0 = blockIdx.y * 128;
  const int n0 = blockIdx.x * 128;
  gemm_core(Xbf, Wbf, C_, m0, n0, acc);
  const int lane = threadIdx.x & 63;
  const int wv = threadIdx.x >> 6;
  const int wm = wv >> 1, wn = wv & 1;
  const int fr = lane & 15, fj = (lane >> 4) * 4;
  #pragma unroll
  for (int n = 0; n < 4; ++n) {
    const int gn = n0 + wn * 64 + n * 16 + fr;
    const int which = (gn >= 2 * C_) ? 2 : ((gn >= C_) ? 1 : 0);
    const int rem = gn - which * C_;
    const int h = rem >> 6, d = rem & 63;
    float* dst = (which == 0) ? q_raw : ((which == 1) ? k_raw : v_raw);
    #pragma unroll
    for (int m = 0; m < 4; ++m) {
      #pragma unroll
      for (int j = 0; j < 4; ++j) {
        const int gm = m0 + wm * 64 + m * 16 + fj + j;
        if (gm < B_ * L_) {
          const int b = (gm >= L_) ? 1 : 0;
          const int l = gm - b * L_;
          dst[(((size_t)b * NH_ + h) * L_ + l) * HD_ + d] = acc[m][n][j];
        }
      }
    }
  }
}

// ---------------------------------------------------------------------------
// Proj GEMM: Abf[3200][768] * Wobf[768][768]^T + bo -> d_out f32
// ---------------------------------------------------------------------------
__global__ __launch_bounds__(256) void proj_gemm_mfma(
    const unsigned short* __restrict__ Abf, const unsigned short* __restrict__ Wobf,
    const float* __restrict__ bo, float* __restrict__ out) {
  f32x4 acc[4][4] = {};
  const int m0 = blockIdx.y * 128;
  const int n0 = blockIdx.x * 128;
  gemm_core(Abf, Wobf, C_, m0, n0, acc);
  const int lane = threadIdx.x & 63;
  const int wv = threadIdx.x >> 6;
  const int wm = wv >> 1, wn = wv & 1;
  const int fr = lane & 15, fj = (lane >> 4) * 4;
  #pragma unroll
  for (int n = 0; n < 4; ++n) {
    const int gn = n0 + wn * 64 + n * 16 + fr;
    const float bias = bo[gn];
    #pragma unroll
    for (int m = 0; m < 4; ++m) {
      #pragma unroll
      for (int j = 0; j < 4; ++j) {
        const int gm = m0 + wm * 64 + m * 16 + fj + j;
        if (gm < B_ * L_) out[(size_t)gm * C_ + gn] = acc[m][n][j] + bias;
      }
    }
  }
}

// ---------------------------------------------------------------------------
// Fused depthwise 3x3 conv + LayerNorm(64) for q/k/v (blockIdx.y selects)
// ---------------------------------------------------------------------------
__global__ __launch_bounds__(256) void pool_ln_fused(
    const float* __restrict__ q_raw, const float* __restrict__ k_raw,
    const float* __restrict__ v_raw,
    const float* __restrict__ qw, const float* __restrict__ kw,
    const float* __restrict__ vw,
    const float* __restrict__ qg, const float* __restrict__ qb2,
    const float* __restrict__ kg, const float* __restrict__ kb2,
    const float* __restrict__ vg, const float* __restrict__ vb2,
    unsigned short* __restrict__ Qp2, unsigned short* __restrict__ Kp2a,
    unsigned short* __restrict__ Vtmp) {
  const int which = blockIdx.y;
  const float* in = (which == 0) ? q_raw : (which == 1) ? k_raw : v_raw;
  const float* w  = (which == 0) ? qw : (which == 1) ? kw : vw;
  const float* g  = (which == 0) ? qg : (which == 1) ? kg : vg;
  const float* bb = (which == 0) ? qb2 : (which == 1) ? kb2 : vb2;
  unsigned short* out = (which == 0) ? Qp2 : (which == 1) ? Kp2a : Vtmp;
  const int stride = (which == 0) ? DP_ : 64;
  const float scale = (which == 1) ? SCALE_K : 1.f;

  const int row = blockIdx.x * 4 + (threadIdx.x >> 6);
  const int d = threadIdx.x & 63;
  const int bh = row / L_;
  const int l  = row % L_;
  const int t  = l / S_;
  const int sq = l % S_;
  const int x = sq / W_, y = sq % W_;
  const float* base = in + ((size_t)bh * L_ + t * S_) * HD_;
  float acc = 0.f;
  #pragma unroll
  for (int dx = 0; dx < 3; ++dx) {
    const int xx = x + dx - 1;
    if (xx < 0 || xx >= H_) continue;
    #pragma unroll
    for (int dy = 0; dy < 3; ++dy) {
      const int yy = y + dy - 1;
      if (yy < 0 || yy >= W_) continue;
      acc += base[(size_t)(xx * W_ + yy) * HD_ + d] * w[(dx * 3 + dy) * HD_ + d];
    }
  }
  float s = acc;
  #pragma unroll
  for (int off = 32; off; off >>= 1) s += __shfl_xor(s, off);
  const float mu = s * (1.f / 64.f);
  const float dv = acc - mu;
  float s2 = dv * dv;
  #pragma unroll
  for (int off = 32; off; off >>= 1) s2 += __shfl_xor(s2, off);
  const float var = s2 * (1.f / 64.f);
  const float val = dv * rsqrtf(var + LN_EPS) * g[d] + bb[d];
  out[(size_t)row * stride + d] = f2bf(val * scale);
}

// ---------------------------------------------------------------------------
// Transpose V per head: Vtmp [bh][L][64] bf16 -> VpT [bh][64][L] bf16
// ---------------------------------------------------------------------------
__global__ __launch_bounds__(256) void transpose_v(
    const unsigned short* __restrict__ Vtmp, unsigned short* __restrict__ VpT) {
  __shared__ unsigned short tile[32][72];
  const int bh = blockIdx.y;
  const int l0 = blockIdx.x * 32;
  const int t = threadIdx.x;
  {
    const int r = t >> 3, c8 = (t & 7) * 8;
    u32x4 v = *(const u32x4*)(Vtmp + ((size_t)bh * L_ + l0 + r) * 64 + c8);
    *(u32x4*)&tile[r][c8] = v;
  }
  __syncthreads();
  const int d = t >> 2, gq = t & 3;
  unsigned short o[8];
  #pragma unroll
  for (int i = 0; i < 8; ++i) o[i] = tile[gq*8 + i][d];
  u32x4 ov;
  ov.x = (uint_)o[0] | ((uint_)o[1] << 16);
  ov.y = (uint_)o[2] | ((uint_)o[3] << 16);
  ov.z = (uint_)o[4] | ((uint_)o[5] << 16);
  ov.w = (uint_)o[6] | ((uint_)o[7] << 16);
  *(u32x4*)(VpT + ((size_t)bh * 64 + d) * L_ + l0 + gq*8) = ov;
}

// ---------------------------------------------------------------------------
// rel-pos rows -> Qp2 dims 64..175 (log2e-scaled; other T-block zeroed)
// ---------------------------------------------------------------------------
__global__ void relpos_fused(
    const unsigned short* __restrict__ Qp2r, const float* __restrict__ rph,
    const float* __restrict__ rpw, unsigned short* __restrict__ Qp2) {
  const int idx = blockIdx.x * blockDim.x + threadIdx.x;
  const int k = idx % H_;
  const int rest = idx / H_;            // bh*L + t*S + sq
  const int sq = rest % S_;
  const int t = (rest % L_) / S_;
  const int x = sq / W_, y = sq % W_;
  const unsigned short* qrow = Qp2r + (size_t)rest * DP_;
  const float* rh = rph + (x - k + H_ - 1) * HD_;
  const float* rw = rpw + (y - k + W_ - 1) * HD_;
  float ah = 0.f, aw = 0.f;
  #pragma unroll
  for (int c = 0; c < HD_; c += 8) {
    u32x4 qv = *(const u32x4*)(qrow + c);
    float4 h0 = *(const float4*)(rh + c);
    float4 h1 = *(const float4*)(rh + c + 4);
    float4 w0 = *(const float4*)(rw + c);
    float4 w1 = *(const float4*)(rw + c + 4);
    const float q0 = bflo(qv.x), q1 = bfhi(qv.x), q2 = bflo(qv.y), q3 = bfhi(qv.y);
    const float q4 = bflo(qv.z), q5 = bfhi(qv.z), q6 = bflo(qv.w), q7 = bfhi(qv.w);
    ah += q0*h0.x + q1*h0.y + q2*h0.z + q3*h0.w + q4*h1.x + q5*h1.y + q6*h1.z + q7*h1.w;
    aw += q0*w0.x + q1*w0.y + q2*w0.z + q3*w0.w + q4*w1.x + q5*w1.y + q6*w1.z + q7*w1.w;
  }
  unsigned short* qd = Qp2 + (size_t)rest * DP_;
  qd[64 + t*56 + k]        = f2bf(ah * LOG2E);
  qd[64 + t*56 + 28 + k]   = f2bf(aw * LOG2E);
  qd[64 + (1-t)*56 + k]      = 0;
  qd[64 + (1-t)*56 + 28 + k] = 0;
}

// ---------------------------------------------------------------------------
// MFMA flash attention. 256 thr (4 waves), grid 1176 (XCD-swizzled).
// Stride-4 KV-tile interleave across waves; one-hot K' frags from table;
// bias MFMAs skipped for cross-temporal tiles.
// ---------------------------------------------------------------------------
__device__ __forceinline__ void load_tile(
    const unsigned short* kbase, const unsigned short* vbase0, int kt,
    u32x4& k0, u32x4& k1, u32x4& k2, u32x4& k3,
    u32x4& va, u32x4& vb, u32x4& vc, u32x4& vd) {
  const unsigned short* kr = kbase + (size_t)kt * 2048;
  k0 = *(const u32x4*)(kr);
  k1 = *(const u32x4*)(kr + 16);
  k2 = *(const u32x4*)(kr + 32);
  k3 = *(const u32x4*)(kr + 48);
  const unsigned short* vr = vbase0 + kt * 32;
  va = *(const u32x4*)(vr);
  vb = *(const u32x4*)(vr + 16);
  vc = *(const u32x4*)(vr + 32 * L_);
  vd = *(const u32x4*)(vr + 32 * L_ + 16);
}

template<bool BIAS>
__device__ __forceinline__ void proc_tile(
    int kt, int lo, int hi, const u32x4 (&qf)[11],
    const unsigned short* __restrict__ OH,
    u32x4 k0, u32x4 k1, u32x4 k2, u32x4 k3,
    u32x4 va, u32x4 vb, u32x4 vc, u32x4 vd,
    f32x16& acc0, f32x16& acc1, float& m_run, float& l_run) {
  u32x4 oh0, oh1, oh2, oh3, oh4, oh5, oh6;
  if (BIAS) {
    const unsigned short* op = OH + (size_t)(kt * 32 + lo) * 112 + hi * 8;
    oh0 = *(const u32x4*)(op);
    oh1 = *(const u32x4*)(op + 16);
    oh2 = *(const u32x4*)(op + 32);
    oh3 = *(const u32x4*)(op + 48);
    oh4 = *(const u32x4*)(op + 64);
    oh5 = *(const u32x4*)(op + 80);
    oh6 = *(const u32x4*)(op + 96);
  }

  f32x16 s = {};
  s = __builtin_amdgcn_mfma_f32_32x32x16_bf16(BC8(k0), BC8(qf[0]), s, 0, 0, 0);
  s = __builtin_amdgcn_mfma_f32_32x32x16_bf16(BC8(k1), BC8(qf[1]), s, 0, 0, 0);
  s = __builtin_amdgcn_mfma_f32_32x32x16_bf16(BC8(k2), BC8(qf[2]), s, 0, 0, 0);
  s = __builtin_amdgcn_mfma_f32_32x32x16_bf16(BC8(k3), BC8(qf[3]), s, 0, 0, 0);
  if (BIAS) {
    s = __builtin_amdgcn_mfma_f32_32x32x16_bf16(BC8(oh0), BC8(qf[4]), s, 0, 0, 0);
    s = __builtin_amdgcn_mfma_f32_32x32x16_bf16(BC8(oh1), BC8(qf[5]), s, 0, 0, 0);
    s = __builtin_amdgcn_mfma_f32_32x32x16_bf16(BC8(oh2), BC8(qf[6]), s, 0, 0, 0);
    s = __builtin_amdgcn_mfma_f32_32x32x16_bf16(BC8(oh3), BC8(qf[7]), s, 0, 0, 0);
    s = __builtin_amdgcn_mfma_f32_32x32x16_bf16(BC8(oh4), BC8(qf[8]), s, 0, 0, 0);
    s = __builtin_amdgcn_mfma_f32_32x32x16_bf16(BC8(oh5), BC8(qf[9]), s, 0, 0, 0);
    s = __builtin_amdgcn_mfma_f32_32x32x16_bf16(BC8(oh6), BC8(qf[10]), s, 0, 0, 0);
  }

  // pairwise max tree (max3-friendly)
  float m01 = fmaxf(s[0], s[1]),  m23 = fmaxf(s[2], s[3]);
  float m45 = fmaxf(s[4], s[5]),  m67 = fmaxf(s[6], s[7]);
  float m89 = fmaxf(s[8], s[9]),  mab = fmaxf(s[10], s[11]);
  float mcd = fmaxf(s[12], s[13]), mef = fmaxf(s[14], s[15]);
  float pmax = fmaxf(fmaxf(fmaxf(m01, m23), fmaxf(m45, m67)),
                     fmaxf(fmaxf(m89, mab), fmaxf(mcd, mef)));
  pmax = fmaxf(pmax, __shfl_xor(pmax, 32));
  if (__any(pmax > m_run + 8.f)) {
    const float mn = fmaxf(m_run, pmax);
    const float f = exp2f(m_run - mn);
    m_run = mn; l_run *= f;
    #pragma unroll
    for (int r = 0; r < 16; ++r) {
      const float fr = __shfl(f, (r & 3) + 8*(r >> 2) + 4*hi);
      acc0[r] *= fr; acc1[r] *= fr;
    }
  }
  float ps = 0.f;
  uint_ pw0, pw1, pw2, pw3, pw4, pw5, pw6, pw7;
  {
    float a, b;
    a = exp2f(s[0]-m_run);  b = exp2f(s[1]-m_run);  ps += a+b; pw0 = cvtpk(a,b);
    a = exp2f(s[2]-m_run);  b = exp2f(s[3]-m_run);  ps += a+b; pw1 = cvtpk(a,b);
    a = exp2f(s[4]-m_run);  b = exp2f(s[5]-m_run);  ps += a+b; pw2 = cvtpk(a,b);
    a = exp2f(s[6]-m_run);  b = exp2f(s[7]-m_run);  ps += a+b; pw3 = cvtpk(a,b);
    a = exp2f(s[8]-m_run);  b = exp2f(s[9]-m_run);  ps += a+b; pw4 = cvtpk(a,b);
    a = exp2f(s[10]-m_run); b = exp2f(s[11]-m_run); ps += a+b; pw5 = cvtpk(a,b);
    a = exp2f(s[12]-m_run); b = exp2f(s[13]-m_run); ps += a+b; pw6 = cvtpk(a,b);
    a = exp2f(s[14]-m_run); b = exp2f(s[15]-m_run); ps += a+b; pw7 = cvtpk(a,b);
  }
  ps += __shfl_xor(ps, 32);
  l_run += ps;

  auto sA = __builtin_amdgcn_permlane32_swap(pw0, pw2, false, false);
  auto sB = __builtin_amdgcn_permlane32_swap(pw1, pw3, false, false);
  auto sC = __builtin_amdgcn_permlane32_swap(pw4, pw6, false, false);
  auto sD = __builtin_amdgcn_permlane32_swap(pw5, pw7, false, false);
  u32x4 pa0, pa1;
  pa0.x = sA[0]; pa0.y = sB[0]; pa0.z = sA[1]; pa0.w = sB[1];
  pa1.x = sC[0]; pa1.y = sD[0]; pa1.z = sC[1]; pa1.w = sD[1];

  acc0 = __builtin_amdgcn_mfma_f32_32x32x16_bf16(BC8(pa0), BC8(va), acc0, 0, 0, 0);
  acc0 = __builtin_amdgcn_mfma_f32_32x32x16_bf16(BC8(pa1), BC8(vb), acc0, 0, 0, 0);
  acc1 = __builtin_amdgcn_mfma_f32_32x32x16_bf16(BC8(pa0), BC8(vc), acc1, 0, 0, 0);
  acc1 = __builtin_amdgcn_mfma_f32_32x32x16_bf16(BC8(pa1), BC8(vd), acc1, 0, 0, 0);
}

__device__ __forceinline__ bool bias_needed(int kt, int qt) {
  const int kmin = (kt * 32 >= S_) ? 1 : 0;
  const int kmax = (kt * 32 + 31 >= S_) ? 1 : 0;
  const int qmin = (qt * 32 >= S_) ? 1 : 0;
  const int qmax = (qt * 32 + 31 >= S_) ? 1 : 0;
  return (kmin <= qmax) && (qmin <= kmax);
}

__global__ __launch_bounds__(256) void attn_mfma(
    const unsigned short* __restrict__ Qp2, const unsigned short* __restrict__ Kp2a,
    const unsigned short* __restrict__ VpT, const unsigned short* __restrict__ OH,
    unsigned short* __restrict__ Abf) {
  __shared__ float red_acc[3][32][64];
  __shared__ float red_ml[4][2][32];

  const int id0 = blockIdx.x;                  // 1176 = 8 * 147
  const int swz = (id0 & 7) * 147 + (id0 >> 3);
  const int qt = swz % 49;
  const int bh = swz / 49;

  const int lane = threadIdx.x & 63;
  const int wv = threadIdx.x >> 6;             // 0..3
  const int lo = lane & 31, hi = lane >> 5;
  const int q0 = qt * 32;

  u32x4 qf[11];
  {
    const unsigned short* qrow = Qp2 + ((size_t)bh * L_ + q0 + lo) * DP_ + hi * 8;
    #pragma unroll
    for (int c = 0; c < 11; ++c) qf[c] = *(const u32x4*)(qrow + c * 16);
  }

  const unsigned short* kbase = Kp2a + ((size_t)bh * L_ + lo) * 64 + hi * 8;
  const unsigned short* vbase0 = VpT + (size_t)bh * 64 * L_ + (size_t)lo * L_ + hi * 8;

  f32x16 acc0 = {}, acc1 = {};
  float m_run = -1e30f, l_run = 0.f;
  const int nt = (49 - wv + 3) >> 2;           // wave wv handles kt = wv + 4*i

  u32x4 ck0, ck1, ck2, ck3, cva, cvb, cvc, cvd;
  u32x4 nk0, nk1, nk2, nk3, nva, nvb, nvc, nvd;
  load_tile(kbase, vbase0, wv, ck0, ck1, ck2, ck3, cva, cvb, cvc, cvd);
  int i = 0;
  for (; i + 2 <= nt; i += 2) {
    const int ktA = wv + 4 * i, ktB = ktA + 4;
    load_tile(kbase, vbase0, ktB, nk0, nk1, nk2, nk3, nva, nvb, nvc, nvd);
    if (bias_needed(ktA, qt))
      proc_tile<true>(ktA, lo, hi, qf, OH, ck0, ck1, ck2, ck3, cva, cvb, cvc, cvd, acc0, acc1, m_run, l_run);
    else
      proc_tile<false>(ktA, lo, hi, qf, OH, ck0, ck1, ck2, ck3, cva, cvb, cvc, cvd, acc0, acc1, m_run, l_run);
    const int ktC = wv + 4 * ((i + 2 < nt) ? i + 2 : nt - 1);
    load_tile(kbase, vbase0, ktC, ck0, ck1, ck2, ck3, cva, cvb, cvc, cvd);
    if (bias_needed(ktB, qt))
      proc_tile<true>(ktB, lo, hi, qf, OH, nk0, nk1, nk2, nk3, nva, nvb, nvc, nvd, acc0, acc1, m_run, l_run);
    else
      proc_tile<false>(ktB, lo, hi, qf, OH, nk0, nk1, nk2, nk3, nva, nvb, nvc, nvd, acc0, acc1, m_run, l_run);
  }
  if (i < nt) {
    const int ktA = wv + 4 * i;
    if (bias_needed(ktA, qt))
      proc_tile<true>(ktA, lo, hi, qf, OH, ck0, ck1, ck2, ck3, cva, cvb, cvc, cvd, acc0, acc1, m_run, l_run);
    else
      proc_tile<false>(ktA, lo, hi, qf, OH, ck0, ck1, ck2, ck3, cva, cvb, cvc, cvd, acc0, acc1, m_run, l_run);
  }

  // merge 4 waves' partial states
  if (hi == 0) { red_ml[wv][0][lo] = m_run; red_ml[wv][1][lo] = l_run; }
  if (wv >= 1) {
    #pragma unroll
    for (int r = 0; r < 16; ++r) {
      const int row = (r & 3) + 8*(r >> 2) + 4*hi;
      red_acc[wv-1][row][lo]      = acc0[r];
      red_acc[wv-1][row][32 + lo] = acc1[r];
    }
  }
  __syncthreads();
  if (wv == 0) {
    const int b = bh / NH_, h = bh % NH_;
    #pragma unroll
    for (int r = 0; r < 16; ++r) {
      const int row = (r & 3) + 8*(r >> 2) + 4*hi;
      const float m0 = red_ml[0][0][row], l0 = red_ml[0][1][row];
      const float m1 = red_ml[1][0][row], l1 = red_ml[1][1][row];
      const float m2 = red_ml[2][0][row], l2 = red_ml[2][1][row];
      const float m3 = red_ml[3][0][row], l3 = red_ml[3][1][row];
      const float M = fmaxf(fmaxf(m0, m1), fmaxf(m2, m3));
      const float w0 = exp2f(m0 - M), w1 = exp2f(m1 - M);
      const float w2 = exp2f(m2 - M), w3 = exp2f(m3 - M);
      const float inv = 1.0f / (l0*w0 + l1*w1 + l2*w2 + l3*w3);
      const float o0 = (acc0[r]*w0 + red_acc[0][row][lo]*w1 +
                        red_acc[1][row][lo]*w2 + red_acc[2][row][lo]*w3) * inv;
      const float o1 = (acc1[r]*w0 + red_acc[0][row][32+lo]*w1 +
                        red_acc[1][row][32+lo]*w2 + red_acc[2][row][32+lo]*w3) * inv;
      const size_t qoff = ((size_t)bh * L_ + q0 + row) * DP_ + lo;
      const size_t ooff = ((size_t)(b * L_ + q0 + row)) * C_ + h * 64 + lo;
      Abf[ooff]      = f2bf(o0 + bf2f(Qp2[qoff]));
      Abf[ooff + 32] = f2bf(o1 + bf2f(Qp2[qoff + 32]));
    }
  }
}

// ---------------------------------------------------------------------------
extern "C" void kernel_launch(void* const* d_in, const int* in_sizes, int n_in,
                              void* d_out, int out_size, void* d_ws, size_t ws_size,
                              hipStream_t stream) {
  const float* x         = (const float*)d_in[0];
  const float* qkv_w     = (const float*)d_in[1];
  const float* out_w     = (const float*)d_in[2];
  const float* out_b     = (const float*)d_in[3];
  const float* q_pool_w  = (const float*)d_in[4];
  const float* k_pool_w  = (const float*)d_in[5];
  const float* v_pool_w  = (const float*)d_in[6];
  const float* q_ln_g    = (const float*)d_in[7];
  const float* q_ln_b    = (const float*)d_in[8];
  const float* k_ln_g    = (const float*)d_in[9];
  const float* k_ln_b    = (const float*)d_in[10];
  const float* v_ln_g    = (const float*)d_in[11];
  const float* v_ln_b    = (const float*)d_in[12];
  const float* rel_pos_h = (const float*)d_in[13];
  const float* rel_pos_w = (const float*)d_in[14];

  float* R = (float*)d_ws;
  const size_t NQ = (size_t)B_ * NH_ * L_ * HD_;   // 2,408,448 f32 slots
  // region map (f32 slots), no live overlaps:
  // A [0,NQ): q_raw -> Abf (1,228,800)     B [NQ,2NQ): k_raw -> VpT (1,204,224)
  // C [2NQ,3NQ): v_raw
  // D [3NQ,+3,311,616): Xbf (1,228,800) -> Qp2
  // E: Kp2a (1,204,224)                    F: Wbf (884,736) -> Vtmp (1,204,224)
  // G: Wobf (294,912)                      H: OneHot (87,808)
  float* q_raw = R;
  unsigned short* Abf = (unsigned short*)R;
  float* k_raw = R + NQ;
  unsigned short* VpT = (unsigned short*)(R + NQ);
  float* v_raw = R + 2*NQ;
  const size_t D_off = 3*NQ;
  unsigned short* Xbf = (unsigned short*)(R + D_off);
  unsigned short* Qp2 = (unsigned short*)(R + D_off);
  const size_t E_off = D_off + 3311616;
  unsigned short* Kp2a = (unsigned short*)(R + E_off);
  const size_t F_off = E_off + 1204224;
  unsigned short* Wbf  = (unsigned short*)(R + F_off);
  unsigned short* Vtmp = (unsigned short*)(R + F_off);
  const size_t G_off = F_off + 1204224;
  unsigned short* Wobf = (unsigned short*)(R + G_off);
  const size_t H_off = G_off + 294912;
  unsigned short* OH   = (unsigned short*)(R + H_off);

  build_onehot<<<686, 256, 0, stream>>>(OH);
  cvt_bf16<<<1200, 256, 0, stream>>>(x, Xbf, 3136*768, 3200*768);
  cvt_bf16<<<864, 256, 0, stream>>>(qkv_w, Wbf, 2304*768, 2304*768);
  cvt_bf16<<<288, 256, 0, stream>>>(out_w, Wobf, 768*768, 768*768);
  qkv_gemm_mfma<<<dim3(18, 25), 256, 0, stream>>>(Xbf, Wbf, q_raw, k_raw, v_raw);
  pool_ln_fused<<<dim3(9408, 3), 256, 0, stream>>>(
      q_raw, k_raw, v_raw, q_pool_w, k_pool_w, v_pool_w,
      q_ln_g, q_ln_b, k_ln_g, k_ln_b, v_ln_g, v_ln_b, Qp2, Kp2a, Vtmp);
  cvt_bf16<<<24, 256, 0, stream>>>(nullptr, Abf + 3136*768, 0, 64*768);  // pad rows
  transpose_v<<<dim3(49, 24), 256, 0, stream>>>(Vtmp, VpT);
  relpos_fused<<<4116, 256, 0, stream>>>(Qp2, rel_pos_h, rel_pos_w, Qp2);
  attn_mfma<<<1176, 256, 0, stream>>>(Qp2, Kp2a, VpT, OH, Abf);
  proj_gemm_mfma<<<dim3(6, 25), 256, 0, stream>>>(Abf, Wobf, out_b, (float*)d_out);
}

// Round 6
// 269.545 us; speedup vs baseline: 1.0768x; 1.0768x over previous
//
#include <hip/hip_runtime.h>
#include <math.h>

#define B_ 2
#define T_ 2
#define H_ 28
#define W_ 28
#define S_ (H_*W_)      /* 784  */
#define L_ (T_*S_)      /* 1568 */
#define C_ 768
#define NH_ 12
#define HD_ 64
#define LN_EPS 1e-5f
#define LOG2E 1.4426950408889634f
#define SCALE_K (0.125f * LOG2E)   /* hd^-0.5 * log2e folded into K' */
#define DP_ 176                     /* augmented head dim: 64 + 2*2*28 */

typedef unsigned int uint_;
typedef unsigned int u32x4 __attribute__((ext_vector_type(4)));
typedef __bf16 bf16x8 __attribute__((ext_vector_type(8)));
typedef float f32x4 __attribute__((ext_vector_type(4)));
typedef float f32x16 __attribute__((ext_vector_type(16)));

#define BC8(x) __builtin_bit_cast(bf16x8, (x))

__device__ __forceinline__ unsigned short f2bf(float f) {
  uint_ u = __builtin_bit_cast(uint_, f);
  u += 0x7FFFu + ((u >> 16) & 1u);
  return (unsigned short)(u >> 16);
}
__device__ __forceinline__ float bf2f(unsigned short h) {
  return __builtin_bit_cast(float, ((uint_)h) << 16);
}
__device__ __forceinline__ float bflo(uint_ u) {
  return __builtin_bit_cast(float, u << 16);
}
__device__ __forceinline__ float bfhi(uint_ u) {
  return __builtin_bit_cast(float, u & 0xFFFF0000u);
}
__device__ __forceinline__ uint_ cvtpk(float a, float b) {
  uint_ r;
  asm("v_cvt_pk_bf16_f32 %0, %1, %2" : "=v"(r) : "v"(a), "v"(b));
  return r;
}
__device__ __forceinline__ void gload16(const void* g, void* l) {
  __builtin_amdgcn_global_load_lds(
      (const __attribute__((address_space(1))) unsigned int*)g,
      (__attribute__((address_space(3))) unsigned int*)l, 16, 0, 0);
}

// ---------------------------------------------------------------------------
// f32 -> bf16 convert, zero-pad tail
// ---------------------------------------------------------------------------
__global__ __launch_bounds__(256) void cvt_bf16(
    const float* __restrict__ src, unsigned short* __restrict__ dst,
    int n_src, int n_total) {
  const int i = (blockIdx.x * 256 + threadIdx.x) * 8;
  if (i >= n_total) return;
  u32x4 o;
  if (i < n_src) {
    float4 a = *(const float4*)(src + i);
    float4 b = *(const float4*)(src + i + 4);
    o.x = cvtpk(a.x, a.y); o.y = cvtpk(a.z, a.w);
    o.z = cvtpk(b.x, b.y); o.w = cvtpk(b.z, b.w);
  } else {
    o.x = 0; o.y = 0; o.z = 0; o.w = 0;
  }
  *(u32x4*)(dst + i) = o;
}

// ---------------------------------------------------------------------------
// bf16 MFMA GEMM core: C = A * B^T, 128x128 tile, BK=32, 4 waves
// ---------------------------------------------------------------------------
__device__ __forceinline__ void gemm_core(
    const unsigned short* __restrict__ A, const unsigned short* __restrict__ Bm,
    int K, int m0, int n0, f32x4 (&acc)[4][4]) {
  __shared__ __align__(16) unsigned short As[128 * 32];
  __shared__ __align__(16) unsigned short Bs[128 * 32];
  const int tid = threadIdx.x;
  const int lane = tid & 63;
  const int wv = tid >> 6;
  const int wm = wv >> 1, wn = wv & 1;
  const int srow = tid >> 2, scol = (tid & 3) * 8;
  const int fr = lane & 15, fk = (lane >> 4) * 8;
  const unsigned short* ag = A + (size_t)(m0 + srow) * K + scol;
  const unsigned short* bg = Bm + (size_t)(n0 + srow) * K + scol;
  unsigned short* asd = As + tid * 8;
  unsigned short* bsd = Bs + tid * 8;
  const int arow = wm * 64 + fr;
  const int brow = wn * 64 + fr;
  for (int k0 = 0; k0 < K; k0 += 32) {
    __syncthreads();
    gload16(ag + k0, asd);
    gload16(ag + (size_t)64 * K + k0, asd + 2048);
    gload16(bg + k0, bsd);
    gload16(bg + (size_t)64 * K + k0, bsd + 2048);
    __syncthreads();
    bf16x8 af[4], bfr[4];
    #pragma unroll
    for (int m = 0; m < 4; ++m)
      af[m] = *(const bf16x8*)(As + (arow + m * 16) * 32 + fk);
    #pragma unroll
    for (int n = 0; n < 4; ++n)
      bfr[n] = *(const bf16x8*)(Bs + (brow + n * 16) * 32 + fk);
    #pragma unroll
    for (int m = 0; m < 4; ++m)
      #pragma unroll
      for (int n = 0; n < 4; ++n)
        acc[m][n] = __builtin_amdgcn_mfma_f32_16x16x32_bf16(af[m], bfr[n], acc[m][n], 0, 0, 0);
  }
}

// ---------------------------------------------------------------------------
// QKV GEMM: Xbf[3200][768] * Wbf[2304][768]^T -> scatter f32 q/k/v [B,NH,L,HD]
// ---------------------------------------------------------------------------
__global__ __launch_bounds__(256) void qkv_gemm_mfma(
    const unsigned short* __restrict__ Xbf, const unsigned short* __restrict__ Wbf,
    float* __restrict__ q_raw, float* __restrict__ k_raw, float* __restrict__ v_raw) {
  f32x4 acc[4][4] = {};
  const int m0 = blockIdx.y * 128;
  const int n0 = blockIdx.x * 128;
  gemm_core(Xbf, Wbf, C_, m0, n0, acc);
  const int lane = threadIdx.x & 63;
  const int wv = threadIdx.x >> 6;
  const int wm = wv >> 1, wn = wv & 1;
  const int fr = lane & 15, fj = (lane >> 4) * 4;
  #pragma unroll
  for (int n = 0; n < 4; ++n) {
    const int gn = n0 + wn * 64 + n * 16 + fr;
    const int which = (gn >= 2 * C_) ? 2 : ((gn >= C_) ? 1 : 0);
    const int rem = gn - which * C_;
    const int h = rem >> 6, d = rem & 63;
    float* dst = (which == 0) ? q_raw : ((which == 1) ? k_raw : v_raw);
    #pragma unroll
    for (int m = 0; m < 4; ++m) {
      #pragma unroll
      for (int j = 0; j < 4; ++j) {
        const int gm = m0 + wm * 64 + m * 16 + fj + j;
        if (gm < B_ * L_) {
          const int b = (gm >= L_) ? 1 : 0;
          const int l = gm - b * L_;
          dst[(((size_t)b * NH_ + h) * L_ + l) * HD_ + d] = acc[m][n][j];
        }
      }
    }
  }
}

// ---------------------------------------------------------------------------
// Proj GEMM: Abf[3200][768] * Wobf[768][768]^T + bo -> d_out f32
// ---------------------------------------------------------------------------
__global__ __launch_bounds__(256) void proj_gemm_mfma(
    const unsigned short* __restrict__ Abf, const unsigned short* __restrict__ Wobf,
    const float* __restrict__ bo, float* __restrict__ out) {
  f32x4 acc[4][4] = {};
  const int m0 = blockIdx.y * 128;
  const int n0 = blockIdx.x * 128;
  gemm_core(Abf, Wobf, C_, m0, n0, acc);
  const int lane = threadIdx.x & 63;
  const int wv = threadIdx.x >> 6;
  const int wm = wv >> 1, wn = wv & 1;
  const int fr = lane & 15, fj = (lane >> 4) * 4;
  #pragma unroll
  for (int n = 0; n < 4; ++n) {
    const int gn = n0 + wn * 64 + n * 16 + fr;
    const float bias = bo[gn];
    #pragma unroll
    for (int m = 0; m < 4; ++m) {
      #pragma unroll
      for (int j = 0; j < 4; ++j) {
        const int gm = m0 + wm * 64 + m * 16 + fj + j;
        if (gm < B_ * L_) out[(size_t)gm * C_ + gn] = acc[m][n][j] + bias;
      }
    }
  }
}

// ---------------------------------------------------------------------------
// Fused depthwise 3x3 conv + LayerNorm(64) for q/k/v (blockIdx.y selects)
// ---------------------------------------------------------------------------
__global__ __launch_bounds__(256) void pool_ln_fused(
    const float* __restrict__ q_raw, const float* __restrict__ k_raw,
    const float* __restrict__ v_raw,
    const float* __restrict__ qw, const float* __restrict__ kw,
    const float* __restrict__ vw,
    const float* __restrict__ qg, const float* __restrict__ qb2,
    const float* __restrict__ kg, const float* __restrict__ kb2,
    const float* __restrict__ vg, const float* __restrict__ vb2,
    unsigned short* __restrict__ Qp2, unsigned short* __restrict__ Kp2a,
    unsigned short* __restrict__ Vtmp) {
  const int which = blockIdx.y;
  const float* in = (which == 0) ? q_raw : (which == 1) ? k_raw : v_raw;
  const float* w  = (which == 0) ? qw : (which == 1) ? kw : vw;
  const float* g  = (which == 0) ? qg : (which == 1) ? kg : vg;
  const float* bb = (which == 0) ? qb2 : (which == 1) ? kb2 : vb2;
  unsigned short* out = (which == 0) ? Qp2 : (which == 1) ? Kp2a : Vtmp;
  const int stride = (which == 0) ? DP_ : 64;
  const float scale = (which == 1) ? SCALE_K : 1.f;

  const int row = blockIdx.x * 4 + (threadIdx.x >> 6);
  const int d = threadIdx.x & 63;
  const int bh = row / L_;
  const int l  = row % L_;
  const int t  = l / S_;
  const int sq = l % S_;
  const int x = sq / W_, y = sq % W_;
  const float* base = in + ((size_t)bh * L_ + t * S_) * HD_;
  float acc = 0.f;
  #pragma unroll
  for (int dx = 0; dx < 3; ++dx) {
    const int xx = x + dx - 1;
    if (xx < 0 || xx >= H_) continue;
    #pragma unroll
    for (int dy = 0; dy < 3; ++dy) {
      const int yy = y + dy - 1;
      if (yy < 0 || yy >= W_) continue;
      acc += base[(size_t)(xx * W_ + yy) * HD_ + d] * w[(dx * 3 + dy) * HD_ + d];
    }
  }
  float s = acc;
  #pragma unroll
  for (int off = 32; off; off >>= 1) s += __shfl_xor(s, off);
  const float mu = s * (1.f / 64.f);
  const float dv = acc - mu;
  float s2 = dv * dv;
  #pragma unroll
  for (int off = 32; off; off >>= 1) s2 += __shfl_xor(s2, off);
  const float var = s2 * (1.f / 64.f);
  const float val = dv * rsqrtf(var + LN_EPS) * g[d] + bb[d];
  out[(size_t)row * stride + d] = f2bf(val * scale);
}

// ---------------------------------------------------------------------------
// Transpose V per head: Vtmp [bh][L][64] bf16 -> VpT [bh][64][L] bf16
// ---------------------------------------------------------------------------
__global__ __launch_bounds__(256) void transpose_v(
    const unsigned short* __restrict__ Vtmp, unsigned short* __restrict__ VpT) {
  __shared__ unsigned short tile[32][72];
  const int bh = blockIdx.y;
  const int l0 = blockIdx.x * 32;
  const int t = threadIdx.x;
  {
    const int r = t >> 3, c8 = (t & 7) * 8;
    u32x4 v = *(const u32x4*)(Vtmp + ((size_t)bh * L_ + l0 + r) * 64 + c8);
    *(u32x4*)&tile[r][c8] = v;
  }
  __syncthreads();
  const int d = t >> 2, gq = t & 3;
  unsigned short o[8];
  #pragma unroll
  for (int i = 0; i < 8; ++i) o[i] = tile[gq*8 + i][d];
  u32x4 ov;
  ov.x = (uint_)o[0] | ((uint_)o[1] << 16);
  ov.y = (uint_)o[2] | ((uint_)o[3] << 16);
  ov.z = (uint_)o[4] | ((uint_)o[5] << 16);
  ov.w = (uint_)o[6] | ((uint_)o[7] << 16);
  *(u32x4*)(VpT + ((size_t)bh * 64 + d) * L_ + l0 + gq*8) = ov;
}

// ---------------------------------------------------------------------------
// rel-pos rows -> Qp2 dims 64..175 (log2e-scaled; other T-block zeroed)
// ---------------------------------------------------------------------------
__global__ void relpos_fused(
    const unsigned short* __restrict__ Qp2r, const float* __restrict__ rph,
    const float* __restrict__ rpw, unsigned short* __restrict__ Qp2) {
  const int idx = blockIdx.x * blockDim.x + threadIdx.x;
  const int k = idx % H_;
  const int rest = idx / H_;            // bh*L + t*S + sq
  const int sq = rest % S_;
  const int t = (rest % L_) / S_;
  const int x = sq / W_, y = sq % W_;
  const unsigned short* qrow = Qp2r + (size_t)rest * DP_;
  const float* rh = rph + (x - k + H_ - 1) * HD_;
  const float* rw = rpw + (y - k + W_ - 1) * HD_;
  float ah = 0.f, aw = 0.f;
  #pragma unroll
  for (int c = 0; c < HD_; c += 8) {
    u32x4 qv = *(const u32x4*)(qrow + c);
    float4 h0 = *(const float4*)(rh + c);
    float4 h1 = *(const float4*)(rh + c + 4);
    float4 w0 = *(const float4*)(rw + c);
    float4 w1 = *(const float4*)(rw + c + 4);
    const float q0 = bflo(qv.x), q1 = bfhi(qv.x), q2 = bflo(qv.y), q3 = bfhi(qv.y);
    const float q4 = bflo(qv.z), q5 = bfhi(qv.z), q6 = bflo(qv.w), q7 = bfhi(qv.w);
    ah += q0*h0.x + q1*h0.y + q2*h0.z + q3*h0.w + q4*h1.x + q5*h1.y + q6*h1.z + q7*h1.w;
    aw += q0*w0.x + q1*w0.y + q2*w0.z + q3*w0.w + q4*w1.x + q5*w1.y + q6*w1.z + q7*w1.w;
  }
  unsigned short* qd = Qp2 + (size_t)rest * DP_;
  qd[64 + t*56 + k]        = f2bf(ah * LOG2E);
  qd[64 + t*56 + 28 + k]   = f2bf(aw * LOG2E);
  qd[64 + (1-t)*56 + k]      = 0;
  qd[64 + (1-t)*56 + 28 + k] = 0;
}

// ---------------------------------------------------------------------------
// MFMA flash attention. 128 thr (2 waves), grid 1176 (XCD-swizzled).
// Stride-2 KV-tile interleave across the 2 waves; VALU one-hot (no mem dep);
// bias MFMAs skipped on cross-temporal tiles.
// ---------------------------------------------------------------------------
__device__ __forceinline__ void load_tile(
    const unsigned short* kbase, const unsigned short* vbase0, int kt,
    u32x4& k0, u32x4& k1, u32x4& k2, u32x4& k3,
    u32x4& va, u32x4& vb, u32x4& vc, u32x4& vd) {
  const unsigned short* kr = kbase + (size_t)kt * 2048;
  k0 = *(const u32x4*)(kr);
  k1 = *(const u32x4*)(kr + 16);
  k2 = *(const u32x4*)(kr + 32);
  k3 = *(const u32x4*)(kr + 48);
  const unsigned short* vr = vbase0 + kt * 32;
  va = *(const u32x4*)(vr);
  vb = *(const u32x4*)(vr + 16);
  vc = *(const u32x4*)(vr + 32 * L_);
  vd = *(const u32x4*)(vr + 32 * L_ + 16);
}

template<bool BIAS>
__device__ __forceinline__ void proc_tile(
    int kt, int lo, int hi, const u32x4 (&qf)[11],
    u32x4 k0, u32x4 k1, u32x4 k2, u32x4 k3,
    u32x4 va, u32x4 vb, u32x4 vc, u32x4 vd,
    f32x16& acc0, f32x16& acc1, float& m_run, float& l_run) {
  f32x16 s = {};
  __builtin_amdgcn_s_setprio(1);
  s = __builtin_amdgcn_mfma_f32_32x32x16_bf16(BC8(k0), BC8(qf[0]), s, 0, 0, 0);
  s = __builtin_amdgcn_mfma_f32_32x32x16_bf16(BC8(k1), BC8(qf[1]), s, 0, 0, 0);
  s = __builtin_amdgcn_mfma_f32_32x32x16_bf16(BC8(k2), BC8(qf[2]), s, 0, 0, 0);
  s = __builtin_amdgcn_mfma_f32_32x32x16_bf16(BC8(k3), BC8(qf[3]), s, 0, 0, 0);
  __builtin_amdgcn_s_setprio(0);
  if (BIAS) {
    // one-hot K' fragment built in-register (no memory dependency)
    const int kr = kt * 32 + lo;
    const int t = (kr >= S_) ? 1 : 0;
    const int sk = kr - t * S_;
    const int x = sk / W_, y = sk - x * W_;
    const int p1 = 64 + t*56 + x;
    const int p2 = 64 + t*56 + 28 + y;
    const uint_ v1 = 0x3F80u << ((p1 & 1) << 4);
    const uint_ v2 = 0x3F80u << ((p2 & 1) << 4);
    const int g1 = p1 >> 3, g2 = p2 >> 3;
    const int w1 = (p1 >> 1) & 3, w2 = (p2 >> 1) & 3;
    __builtin_amdgcn_s_setprio(1);
    #pragma unroll
    for (int c = 4; c < 11; ++c) {
      const int gg = 2*c + hi;
      u32x4 oh;
      oh.x = ((g1 == gg && w1 == 0) ? v1 : 0u) | ((g2 == gg && w2 == 0) ? v2 : 0u);
      oh.y = ((g1 == gg && w1 == 1) ? v1 : 0u) | ((g2 == gg && w2 == 1) ? v2 : 0u);
      oh.z = ((g1 == gg && w1 == 2) ? v1 : 0u) | ((g2 == gg && w2 == 2) ? v2 : 0u);
      oh.w = ((g1 == gg && w1 == 3) ? v1 : 0u) | ((g2 == gg && w2 == 3) ? v2 : 0u);
      s = __builtin_amdgcn_mfma_f32_32x32x16_bf16(BC8(oh), BC8(qf[c]), s, 0, 0, 0);
    }
    __builtin_amdgcn_s_setprio(0);
  }

  // pairwise max tree
  float m01 = fmaxf(s[0], s[1]),  m23 = fmaxf(s[2], s[3]);
  float m45 = fmaxf(s[4], s[5]),  m67 = fmaxf(s[6], s[7]);
  float m89 = fmaxf(s[8], s[9]),  mab = fmaxf(s[10], s[11]);
  float mcd = fmaxf(s[12], s[13]), mef = fmaxf(s[14], s[15]);
  float pmax = fmaxf(fmaxf(fmaxf(m01, m23), fmaxf(m45, m67)),
                     fmaxf(fmaxf(m89, mab), fmaxf(mcd, mef)));
  pmax = fmaxf(pmax, __shfl_xor(pmax, 32));
  if (__any(pmax > m_run + 8.f)) {            // defer-max (log2 units)
    const float mn = fmaxf(m_run, pmax);
    const float f = exp2f(m_run - mn);
    m_run = mn; l_run *= f;
    #pragma unroll
    for (int r = 0; r < 16; ++r) {
      const float fr = __shfl(f, (r & 3) + 8*(r >> 2) + 4*hi);
      acc0[r] *= fr; acc1[r] *= fr;
    }
  }
  float ps = 0.f;
  uint_ pw0, pw1, pw2, pw3, pw4, pw5, pw6, pw7;
  {
    float a, b;
    a = exp2f(s[0]-m_run);  b = exp2f(s[1]-m_run);  ps += a+b; pw0 = cvtpk(a,b);
    a = exp2f(s[2]-m_run);  b = exp2f(s[3]-m_run);  ps += a+b; pw1 = cvtpk(a,b);
    a = exp2f(s[4]-m_run);  b = exp2f(s[5]-m_run);  ps += a+b; pw2 = cvtpk(a,b);
    a = exp2f(s[6]-m_run);  b = exp2f(s[7]-m_run);  ps += a+b; pw3 = cvtpk(a,b);
    a = exp2f(s[8]-m_run);  b = exp2f(s[9]-m_run);  ps += a+b; pw4 = cvtpk(a,b);
    a = exp2f(s[10]-m_run); b = exp2f(s[11]-m_run); ps += a+b; pw5 = cvtpk(a,b);
    a = exp2f(s[12]-m_run); b = exp2f(s[13]-m_run); ps += a+b; pw6 = cvtpk(a,b);
    a = exp2f(s[14]-m_run); b = exp2f(s[15]-m_run); ps += a+b; pw7 = cvtpk(a,b);
  }
  ps += __shfl_xor(ps, 32);
  l_run += ps;

  auto sA = __builtin_amdgcn_permlane32_swap(pw0, pw2, false, false);
  auto sB = __builtin_amdgcn_permlane32_swap(pw1, pw3, false, false);
  auto sC = __builtin_amdgcn_permlane32_swap(pw4, pw6, false, false);
  auto sD = __builtin_amdgcn_permlane32_swap(pw5, pw7, false, false);
  u32x4 pa0, pa1;
  pa0.x = sA[0]; pa0.y = sB[0]; pa0.z = sA[1]; pa0.w = sB[1];
  pa1.x = sC[0]; pa1.y = sD[0]; pa1.z = sC[1]; pa1.w = sD[1];

  __builtin_amdgcn_s_setprio(1);
  acc0 = __builtin_amdgcn_mfma_f32_32x32x16_bf16(BC8(pa0), BC8(va), acc0, 0, 0, 0);
  acc0 = __builtin_amdgcn_mfma_f32_32x32x16_bf16(BC8(pa1), BC8(vb), acc0, 0, 0, 0);
  acc1 = __builtin_amdgcn_mfma_f32_32x32x16_bf16(BC8(pa0), BC8(vc), acc1, 0, 0, 0);
  acc1 = __builtin_amdgcn_mfma_f32_32x32x16_bf16(BC8(pa1), BC8(vd), acc1, 0, 0, 0);
  __builtin_amdgcn_s_setprio(0);
}

__device__ __forceinline__ bool bias_needed(int kt, int qt) {
  const int kmin = (kt * 32 >= S_) ? 1 : 0;
  const int kmax = (kt * 32 + 31 >= S_) ? 1 : 0;
  const int qmin = (qt * 32 >= S_) ? 1 : 0;
  const int qmax = (qt * 32 + 31 >= S_) ? 1 : 0;
  return (kmin <= qmax) && (qmin <= kmax);
}

__global__ __launch_bounds__(128) void attn_mfma(
    const unsigned short* __restrict__ Qp2, const unsigned short* __restrict__ Kp2a,
    const unsigned short* __restrict__ VpT,
    unsigned short* __restrict__ Abf) {
  __shared__ float red_acc[32][64];
  __shared__ float red_ml[2][2][32];

  const int id0 = blockIdx.x;                  // 1176 = 8 * 147
  const int swz = (id0 & 7) * 147 + (id0 >> 3);
  const int qt = swz % 49;
  const int bh = swz / 49;

  const int lane = threadIdx.x & 63;
  const int wv = threadIdx.x >> 6;             // 0,1
  const int lo = lane & 31, hi = lane >> 5;
  const int q0 = qt * 32;

  u32x4 qf[11];
  {
    const unsigned short* qrow = Qp2 + ((size_t)bh * L_ + q0 + lo) * DP_ + hi * 8;
    #pragma unroll
    for (int c = 0; c < 11; ++c) qf[c] = *(const u32x4*)(qrow + c * 16);
  }

  const unsigned short* kbase = Kp2a + ((size_t)bh * L_ + lo) * 64 + hi * 8;
  const unsigned short* vbase0 = VpT + (size_t)bh * 64 * L_ + (size_t)lo * L_ + hi * 8;

  f32x16 acc0 = {}, acc1 = {};
  float m_run = -1e30f, l_run = 0.f;
  const int nt = 25 - wv;                      // wave wv: kt = wv + 2*i

  u32x4 ck0, ck1, ck2, ck3, cva, cvb, cvc, cvd;
  u32x4 nk0, nk1, nk2, nk3, nva, nvb, nvc, nvd;
  load_tile(kbase, vbase0, wv, ck0, ck1, ck2, ck3, cva, cvb, cvc, cvd);
  int i = 0;
  for (; i + 2 <= nt; i += 2) {
    const int ktA = wv + 2 * i, ktB = ktA + 2;
    load_tile(kbase, vbase0, ktB, nk0, nk1, nk2, nk3, nva, nvb, nvc, nvd);
    if (bias_needed(ktA, qt))
      proc_tile<true>(ktA, lo, hi, qf, ck0, ck1, ck2, ck3, cva, cvb, cvc, cvd, acc0, acc1, m_run, l_run);
    else
      proc_tile<false>(ktA, lo, hi, qf, ck0, ck1, ck2, ck3, cva, cvb, cvc, cvd, acc0, acc1, m_run, l_run);
    const int ktC = wv + 2 * ((i + 2 < nt) ? i + 2 : nt - 1);
    load_tile(kbase, vbase0, ktC, ck0, ck1, ck2, ck3, cva, cvb, cvc, cvd);
    if (bias_needed(ktB, qt))
      proc_tile<true>(ktB, lo, hi, qf, nk0, nk1, nk2, nk3, nva, nvb, nvc, nvd, acc0, acc1, m_run, l_run);
    else
      proc_tile<false>(ktB, lo, hi, qf, nk0, nk1, nk2, nk3, nva, nvb, nvc, nvd, acc0, acc1, m_run, l_run);
  }
  if (i < nt) {
    const int ktA = wv + 2 * i;
    if (bias_needed(ktA, qt))
      proc_tile<true>(ktA, lo, hi, qf, ck0, ck1, ck2, ck3, cva, cvb, cvc, cvd, acc0, acc1, m_run, l_run);
    else
      proc_tile<false>(ktA, lo, hi, qf, ck0, ck1, ck2, ck3, cva, cvb, cvc, cvd, acc0, acc1, m_run, l_run);
  }

  // merge the two waves' partial states
  if (hi == 0) { red_ml[wv][0][lo] = m_run; red_ml[wv][1][lo] = l_run; }
  if (wv == 1) {
    #pragma unroll
    for (int r = 0; r < 16; ++r) {
      const int row = (r & 3) + 8*(r >> 2) + 4*hi;
      red_acc[row][lo]      = acc0[r];
      red_acc[row][32 + lo] = acc1[r];
    }
  }
  __syncthreads();
  if (wv == 0) {
    const int b = bh / NH_, h = bh % NH_;
    #pragma unroll
    for (int r = 0; r < 16; ++r) {
      const int row = (r & 3) + 8*(r >> 2) + 4*hi;
      const float m0 = red_ml[0][0][row], l0 = red_ml[0][1][row];
      const float m1 = red_ml[1][0][row], l1 = red_ml[1][1][row];
      const float M = fmaxf(m0, m1);
      const float w0 = exp2f(m0 - M), w1 = exp2f(m1 - M);
      const float inv = 1.0f / (l0 * w0 + l1 * w1);
      const float o0 = (acc0[r] * w0 + red_acc[row][lo] * w1) * inv;
      const float o1 = (acc1[r] * w0 + red_acc[row][32 + lo] * w1) * inv;
      const size_t qoff = ((size_t)bh * L_ + q0 + row) * DP_ + lo;
      const size_t ooff = ((size_t)(b * L_ + q0 + row)) * C_ + h * 64 + lo;
      Abf[ooff]      = f2bf(o0 + bf2f(Qp2[qoff]));
      Abf[ooff + 32] = f2bf(o1 + bf2f(Qp2[qoff + 32]));
    }
  }
}

// ---------------------------------------------------------------------------
extern "C" void kernel_launch(void* const* d_in, const int* in_sizes, int n_in,
                              void* d_out, int out_size, void* d_ws, size_t ws_size,
                              hipStream_t stream) {
  const float* x         = (const float*)d_in[0];
  const float* qkv_w     = (const float*)d_in[1];
  const float* out_w     = (const float*)d_in[2];
  const float* out_b     = (const float*)d_in[3];
  const float* q_pool_w  = (const float*)d_in[4];
  const float* k_pool_w  = (const float*)d_in[5];
  const float* v_pool_w  = (const float*)d_in[6];
  const float* q_ln_g    = (const float*)d_in[7];
  const float* q_ln_b    = (const float*)d_in[8];
  const float* k_ln_g    = (const float*)d_in[9];
  const float* k_ln_b    = (const float*)d_in[10];
  const float* v_ln_g    = (const float*)d_in[11];
  const float* v_ln_b    = (const float*)d_in[12];
  const float* rel_pos_h = (const float*)d_in[13];
  const float* rel_pos_w = (const float*)d_in[14];

  float* R = (float*)d_ws;
  const size_t NQ = (size_t)B_ * NH_ * L_ * HD_;   // 2,408,448 f32 slots
  // region map (f32 slots), no live overlaps:
  // A [0,NQ): q_raw -> Abf (1,228,800)     B [NQ,2NQ): k_raw -> VpT (1,204,224)
  // C [2NQ,3NQ): v_raw
  // D [3NQ,+3,311,616): Xbf (1,228,800) -> Qp2
  // E: Kp2a (1,204,224)                    F: Wbf (884,736) -> Vtmp (1,204,224)
  // G: Wobf (294,912)
  float* q_raw = R;
  unsigned short* Abf = (unsigned short*)R;
  float* k_raw = R + NQ;
  unsigned short* VpT = (unsigned short*)(R + NQ);
  float* v_raw = R + 2*NQ;
  const size_t D_off = 3*NQ;
  unsigned short* Xbf = (unsigned short*)(R + D_off);
  unsigned short* Qp2 = (unsigned short*)(R + D_off);
  const size_t E_off = D_off + 3311616;
  unsigned short* Kp2a = (unsigned short*)(R + E_off);
  const size_t F_off = E_off + 1204224;
  unsigned short* Wbf  = (unsigned short*)(R + F_off);
  unsigned short* Vtmp = (unsigned short*)(R + F_off);
  const size_t G_off = F_off + 1204224;
  unsigned short* Wobf = (unsigned short*)(R + G_off);

  cvt_bf16<<<1200, 256, 0, stream>>>(x, Xbf, 3136*768, 3200*768);
  cvt_bf16<<<864, 256, 0, stream>>>(qkv_w, Wbf, 2304*768, 2304*768);
  cvt_bf16<<<288, 256, 0, stream>>>(out_w, Wobf, 768*768, 768*768);
  qkv_gemm_mfma<<<dim3(18, 25), 256, 0, stream>>>(Xbf, Wbf, q_raw, k_raw, v_raw);
  pool_ln_fused<<<dim3(9408, 3), 256, 0, stream>>>(
      q_raw, k_raw, v_raw, q_pool_w, k_pool_w, v_pool_w,
      q_ln_g, q_ln_b, k_ln_g, k_ln_b, v_ln_g, v_ln_b, Qp2, Kp2a, Vtmp);
  cvt_bf16<<<24, 256, 0, stream>>>(nullptr, Abf + 3136*768, 0, 64*768);  // pad rows
  transpose_v<<<dim3(49, 24), 256, 0, stream>>>(Vtmp, VpT);
  relpos_fused<<<4116, 256, 0, stream>>>(Qp2, rel_pos_h, rel_pos_w, Qp2);
  attn_mfma<<<1176, 128, 0, stream>>>(Qp2, Kp2a, VpT, Abf);
  proj_gemm_mfma<<<dim3(6, 25), 256, 0, stream>>>(Abf, Wobf, out_b, (float*)d_out);
}

// Round 7
// 258.358 us; speedup vs baseline: 1.1234x; 1.0433x over previous
//
#include <hip/hip_runtime.h>
#include <math.h>

#define B_ 2
#define T_ 2
#define H_ 28
#define W_ 28
#define S_ (H_*W_)      /* 784  */
#define L_ (T_*S_)      /* 1568 */
#define C_ 768
#define NH_ 12
#define HD_ 64
#define LN_EPS 1e-5f
#define LOG2E 1.4426950408889634f
#define SCALE_K (0.125f * LOG2E)   /* hd^-0.5 * log2e folded into K' */
#define DP_ 176                     /* augmented head dim: 64 + 2*2*28 */

typedef unsigned int uint_;
typedef unsigned int u32x4 __attribute__((ext_vector_type(4)));
typedef __bf16 bf16x8 __attribute__((ext_vector_type(8)));
typedef float f32x4 __attribute__((ext_vector_type(4)));
typedef float f32x16 __attribute__((ext_vector_type(16)));

#define BC8(x) __builtin_bit_cast(bf16x8, (x))

__device__ __forceinline__ unsigned short f2bf(float f) {
  uint_ u = __builtin_bit_cast(uint_, f);
  u += 0x7FFFu + ((u >> 16) & 1u);
  return (unsigned short)(u >> 16);
}
__device__ __forceinline__ float bf2f(unsigned short h) {
  return __builtin_bit_cast(float, ((uint_)h) << 16);
}
__device__ __forceinline__ float bflo(uint_ u) {
  return __builtin_bit_cast(float, u << 16);
}
__device__ __forceinline__ float bfhi(uint_ u) {
  return __builtin_bit_cast(float, u & 0xFFFF0000u);
}
__device__ __forceinline__ uint_ cvtpk(float a, float b) {
  uint_ r;
  asm("v_cvt_pk_bf16_f32 %0, %1, %2" : "=v"(r) : "v"(a), "v"(b));
  return r;
}
__device__ __forceinline__ void gload16(const void* g, void* l) {
  __builtin_amdgcn_global_load_lds(
      (const __attribute__((address_space(1))) unsigned int*)g,
      (__attribute__((address_space(3))) unsigned int*)l, 16, 0, 0);
}

// ---------------------------------------------------------------------------
// f32 -> bf16 convert, zero-pad tail
// ---------------------------------------------------------------------------
__global__ __launch_bounds__(256) void cvt_bf16(
    const float* __restrict__ src, unsigned short* __restrict__ dst,
    int n_src, int n_total) {
  const int i = (blockIdx.x * 256 + threadIdx.x) * 8;
  if (i >= n_total) return;
  u32x4 o;
  if (i < n_src) {
    float4 a = *(const float4*)(src + i);
    float4 b = *(const float4*)(src + i + 4);
    o.x = cvtpk(a.x, a.y); o.y = cvtpk(a.z, a.w);
    o.z = cvtpk(b.x, b.y); o.w = cvtpk(b.z, b.w);
  } else {
    o.x = 0; o.y = 0; o.z = 0; o.w = 0;
  }
  *(u32x4*)(dst + i) = o;
}

// ---------------------------------------------------------------------------
// bf16 MFMA GEMM core: C = A * B^T, 128x128 tile, BK=32, 4 waves
// ---------------------------------------------------------------------------
__device__ __forceinline__ void gemm_core(
    const unsigned short* __restrict__ A, const unsigned short* __restrict__ Bm,
    int K, int m0, int n0, f32x4 (&acc)[4][4]) {
  __shared__ __align__(16) unsigned short As[128 * 32];
  __shared__ __align__(16) unsigned short Bs[128 * 32];
  const int tid = threadIdx.x;
  const int lane = tid & 63;
  const int wv = tid >> 6;
  const int wm = wv >> 1, wn = wv & 1;
  const int srow = tid >> 2, scol = (tid & 3) * 8;
  const int fr = lane & 15, fk = (lane >> 4) * 8;
  const unsigned short* ag = A + (size_t)(m0 + srow) * K + scol;
  const unsigned short* bg = Bm + (size_t)(n0 + srow) * K + scol;
  unsigned short* asd = As + tid * 8;
  unsigned short* bsd = Bs + tid * 8;
  const int arow = wm * 64 + fr;
  const int brow = wn * 64 + fr;
  for (int k0 = 0; k0 < K; k0 += 32) {
    __syncthreads();
    gload16(ag + k0, asd);
    gload16(ag + (size_t)64 * K + k0, asd + 2048);
    gload16(bg + k0, bsd);
    gload16(bg + (size_t)64 * K + k0, bsd + 2048);
    __syncthreads();
    bf16x8 af[4], bfr[4];
    #pragma unroll
    for (int m = 0; m < 4; ++m)
      af[m] = *(const bf16x8*)(As + (arow + m * 16) * 32 + fk);
    #pragma unroll
    for (int n = 0; n < 4; ++n)
      bfr[n] = *(const bf16x8*)(Bs + (brow + n * 16) * 32 + fk);
    #pragma unroll
    for (int m = 0; m < 4; ++m)
      #pragma unroll
      for (int n = 0; n < 4; ++n)
        acc[m][n] = __builtin_amdgcn_mfma_f32_16x16x32_bf16(af[m], bfr[n], acc[m][n], 0, 0, 0);
  }
}

// ---------------------------------------------------------------------------
// QKV GEMM: Xbf[3200][768] * Wbf[2304][768]^T -> scatter f32 q/k/v [B,NH,L,HD]
// ---------------------------------------------------------------------------
__global__ __launch_bounds__(256) void qkv_gemm_mfma(
    const unsigned short* __restrict__ Xbf, const unsigned short* __restrict__ Wbf,
    float* __restrict__ q_raw, float* __restrict__ k_raw, float* __restrict__ v_raw) {
  f32x4 acc[4][4] = {};
  const int m0 = blockIdx.y * 128;
  const int n0 = blockIdx.x * 128;
  gemm_core(Xbf, Wbf, C_, m0, n0, acc);
  const int lane = threadIdx.x & 63;
  const int wv = threadIdx.x >> 6;
  const int wm = wv >> 1, wn = wv & 1;
  const int fr = lane & 15, fj = (lane >> 4) * 4;
  #pragma unroll
  for (int n = 0; n < 4; ++n) {
    const int gn = n0 + wn * 64 + n * 16 + fr;
    const int which = (gn >= 2 * C_) ? 2 : ((gn >= C_) ? 1 : 0);
    const int rem = gn - which * C_;
    const int h = rem >> 6, d = rem & 63;
    float* dst = (which == 0) ? q_raw : ((which == 1) ? k_raw : v_raw);
    #pragma unroll
    for (int m = 0; m < 4; ++m) {
      #pragma unroll
      for (int j = 0; j < 4; ++j) {
        const int gm = m0 + wm * 64 + m * 16 + fj + j;
        if (gm < B_ * L_) {
          const int b = (gm >= L_) ? 1 : 0;
          const int l = gm - b * L_;
          dst[(((size_t)b * NH_ + h) * L_ + l) * HD_ + d] = acc[m][n][j];
        }
      }
    }
  }
}

// ---------------------------------------------------------------------------
// Proj GEMM: Abf[3200][768] * Wobf[768][768]^T + bo -> d_out f32
// ---------------------------------------------------------------------------
__global__ __launch_bounds__(256) void proj_gemm_mfma(
    const unsigned short* __restrict__ Abf, const unsigned short* __restrict__ Wobf,
    const float* __restrict__ bo, float* __restrict__ out) {
  f32x4 acc[4][4] = {};
  const int m0 = blockIdx.y * 128;
  const int n0 = blockIdx.x * 128;
  gemm_core(Abf, Wobf, C_, m0, n0, acc);
  const int lane = threadIdx.x & 63;
  const int wv = threadIdx.x >> 6;
  const int wm = wv >> 1, wn = wv & 1;
  const int fr = lane & 15, fj = (lane >> 4) * 4;
  #pragma unroll
  for (int n = 0; n < 4; ++n) {
    const int gn = n0 + wn * 64 + n * 16 + fr;
    const float bias = bo[gn];
    #pragma unroll
    for (int m = 0; m < 4; ++m) {
      #pragma unroll
      for (int j = 0; j < 4; ++j) {
        const int gm = m0 + wm * 64 + m * 16 + fj + j;
        if (gm < B_ * L_) out[(size_t)gm * C_ + gn] = acc[m][n][j] + bias;
      }
    }
  }
}

// ---------------------------------------------------------------------------
// Fused depthwise 3x3 conv + LayerNorm(64) for q/k/v (blockIdx.y selects)
// ---------------------------------------------------------------------------
__global__ __launch_bounds__(256) void pool_ln_fused(
    const float* __restrict__ q_raw, const float* __restrict__ k_raw,
    const float* __restrict__ v_raw,
    const float* __restrict__ qw, const float* __restrict__ kw,
    const float* __restrict__ vw,
    const float* __restrict__ qg, const float* __restrict__ qb2,
    const float* __restrict__ kg, const float* __restrict__ kb2,
    const float* __restrict__ vg, const float* __restrict__ vb2,
    unsigned short* __restrict__ Qp2, unsigned short* __restrict__ Kp2a,
    unsigned short* __restrict__ Vtmp) {
  const int which = blockIdx.y;
  const float* in = (which == 0) ? q_raw : (which == 1) ? k_raw : v_raw;
  const float* w  = (which == 0) ? qw : (which == 1) ? kw : vw;
  const float* g  = (which == 0) ? qg : (which == 1) ? kg : vg;
  const float* bb = (which == 0) ? qb2 : (which == 1) ? kb2 : vb2;
  unsigned short* out = (which == 0) ? Qp2 : (which == 1) ? Kp2a : Vtmp;
  const int stride = (which == 0) ? DP_ : 64;
  const float scale = (which == 1) ? SCALE_K : 1.f;

  const int row = blockIdx.x * 4 + (threadIdx.x >> 6);
  const int d = threadIdx.x & 63;
  const int bh = row / L_;
  const int l  = row % L_;
  const int t  = l / S_;
  const int sq = l % S_;
  const int x = sq / W_, y = sq % W_;
  const float* base = in + ((size_t)bh * L_ + t * S_) * HD_;
  float acc = 0.f;
  #pragma unroll
  for (int dx = 0; dx < 3; ++dx) {
    const int xx = x + dx - 1;
    if (xx < 0 || xx >= H_) continue;
    #pragma unroll
    for (int dy = 0; dy < 3; ++dy) {
      const int yy = y + dy - 1;
      if (yy < 0 || yy >= W_) continue;
      acc += base[(size_t)(xx * W_ + yy) * HD_ + d] * w[(dx * 3 + dy) * HD_ + d];
    }
  }
  float s = acc;
  #pragma unroll
  for (int off = 32; off; off >>= 1) s += __shfl_xor(s, off);
  const float mu = s * (1.f / 64.f);
  const float dv = acc - mu;
  float s2 = dv * dv;
  #pragma unroll
  for (int off = 32; off; off >>= 1) s2 += __shfl_xor(s2, off);
  const float var = s2 * (1.f / 64.f);
  const float val = dv * rsqrtf(var + LN_EPS) * g[d] + bb[d];
  out[(size_t)row * stride + d] = f2bf(val * scale);
}

// ---------------------------------------------------------------------------
// Transpose V per head: Vtmp [bh][L][64] bf16 -> VpT [bh][64][L] bf16
// ---------------------------------------------------------------------------
__global__ __launch_bounds__(256) void transpose_v(
    const unsigned short* __restrict__ Vtmp, unsigned short* __restrict__ VpT) {
  __shared__ unsigned short tile[32][72];
  const int bh = blockIdx.y;
  const int l0 = blockIdx.x * 32;
  const int t = threadIdx.x;
  {
    const int r = t >> 3, c8 = (t & 7) * 8;
    u32x4 v = *(const u32x4*)(Vtmp + ((size_t)bh * L_ + l0 + r) * 64 + c8);
    *(u32x4*)&tile[r][c8] = v;
  }
  __syncthreads();
  const int d = t >> 2, gq = t & 3;
  unsigned short o[8];
  #pragma unroll
  for (int i = 0; i < 8; ++i) o[i] = tile[gq*8 + i][d];
  u32x4 ov;
  ov.x = (uint_)o[0] | ((uint_)o[1] << 16);
  ov.y = (uint_)o[2] | ((uint_)o[3] << 16);
  ov.z = (uint_)o[4] | ((uint_)o[5] << 16);
  ov.w = (uint_)o[6] | ((uint_)o[7] << 16);
  *(u32x4*)(VpT + ((size_t)bh * 64 + d) * L_ + l0 + gq*8) = ov;
}

// ---------------------------------------------------------------------------
// rel-pos rows -> Qp2 dims 64..175 (log2e-scaled; other T-block zeroed)
// ---------------------------------------------------------------------------
__global__ void relpos_fused(
    const unsigned short* __restrict__ Qp2r, const float* __restrict__ rph,
    const float* __restrict__ rpw, unsigned short* __restrict__ Qp2) {
  const int idx = blockIdx.x * blockDim.x + threadIdx.x;
  const int k = idx % H_;
  const int rest = idx / H_;            // bh*L + t*S + sq
  const int sq = rest % S_;
  const int t = (rest % L_) / S_;
  const int x = sq / W_, y = sq % W_;
  const unsigned short* qrow = Qp2r + (size_t)rest * DP_;
  const float* rh = rph + (x - k + H_ - 1) * HD_;
  const float* rw = rpw + (y - k + W_ - 1) * HD_;
  float ah = 0.f, aw = 0.f;
  #pragma unroll
  for (int c = 0; c < HD_; c += 8) {
    u32x4 qv = *(const u32x4*)(qrow + c);
    float4 h0 = *(const float4*)(rh + c);
    float4 h1 = *(const float4*)(rh + c + 4);
    float4 w0 = *(const float4*)(rw + c);
    float4 w1 = *(const float4*)(rw + c + 4);
    const float q0 = bflo(qv.x), q1 = bfhi(qv.x), q2 = bflo(qv.y), q3 = bfhi(qv.y);
    const float q4 = bflo(qv.z), q5 = bfhi(qv.z), q6 = bflo(qv.w), q7 = bfhi(qv.w);
    ah += q0*h0.x + q1*h0.y + q2*h0.z + q3*h0.w + q4*h1.x + q5*h1.y + q6*h1.z + q7*h1.w;
    aw += q0*w0.x + q1*w0.y + q2*w0.z + q3*w0.w + q4*w1.x + q5*w1.y + q6*w1.z + q7*w1.w;
  }
  unsigned short* qd = Qp2 + (size_t)rest * DP_;
  qd[64 + t*56 + k]        = f2bf(ah * LOG2E);
  qd[64 + t*56 + 28 + k]   = f2bf(aw * LOG2E);
  qd[64 + (1-t)*56 + k]      = 0;
  qd[64 + (1-t)*56 + 28 + k] = 0;
}

// ---------------------------------------------------------------------------
// MFMA flash attention. 128 thr (2 waves), grid 1176 (XCD-swizzled).
// Stride-2 KV interleave; K double-buffered in regs, V single-buffered
// (loaded under softmax); bias Q-fragments loaded per bias tile (L1-hot);
// no setprio.
// ---------------------------------------------------------------------------
__device__ __forceinline__ void load_k(
    const unsigned short* kbase, int kt,
    u32x4& k0, u32x4& k1, u32x4& k2, u32x4& k3) {
  const unsigned short* kr = kbase + (size_t)kt * 2048;
  k0 = *(const u32x4*)(kr);
  k1 = *(const u32x4*)(kr + 16);
  k2 = *(const u32x4*)(kr + 32);
  k3 = *(const u32x4*)(kr + 48);
}

template<bool BIAS>
__device__ __forceinline__ void proc_tile(
    int kt, int lo, int hi, const u32x4 (&qf)[4],
    const unsigned short* __restrict__ qbias,   // Qp2 row + 64, this lane
    const unsigned short* __restrict__ vbase0,
    u32x4 k0, u32x4 k1, u32x4 k2, u32x4 k3,
    f32x16& acc0, f32x16& acc1, float& m_run, float& l_run) {
  f32x16 s = {};
  s = __builtin_amdgcn_mfma_f32_32x32x16_bf16(BC8(k0), BC8(qf[0]), s, 0, 0, 0);
  s = __builtin_amdgcn_mfma_f32_32x32x16_bf16(BC8(k1), BC8(qf[1]), s, 0, 0, 0);
  s = __builtin_amdgcn_mfma_f32_32x32x16_bf16(BC8(k2), BC8(qf[2]), s, 0, 0, 0);
  s = __builtin_amdgcn_mfma_f32_32x32x16_bf16(BC8(k3), BC8(qf[3]), s, 0, 0, 0);
  if (BIAS) {
    // one-hot K' fragment built in-register; bias Q-fragments from L1-hot mem
    const int kr = kt * 32 + lo;
    const int t = (kr >= S_) ? 1 : 0;
    const int sk = kr - t * S_;
    const int x = sk / W_, y = sk - x * W_;
    const int p1 = 64 + t*56 + x;
    const int p2 = 64 + t*56 + 28 + y;
    const uint_ v1 = 0x3F80u << ((p1 & 1) << 4);
    const uint_ v2 = 0x3F80u << ((p2 & 1) << 4);
    const int g1 = p1 >> 3, g2 = p2 >> 3;
    const int w1 = (p1 >> 1) & 3, w2 = (p2 >> 1) & 3;
    #pragma unroll
    for (int c = 4; c < 11; ++c) {
      const int gg = 2*c + hi;
      u32x4 oh;
      oh.x = ((g1 == gg && w1 == 0) ? v1 : 0u) | ((g2 == gg && w2 == 0) ? v2 : 0u);
      oh.y = ((g1 == gg && w1 == 1) ? v1 : 0u) | ((g2 == gg && w2 == 1) ? v2 : 0u);
      oh.z = ((g1 == gg && w1 == 2) ? v1 : 0u) | ((g2 == gg && w2 == 2) ? v2 : 0u);
      oh.w = ((g1 == gg && w1 == 3) ? v1 : 0u) | ((g2 == gg && w2 == 3) ? v2 : 0u);
      const u32x4 qb = *(const u32x4*)(qbias + (c - 4) * 16);
      s = __builtin_amdgcn_mfma_f32_32x32x16_bf16(BC8(oh), BC8(qb), s, 0, 0, 0);
    }
  }

  // issue V loads now — consumed after softmax (latency hidden under VALU)
  const unsigned short* vr = vbase0 + kt * 32;
  const u32x4 va = *(const u32x4*)(vr);
  const u32x4 vb = *(const u32x4*)(vr + 16);
  const u32x4 vc = *(const u32x4*)(vr + 32 * L_);
  const u32x4 vd = *(const u32x4*)(vr + 32 * L_ + 16);

  // pairwise max tree
  float m01 = fmaxf(s[0], s[1]),  m23 = fmaxf(s[2], s[3]);
  float m45 = fmaxf(s[4], s[5]),  m67 = fmaxf(s[6], s[7]);
  float m89 = fmaxf(s[8], s[9]),  mab = fmaxf(s[10], s[11]);
  float mcd = fmaxf(s[12], s[13]), mef = fmaxf(s[14], s[15]);
  float pmax = fmaxf(fmaxf(fmaxf(m01, m23), fmaxf(m45, m67)),
                     fmaxf(fmaxf(m89, mab), fmaxf(mcd, mef)));
  pmax = fmaxf(pmax, __shfl_xor(pmax, 32));
  if (__any(pmax > m_run + 8.f)) {            // defer-max (log2 units)
    const float mn = fmaxf(m_run, pmax);
    const float f = exp2f(m_run - mn);
    m_run = mn; l_run *= f;
    #pragma unroll
    for (int r = 0; r < 16; ++r) {
      const float fr = __shfl(f, (r & 3) + 8*(r >> 2) + 4*hi);
      acc0[r] *= fr; acc1[r] *= fr;
    }
  }
  float ps = 0.f;
  uint_ pw0, pw1, pw2, pw3, pw4, pw5, pw6, pw7;
  {
    float a, b;
    a = exp2f(s[0]-m_run);  b = exp2f(s[1]-m_run);  ps += a+b; pw0 = cvtpk(a,b);
    a = exp2f(s[2]-m_run);  b = exp2f(s[3]-m_run);  ps += a+b; pw1 = cvtpk(a,b);
    a = exp2f(s[4]-m_run);  b = exp2f(s[5]-m_run);  ps += a+b; pw2 = cvtpk(a,b);
    a = exp2f(s[6]-m_run);  b = exp2f(s[7]-m_run);  ps += a+b; pw3 = cvtpk(a,b);
    a = exp2f(s[8]-m_run);  b = exp2f(s[9]-m_run);  ps += a+b; pw4 = cvtpk(a,b);
    a = exp2f(s[10]-m_run); b = exp2f(s[11]-m_run); ps += a+b; pw5 = cvtpk(a,b);
    a = exp2f(s[12]-m_run); b = exp2f(s[13]-m_run); ps += a+b; pw6 = cvtpk(a,b);
    a = exp2f(s[14]-m_run); b = exp2f(s[15]-m_run); ps += a+b; pw7 = cvtpk(a,b);
  }
  ps += __shfl_xor(ps, 32);
  l_run += ps;

  auto sA = __builtin_amdgcn_permlane32_swap(pw0, pw2, false, false);
  auto sB = __builtin_amdgcn_permlane32_swap(pw1, pw3, false, false);
  auto sC = __builtin_amdgcn_permlane32_swap(pw4, pw6, false, false);
  auto sD = __builtin_amdgcn_permlane32_swap(pw5, pw7, false, false);
  u32x4 pa0, pa1;
  pa0.x = sA[0]; pa0.y = sB[0]; pa0.z = sA[1]; pa0.w = sB[1];
  pa1.x = sC[0]; pa1.y = sD[0]; pa1.z = sC[1]; pa1.w = sD[1];

  acc0 = __builtin_amdgcn_mfma_f32_32x32x16_bf16(BC8(pa0), BC8(va), acc0, 0, 0, 0);
  acc0 = __builtin_amdgcn_mfma_f32_32x32x16_bf16(BC8(pa1), BC8(vb), acc0, 0, 0, 0);
  acc1 = __builtin_amdgcn_mfma_f32_32x32x16_bf16(BC8(pa0), BC8(vc), acc1, 0, 0, 0);
  acc1 = __builtin_amdgcn_mfma_f32_32x32x16_bf16(BC8(pa1), BC8(vd), acc1, 0, 0, 0);
}

__device__ __forceinline__ bool bias_needed(int kt, int qt) {
  const int kmin = (kt * 32 >= S_) ? 1 : 0;
  const int kmax = (kt * 32 + 31 >= S_) ? 1 : 0;
  const int qmin = (qt * 32 >= S_) ? 1 : 0;
  const int qmax = (qt * 32 + 31 >= S_) ? 1 : 0;
  return (kmin <= qmax) && (qmin <= kmax);
}

__global__ __launch_bounds__(128) void attn_mfma(
    const unsigned short* __restrict__ Qp2, const unsigned short* __restrict__ Kp2a,
    const unsigned short* __restrict__ VpT,
    unsigned short* __restrict__ Abf) {
  __shared__ float red_acc[32][64];
  __shared__ float red_ml[2][2][32];

  const int id0 = blockIdx.x;                  // 1176 = 8 * 147
  const int swz = (id0 & 7) * 147 + (id0 >> 3);
  const int qt = swz % 49;
  const int bh = swz / 49;

  const int lane = threadIdx.x & 63;
  const int wv = threadIdx.x >> 6;             // 0,1
  const int lo = lane & 31, hi = lane >> 5;
  const int q0 = qt * 32;

  const unsigned short* qrow = Qp2 + ((size_t)bh * L_ + q0 + lo) * DP_ + hi * 8;
  u32x4 qf[4];
  #pragma unroll
  for (int c = 0; c < 4; ++c) qf[c] = *(const u32x4*)(qrow + c * 16);
  const unsigned short* qbias = qrow + 64;

  const unsigned short* kbase = Kp2a + ((size_t)bh * L_ + lo) * 64 + hi * 8;
  const unsigned short* vbase0 = VpT + (size_t)bh * 64 * L_ + (size_t)lo * L_ + hi * 8;

  f32x16 acc0 = {}, acc1 = {};
  float m_run = -1e30f, l_run = 0.f;
  const int nt = 25 - wv;                      // wave wv: kt = wv + 2*i

  u32x4 ck0, ck1, ck2, ck3;
  u32x4 nk0, nk1, nk2, nk3;
  load_k(kbase, wv, ck0, ck1, ck2, ck3);
  int i = 0;
  for (; i + 2 <= nt; i += 2) {
    const int ktA = wv + 2 * i, ktB = ktA + 2;
    load_k(kbase, ktB, nk0, nk1, nk2, nk3);
    if (bias_needed(ktA, qt))
      proc_tile<true>(ktA, lo, hi, qf, qbias, vbase0, ck0, ck1, ck2, ck3, acc0, acc1, m_run, l_run);
    else
      proc_tile<false>(ktA, lo, hi, qf, qbias, vbase0, ck0, ck1, ck2, ck3, acc0, acc1, m_run, l_run);
    const int ktC = wv + 2 * ((i + 2 < nt) ? i + 2 : nt - 1);
    load_k(kbase, ktC, ck0, ck1, ck2, ck3);
    if (bias_needed(ktB, qt))
      proc_tile<true>(ktB, lo, hi, qf, qbias, vbase0, nk0, nk1, nk2, nk3, acc0, acc1, m_run, l_run);
    else
      proc_tile<false>(ktB, lo, hi, qf, qbias, vbase0, nk0, nk1, nk2, nk3, acc0, acc1, m_run, l_run);
  }
  if (i < nt) {
    const int ktA = wv + 2 * i;
    if (bias_needed(ktA, qt))
      proc_tile<true>(ktA, lo, hi, qf, qbias, vbase0, ck0, ck1, ck2, ck3, acc0, acc1, m_run, l_run);
    else
      proc_tile<false>(ktA, lo, hi, qf, qbias, vbase0, ck0, ck1, ck2, ck3, acc0, acc1, m_run, l_run);
  }

  // merge the two waves' partial states
  if (hi == 0) { red_ml[wv][0][lo] = m_run; red_ml[wv][1][lo] = l_run; }
  if (wv == 1) {
    #pragma unroll
    for (int r = 0; r < 16; ++r) {
      const int row = (r & 3) + 8*(r >> 2) + 4*hi;
      red_acc[row][lo]      = acc0[r];
      red_acc[row][32 + lo] = acc1[r];
    }
  }
  __syncthreads();
  if (wv == 0) {
    const int b = bh / NH_, h = bh % NH_;
    #pragma unroll
    for (int r = 0; r < 16; ++r) {
      const int row = (r & 3) + 8*(r >> 2) + 4*hi;
      const float m0 = red_ml[0][0][row], l0 = red_ml[0][1][row];
      const float m1 = red_ml[1][0][row], l1 = red_ml[1][1][row];
      const float M = fmaxf(m0, m1);
      const float w0 = exp2f(m0 - M), w1 = exp2f(m1 - M);
      const float inv = 1.0f / (l0 * w0 + l1 * w1);
      const float o0 = (acc0[r] * w0 + red_acc[row][lo] * w1) * inv;
      const float o1 = (acc1[r] * w0 + red_acc[row][32 + lo] * w1) * inv;
      const size_t qoff = ((size_t)bh * L_ + q0 + row) * DP_ + lo;
      const size_t ooff = ((size_t)(b * L_ + q0 + row)) * C_ + h * 64 + lo;
      Abf[ooff]      = f2bf(o0 + bf2f(Qp2[qoff]));
      Abf[ooff + 32] = f2bf(o1 + bf2f(Qp2[qoff + 32]));
    }
  }
}

// ---------------------------------------------------------------------------
extern "C" void kernel_launch(void* const* d_in, const int* in_sizes, int n_in,
                              void* d_out, int out_size, void* d_ws, size_t ws_size,
                              hipStream_t stream) {
  const float* x         = (const float*)d_in[0];
  const float* qkv_w     = (const float*)d_in[1];
  const float* out_w     = (const float*)d_in[2];
  const float* out_b     = (const float*)d_in[3];
  const float* q_pool_w  = (const float*)d_in[4];
  const float* k_pool_w  = (const float*)d_in[5];
  const float* v_pool_w  = (const float*)d_in[6];
  const float* q_ln_g    = (const float*)d_in[7];
  const float* q_ln_b    = (const float*)d_in[8];
  const float* k_ln_g    = (const float*)d_in[9];
  const float* k_ln_b    = (const float*)d_in[10];
  const float* v_ln_g    = (const float*)d_in[11];
  const float* v_ln_b    = (const float*)d_in[12];
  const float* rel_pos_h = (const float*)d_in[13];
  const float* rel_pos_w = (const float*)d_in[14];

  float* R = (float*)d_ws;
  const size_t NQ = (size_t)B_ * NH_ * L_ * HD_;   // 2,408,448 f32 slots
  // region map (f32 slots), no live overlaps:
  // A [0,NQ): q_raw -> Abf (1,228,800)     B [NQ,2NQ): k_raw -> VpT (1,204,224)
  // C [2NQ,3NQ): v_raw
  // D [3NQ,+3,311,616): Xbf (1,228,800) -> Qp2
  // E: Kp2a (1,204,224)                    F: Wbf (884,736) -> Vtmp (1,204,224)
  // G: Wobf (294,912)
  float* q_raw = R;
  unsigned short* Abf = (unsigned short*)R;
  float* k_raw = R + NQ;
  unsigned short* VpT = (unsigned short*)(R + NQ);
  float* v_raw = R + 2*NQ;
  const size_t D_off = 3*NQ;
  unsigned short* Xbf = (unsigned short*)(R + D_off);
  unsigned short* Qp2 = (unsigned short*)(R + D_off);
  const size_t E_off = D_off + 3311616;
  unsigned short* Kp2a = (unsigned short*)(R + E_off);
  const size_t F_off = E_off + 1204224;
  unsigned short* Wbf  = (unsigned short*)(R + F_off);
  unsigned short* Vtmp = (unsigned short*)(R + F_off);
  const size_t G_off = F_off + 1204224;
  unsigned short* Wobf = (unsigned short*)(R + G_off);

  cvt_bf16<<<1200, 256, 0, stream>>>(x, Xbf, 3136*768, 3200*768);
  cvt_bf16<<<864, 256, 0, stream>>>(qkv_w, Wbf, 2304*768, 2304*768);
  cvt_bf16<<<288, 256, 0, stream>>>(out_w, Wobf, 768*768, 768*768);
  qkv_gemm_mfma<<<dim3(18, 25), 256, 0, stream>>>(Xbf, Wbf, q_raw, k_raw, v_raw);
  pool_ln_fused<<<dim3(9408, 3), 256, 0, stream>>>(
      q_raw, k_raw, v_raw, q_pool_w, k_pool_w, v_pool_w,
      q_ln_g, q_ln_b, k_ln_g, k_ln_b, v_ln_g, v_ln_b, Qp2, Kp2a, Vtmp);
  cvt_bf16<<<24, 256, 0, stream>>>(nullptr, Abf + 3136*768, 0, 64*768);  // pad rows
  transpose_v<<<dim3(49, 24), 256, 0, stream>>>(Vtmp, VpT);
  relpos_fused<<<4116, 256, 0, stream>>>(Qp2, rel_pos_h, rel_pos_w, Qp2);
  attn_mfma<<<1176, 128, 0, stream>>>(Qp2, Kp2a, VpT, Abf);
  proj_gemm_mfma<<<dim3(6, 25), 256, 0, stream>>>(Abf, Wobf, out_b, (float*)d_out);
}

// Round 8
// 244.752 us; speedup vs baseline: 1.1858x; 1.0556x over previous
//
#include <hip/hip_runtime.h>
#include <math.h>

#define B_ 2
#define T_ 2
#define H_ 28
#define W_ 28
#define S_ (H_*W_)      /* 784  */
#define L_ (T_*S_)      /* 1568 */
#define C_ 768
#define NH_ 12
#define HD_ 64
#define LN_EPS 1e-5f
#define LOG2E 1.4426950408889634f
#define SCALE_K (0.125f * LOG2E)   /* hd^-0.5 * log2e folded into K' */
#define DP_ 176                     /* augmented head dim: 64 + 2*2*28 */

typedef unsigned int uint_;
typedef unsigned int u32x4 __attribute__((ext_vector_type(4)));
typedef __bf16 bf16x8 __attribute__((ext_vector_type(8)));
typedef float f32x4 __attribute__((ext_vector_type(4)));
typedef float f32x16 __attribute__((ext_vector_type(16)));

#define BC8(x) __builtin_bit_cast(bf16x8, (x))

__device__ __forceinline__ unsigned short f2bf(float f) {
  uint_ u = __builtin_bit_cast(uint_, f);
  u += 0x7FFFu + ((u >> 16) & 1u);
  return (unsigned short)(u >> 16);
}
__device__ __forceinline__ float bf2f(unsigned short h) {
  return __builtin_bit_cast(float, ((uint_)h) << 16);
}
__device__ __forceinline__ float bflo(uint_ u) {
  return __builtin_bit_cast(float, u << 16);
}
__device__ __forceinline__ float bfhi(uint_ u) {
  return __builtin_bit_cast(float, u & 0xFFFF0000u);
}
__device__ __forceinline__ uint_ cvtpk(float a, float b) {
  uint_ r;
  asm("v_cvt_pk_bf16_f32 %0, %1, %2" : "=v"(r) : "v"(a), "v"(b));
  return r;
}
__device__ __forceinline__ void gload16(const void* g, void* l) {
  __builtin_amdgcn_global_load_lds(
      (const __attribute__((address_space(1))) unsigned int*)g,
      (__attribute__((address_space(3))) unsigned int*)l, 16, 0, 0);
}

// ---------------------------------------------------------------------------
// Fused f32 -> bf16 convert for x / qkv_w / out_w (range-dispatched)
// ---------------------------------------------------------------------------
__global__ __launch_bounds__(256) void cvt_all(
    const float* __restrict__ s0, int n0, unsigned short* __restrict__ d0,
    const float* __restrict__ s1, int n1, unsigned short* __restrict__ d1,
    const float* __restrict__ s2, int n2, unsigned short* __restrict__ d2) {
  int i = (blockIdx.x * 256 + threadIdx.x) * 8;
  const float* s; unsigned short* d;
  if (i < n0) { s = s0; d = d0; }
  else if (i < n0 + n1) { i -= n0; s = s1; d = d1; }
  else { i -= n0 + n1; if (i >= n2) return; s = s2; d = d2; }
  float4 a = *(const float4*)(s + i);
  float4 b = *(const float4*)(s + i + 4);
  u32x4 o;
  o.x = cvtpk(a.x, a.y); o.y = cvtpk(a.z, a.w);
  o.z = cvtpk(b.x, b.y); o.w = cvtpk(b.z, b.w);
  *(u32x4*)(d + i) = o;
}

// ---------------------------------------------------------------------------
// bf16 MFMA GEMM core: C = A * B^T, 128x128 tile, BK=32, 4 waves
// ---------------------------------------------------------------------------
__device__ __forceinline__ void gemm_core(
    const unsigned short* __restrict__ A, const unsigned short* __restrict__ Bm,
    int K, int m0, int n0, f32x4 (&acc)[4][4]) {
  __shared__ __align__(16) unsigned short As[128 * 32];
  __shared__ __align__(16) unsigned short Bs[128 * 32];
  const int tid = threadIdx.x;
  const int lane = tid & 63;
  const int wv = tid >> 6;
  const int wm = wv >> 1, wn = wv & 1;
  const int srow = tid >> 2, scol = (tid & 3) * 8;
  const int fr = lane & 15, fk = (lane >> 4) * 8;
  const unsigned short* ag = A + (size_t)(m0 + srow) * K + scol;
  const unsigned short* bg = Bm + (size_t)(n0 + srow) * K + scol;
  unsigned short* asd = As + tid * 8;
  unsigned short* bsd = Bs + tid * 8;
  const int arow = wm * 64 + fr;
  const int brow = wn * 64 + fr;
  for (int k0 = 0; k0 < K; k0 += 32) {
    __syncthreads();
    gload16(ag + k0, asd);
    gload16(ag + (size_t)64 * K + k0, asd + 2048);
    gload16(bg + k0, bsd);
    gload16(bg + (size_t)64 * K + k0, bsd + 2048);
    __syncthreads();
    bf16x8 af[4], bfr[4];
    #pragma unroll
    for (int m = 0; m < 4; ++m)
      af[m] = *(const bf16x8*)(As + (arow + m * 16) * 32 + fk);
    #pragma unroll
    for (int n = 0; n < 4; ++n)
      bfr[n] = *(const bf16x8*)(Bs + (brow + n * 16) * 32 + fk);
    #pragma unroll
    for (int m = 0; m < 4; ++m)
      #pragma unroll
      for (int n = 0; n < 4; ++n)
        acc[m][n] = __builtin_amdgcn_mfma_f32_16x16x32_bf16(af[m], bfr[n], acc[m][n], 0, 0, 0);
  }
}

// ---------------------------------------------------------------------------
// QKV GEMM: Xbf[3200][768] * Wbf[2304][768]^T -> scatter f32 q/k/v [B,NH,L,HD]
// ---------------------------------------------------------------------------
__global__ __launch_bounds__(256) void qkv_gemm_mfma(
    const unsigned short* __restrict__ Xbf, const unsigned short* __restrict__ Wbf,
    float* __restrict__ q_raw, float* __restrict__ k_raw, float* __restrict__ v_raw) {
  f32x4 acc[4][4] = {};
  const int m0 = blockIdx.y * 128;
  const int n0 = blockIdx.x * 128;
  gemm_core(Xbf, Wbf, C_, m0, n0, acc);
  const int lane = threadIdx.x & 63;
  const int wv = threadIdx.x >> 6;
  const int wm = wv >> 1, wn = wv & 1;
  const int fr = lane & 15, fj = (lane >> 4) * 4;
  #pragma unroll
  for (int n = 0; n < 4; ++n) {
    const int gn = n0 + wn * 64 + n * 16 + fr;
    const int which = (gn >= 2 * C_) ? 2 : ((gn >= C_) ? 1 : 0);
    const int rem = gn - which * C_;
    const int h = rem >> 6, d = rem & 63;
    float* dst = (which == 0) ? q_raw : ((which == 1) ? k_raw : v_raw);
    #pragma unroll
    for (int m = 0; m < 4; ++m) {
      #pragma unroll
      for (int j = 0; j < 4; ++j) {
        const int gm = m0 + wm * 64 + m * 16 + fj + j;
        if (gm < B_ * L_) {
          const int b = (gm >= L_) ? 1 : 0;
          const int l = gm - b * L_;
          dst[(((size_t)b * NH_ + h) * L_ + l) * HD_ + d] = acc[m][n][j];
        }
      }
    }
  }
}

// ---------------------------------------------------------------------------
// Proj GEMM: Abf[3200][768] * Wobf[768][768]^T + bo -> d_out f32
// ---------------------------------------------------------------------------
__global__ __launch_bounds__(256) void proj_gemm_mfma(
    const unsigned short* __restrict__ Abf, const unsigned short* __restrict__ Wobf,
    const float* __restrict__ bo, float* __restrict__ out) {
  f32x4 acc[4][4] = {};
  const int m0 = blockIdx.y * 128;
  const int n0 = blockIdx.x * 128;
  gemm_core(Abf, Wobf, C_, m0, n0, acc);
  const int lane = threadIdx.x & 63;
  const int wv = threadIdx.x >> 6;
  const int wm = wv >> 1, wn = wv & 1;
  const int fr = lane & 15, fj = (lane >> 4) * 4;
  #pragma unroll
  for (int n = 0; n < 4; ++n) {
    const int gn = n0 + wn * 64 + n * 16 + fr;
    const float bias = bo[gn];
    #pragma unroll
    for (int m = 0; m < 4; ++m) {
      #pragma unroll
      for (int j = 0; j < 4; ++j) {
        const int gm = m0 + wm * 64 + m * 16 + fj + j;
        if (gm < B_ * L_) out[(size_t)gm * C_ + gn] = acc[m][n][j] + bias;
      }
    }
  }
}

// ---------------------------------------------------------------------------
// Fused depthwise 3x3 conv + LayerNorm(64) for q/k/v (blockIdx.y selects)
// ---------------------------------------------------------------------------
__global__ __launch_bounds__(256) void pool_ln_fused(
    const float* __restrict__ q_raw, const float* __restrict__ k_raw,
    const float* __restrict__ v_raw,
    const float* __restrict__ qw, const float* __restrict__ kw,
    const float* __restrict__ vw,
    const float* __restrict__ qg, const float* __restrict__ qb2,
    const float* __restrict__ kg, const float* __restrict__ kb2,
    const float* __restrict__ vg, const float* __restrict__ vb2,
    unsigned short* __restrict__ Qp2, unsigned short* __restrict__ Kp2a,
    unsigned short* __restrict__ Vtmp) {
  const int which = blockIdx.y;
  const float* in = (which == 0) ? q_raw : (which == 1) ? k_raw : v_raw;
  const float* w  = (which == 0) ? qw : (which == 1) ? kw : vw;
  const float* g  = (which == 0) ? qg : (which == 1) ? kg : vg;
  const float* bb = (which == 0) ? qb2 : (which == 1) ? kb2 : vb2;
  unsigned short* out = (which == 0) ? Qp2 : (which == 1) ? Kp2a : Vtmp;
  const int stride = (which == 0) ? DP_ : 64;
  const float scale = (which == 1) ? SCALE_K : 1.f;

  const int row = blockIdx.x * 4 + (threadIdx.x >> 6);
  const int d = threadIdx.x & 63;
  const int bh = row / L_;
  const int l  = row % L_;
  const int t  = l / S_;
  const int sq = l % S_;
  const int x = sq / W_, y = sq % W_;
  const float* base = in + ((size_t)bh * L_ + t * S_) * HD_;
  float acc = 0.f;
  #pragma unroll
  for (int dx = 0; dx < 3; ++dx) {
    const int xx = x + dx - 1;
    if (xx < 0 || xx >= H_) continue;
    #pragma unroll
    for (int dy = 0; dy < 3; ++dy) {
      const int yy = y + dy - 1;
      if (yy < 0 || yy >= W_) continue;
      acc += base[(size_t)(xx * W_ + yy) * HD_ + d] * w[(dx * 3 + dy) * HD_ + d];
    }
  }
  float s = acc;
  #pragma unroll
  for (int off = 32; off; off >>= 1) s += __shfl_xor(s, off);
  const float mu = s * (1.f / 64.f);
  const float dv = acc - mu;
  float s2 = dv * dv;
  #pragma unroll
  for (int off = 32; off; off >>= 1) s2 += __shfl_xor(s2, off);
  const float var = s2 * (1.f / 64.f);
  const float val = dv * rsqrtf(var + LN_EPS) * g[d] + bb[d];
  out[(size_t)row * stride + d] = f2bf(val * scale);
}

// ---------------------------------------------------------------------------
// Transpose V per head: Vtmp [bh][L][64] bf16 -> VpT [bh][64][L] bf16
// ---------------------------------------------------------------------------
__global__ __launch_bounds__(256) void transpose_v(
    const unsigned short* __restrict__ Vtmp, unsigned short* __restrict__ VpT) {
  __shared__ unsigned short tile[32][72];
  const int bh = blockIdx.y;
  const int l0 = blockIdx.x * 32;
  const int t = threadIdx.x;
  {
    const int r = t >> 3, c8 = (t & 7) * 8;
    u32x4 v = *(const u32x4*)(Vtmp + ((size_t)bh * L_ + l0 + r) * 64 + c8);
    *(u32x4*)&tile[r][c8] = v;
  }
  __syncthreads();
  const int d = t >> 2, gq = t & 3;
  unsigned short o[8];
  #pragma unroll
  for (int i = 0; i < 8; ++i) o[i] = tile[gq*8 + i][d];
  u32x4 ov;
  ov.x = (uint_)o[0] | ((uint_)o[1] << 16);
  ov.y = (uint_)o[2] | ((uint_)o[3] << 16);
  ov.z = (uint_)o[4] | ((uint_)o[5] << 16);
  ov.w = (uint_)o[6] | ((uint_)o[7] << 16);
  *(u32x4*)(VpT + ((size_t)bh * 64 + d) * L_ + l0 + gq*8) = ov;
}

// ---------------------------------------------------------------------------
// rel-pos rows -> Qp2 dims 64..175 (log2e-scaled; other T-block zeroed)
// ---------------------------------------------------------------------------
__global__ void relpos_fused(
    const unsigned short* __restrict__ Qp2r, const float* __restrict__ rph,
    const float* __restrict__ rpw, unsigned short* __restrict__ Qp2) {
  const int idx = blockIdx.x * blockDim.x + threadIdx.x;
  const int k = idx % H_;
  const int rest = idx / H_;            // bh*L + t*S + sq
  const int sq = rest % S_;
  const int t = (rest % L_) / S_;
  const int x = sq / W_, y = sq % W_;
  const unsigned short* qrow = Qp2r + (size_t)rest * DP_;
  const float* rh = rph + (x - k + H_ - 1) * HD_;
  const float* rw = rpw + (y - k + W_ - 1) * HD_;
  float ah = 0.f, aw = 0.f;
  #pragma unroll
  for (int c = 0; c < HD_; c += 8) {
    u32x4 qv = *(const u32x4*)(qrow + c);
    float4 h0 = *(const float4*)(rh + c);
    float4 h1 = *(const float4*)(rh + c + 4);
    float4 w0 = *(const float4*)(rw + c);
    float4 w1 = *(const float4*)(rw + c + 4);
    const float q0 = bflo(qv.x), q1 = bfhi(qv.x), q2 = bflo(qv.y), q3 = bfhi(qv.y);
    const float q4 = bflo(qv.z), q5 = bfhi(qv.z), q6 = bflo(qv.w), q7 = bfhi(qv.w);
    ah += q0*h0.x + q1*h0.y + q2*h0.z + q3*h0.w + q4*h1.x + q5*h1.y + q6*h1.z + q7*h1.w;
    aw += q0*w0.x + q1*w0.y + q2*w0.z + q3*w0.w + q4*w1.x + q5*w1.y + q6*w1.z + q7*w1.w;
  }
  unsigned short* qd = Qp2 + (size_t)rest * DP_;
  qd[64 + t*56 + k]        = f2bf(ah * LOG2E);
  qd[64 + t*56 + 28 + k]   = f2bf(aw * LOG2E);
  qd[64 + (1-t)*56 + k]      = 0;
  qd[64 + (1-t)*56 + 28 + k] = 0;
}

// ---------------------------------------------------------------------------
// MFMA flash attention. 256 thr (4 waves), grid 1176 (XCD-swizzled).
// Stride-4 KV interleave; K double-buffered in regs, V single-buffered
// (loaded under softmax); bias Q-fragments loaded per bias tile (L1-hot).
// ---------------------------------------------------------------------------
__device__ __forceinline__ void load_k(
    const unsigned short* kbase, int kt,
    u32x4& k0, u32x4& k1, u32x4& k2, u32x4& k3) {
  const unsigned short* kr = kbase + (size_t)kt * 2048;
  k0 = *(const u32x4*)(kr);
  k1 = *(const u32x4*)(kr + 16);
  k2 = *(const u32x4*)(kr + 32);
  k3 = *(const u32x4*)(kr + 48);
}

template<bool BIAS>
__device__ __forceinline__ void proc_tile(
    int kt, int lo, int hi, const u32x4 (&qf)[4],
    const unsigned short* __restrict__ qbias,   // Qp2 row + 64, this lane
    const unsigned short* __restrict__ vbase0,
    u32x4 k0, u32x4 k1, u32x4 k2, u32x4 k3,
    f32x16& acc0, f32x16& acc1, float& m_run, float& l_run) {
  f32x16 s = {};
  s = __builtin_amdgcn_mfma_f32_32x32x16_bf16(BC8(k0), BC8(qf[0]), s, 0, 0, 0);
  s = __builtin_amdgcn_mfma_f32_32x32x16_bf16(BC8(k1), BC8(qf[1]), s, 0, 0, 0);
  s = __builtin_amdgcn_mfma_f32_32x32x16_bf16(BC8(k2), BC8(qf[2]), s, 0, 0, 0);
  s = __builtin_amdgcn_mfma_f32_32x32x16_bf16(BC8(k3), BC8(qf[3]), s, 0, 0, 0);
  if (BIAS) {
    // one-hot K' fragment built in-register; bias Q-fragments from L1-hot mem
    const int kr = kt * 32 + lo;
    const int t = (kr >= S_) ? 1 : 0;
    const int sk = kr - t * S_;
    const int x = sk / W_, y = sk - x * W_;
    const int p1 = 64 + t*56 + x;
    const int p2 = 64 + t*56 + 28 + y;
    const uint_ v1 = 0x3F80u << ((p1 & 1) << 4);
    const uint_ v2 = 0x3F80u << ((p2 & 1) << 4);
    const int g1 = p1 >> 3, g2 = p2 >> 3;
    const int w1 = (p1 >> 1) & 3, w2 = (p2 >> 1) & 3;
    #pragma unroll
    for (int c = 4; c < 11; ++c) {
      const int gg = 2*c + hi;
      u32x4 oh;
      oh.x = ((g1 == gg && w1 == 0) ? v1 : 0u) | ((g2 == gg && w2 == 0) ? v2 : 0u);
      oh.y = ((g1 == gg && w1 == 1) ? v1 : 0u) | ((g2 == gg && w2 == 1) ? v2 : 0u);
      oh.z = ((g1 == gg && w1 == 2) ? v1 : 0u) | ((g2 == gg && w2 == 2) ? v2 : 0u);
      oh.w = ((g1 == gg && w1 == 3) ? v1 : 0u) | ((g2 == gg && w2 == 3) ? v2 : 0u);
      const u32x4 qb = *(const u32x4*)(qbias + (c - 4) * 16);
      s = __builtin_amdgcn_mfma_f32_32x32x16_bf16(BC8(oh), BC8(qb), s, 0, 0, 0);
    }
  }

  // issue V loads now — consumed after softmax (latency hidden under VALU)
  const unsigned short* vr = vbase0 + kt * 32;
  const u32x4 va = *(const u32x4*)(vr);
  const u32x4 vb = *(const u32x4*)(vr + 16);
  const u32x4 vc = *(const u32x4*)(vr + 32 * L_);
  const u32x4 vd = *(const u32x4*)(vr + 32 * L_ + 16);

  // pairwise max tree
  float m01 = fmaxf(s[0], s[1]),  m23 = fmaxf(s[2], s[3]);
  float m45 = fmaxf(s[4], s[5]),  m67 = fmaxf(s[6], s[7]);
  float m89 = fmaxf(s[8], s[9]),  mab = fmaxf(s[10], s[11]);
  float mcd = fmaxf(s[12], s[13]), mef = fmaxf(s[14], s[15]);
  float pmax = fmaxf(fmaxf(fmaxf(m01, m23), fmaxf(m45, m67)),
                     fmaxf(fmaxf(m89, mab), fmaxf(mcd, mef)));
  pmax = fmaxf(pmax, __shfl_xor(pmax, 32));
  if (__any(pmax > m_run + 8.f)) {            // defer-max (log2 units)
    const float mn = fmaxf(m_run, pmax);
    const float f = exp2f(m_run - mn);
    m_run = mn; l_run *= f;
    #pragma unroll
    for (int r = 0; r < 16; ++r) {
      const float fr = __shfl(f, (r & 3) + 8*(r >> 2) + 4*hi);
      acc0[r] *= fr; acc1[r] *= fr;
    }
  }
  float ps = 0.f;
  uint_ pw0, pw1, pw2, pw3, pw4, pw5, pw6, pw7;
  {
    float a, b;
    a = exp2f(s[0]-m_run);  b = exp2f(s[1]-m_run);  ps += a+b; pw0 = cvtpk(a,b);
    a = exp2f(s[2]-m_run);  b = exp2f(s[3]-m_run);  ps += a+b; pw1 = cvtpk(a,b);
    a = exp2f(s[4]-m_run);  b = exp2f(s[5]-m_run);  ps += a+b; pw2 = cvtpk(a,b);
    a = exp2f(s[6]-m_run);  b = exp2f(s[7]-m_run);  ps += a+b; pw3 = cvtpk(a,b);
    a = exp2f(s[8]-m_run);  b = exp2f(s[9]-m_run);  ps += a+b; pw4 = cvtpk(a,b);
    a = exp2f(s[10]-m_run); b = exp2f(s[11]-m_run); ps += a+b; pw5 = cvtpk(a,b);
    a = exp2f(s[12]-m_run); b = exp2f(s[13]-m_run); ps += a+b; pw6 = cvtpk(a,b);
    a = exp2f(s[14]-m_run); b = exp2f(s[15]-m_run); ps += a+b; pw7 = cvtpk(a,b);
  }
  ps += __shfl_xor(ps, 32);
  l_run += ps;

  auto sA = __builtin_amdgcn_permlane32_swap(pw0, pw2, false, false);
  auto sB = __builtin_amdgcn_permlane32_swap(pw1, pw3, false, false);
  auto sC = __builtin_amdgcn_permlane32_swap(pw4, pw6, false, false);
  auto sD = __builtin_amdgcn_permlane32_swap(pw5, pw7, false, false);
  u32x4 pa0, pa1;
  pa0.x = sA[0]; pa0.y = sB[0]; pa0.z = sA[1]; pa0.w = sB[1];
  pa1.x = sC[0]; pa1.y = sD[0]; pa1.z = sC[1]; pa1.w = sD[1];

  acc0 = __builtin_amdgcn_mfma_f32_32x32x16_bf16(BC8(pa0), BC8(va), acc0, 0, 0, 0);
  acc0 = __builtin_amdgcn_mfma_f32_32x32x16_bf16(BC8(pa1), BC8(vb), acc0, 0, 0, 0);
  acc1 = __builtin_amdgcn_mfma_f32_32x32x16_bf16(BC8(pa0), BC8(vc), acc1, 0, 0, 0);
  acc1 = __builtin_amdgcn_mfma_f32_32x32x16_bf16(BC8(pa1), BC8(vd), acc1, 0, 0, 0);
}

__device__ __forceinline__ bool bias_needed(int kt, int qt) {
  const int kmin = (kt * 32 >= S_) ? 1 : 0;
  const int kmax = (kt * 32 + 31 >= S_) ? 1 : 0;
  const int qmin = (qt * 32 >= S_) ? 1 : 0;
  const int qmax = (qt * 32 + 31 >= S_) ? 1 : 0;
  return (kmin <= qmax) && (qmin <= kmax);
}

__global__ __launch_bounds__(256) void attn_mfma(
    const unsigned short* __restrict__ Qp2, const unsigned short* __restrict__ Kp2a,
    const unsigned short* __restrict__ VpT,
    unsigned short* __restrict__ Abf) {
  __shared__ float red_acc[3][32][64];
  __shared__ float red_ml[4][2][32];

  const int id0 = blockIdx.x;                  // 1176 = 8 * 147
  const int swz = (id0 & 7) * 147 + (id0 >> 3);
  const int qt = swz % 49;
  const int bh = swz / 49;

  const int lane = threadIdx.x & 63;
  const int wv = threadIdx.x >> 6;             // 0..3
  const int lo = lane & 31, hi = lane >> 5;
  const int q0 = qt * 32;

  const unsigned short* qrow = Qp2 + ((size_t)bh * L_ + q0 + lo) * DP_ + hi * 8;
  u32x4 qf[4];
  #pragma unroll
  for (int c = 0; c < 4; ++c) qf[c] = *(const u32x4*)(qrow + c * 16);
  const unsigned short* qbias = qrow + 64;

  const unsigned short* kbase = Kp2a + ((size_t)bh * L_ + lo) * 64 + hi * 8;
  const unsigned short* vbase0 = VpT + (size_t)bh * 64 * L_ + (size_t)lo * L_ + hi * 8;

  f32x16 acc0 = {}, acc1 = {};
  float m_run = -1e30f, l_run = 0.f;
  const int nt = (49 - wv + 3) >> 2;           // wave wv: kt = wv + 4*i

  u32x4 ck0, ck1, ck2, ck3;
  u32x4 nk0, nk1, nk2, nk3;
  load_k(kbase, wv, ck0, ck1, ck2, ck3);
  int i = 0;
  for (; i + 2 <= nt; i += 2) {
    const int ktA = wv + 4 * i, ktB = ktA + 4;
    load_k(kbase, ktB, nk0, nk1, nk2, nk3);
    if (bias_needed(ktA, qt))
      proc_tile<true>(ktA, lo, hi, qf, qbias, vbase0, ck0, ck1, ck2, ck3, acc0, acc1, m_run, l_run);
    else
      proc_tile<false>(ktA, lo, hi, qf, qbias, vbase0, ck0, ck1, ck2, ck3, acc0, acc1, m_run, l_run);
    const int ktC = wv + 4 * ((i + 2 < nt) ? i + 2 : nt - 1);
    load_k(kbase, ktC, ck0, ck1, ck2, ck3);
    if (bias_needed(ktB, qt))
      proc_tile<true>(ktB, lo, hi, qf, qbias, vbase0, nk0, nk1, nk2, nk3, acc0, acc1, m_run, l_run);
    else
      proc_tile<false>(ktB, lo, hi, qf, qbias, vbase0, nk0, nk1, nk2, nk3, acc0, acc1, m_run, l_run);
  }
  if (i < nt) {
    const int ktA = wv + 4 * i;
    if (bias_needed(ktA, qt))
      proc_tile<true>(ktA, lo, hi, qf, qbias, vbase0, ck0, ck1, ck2, ck3, acc0, acc1, m_run, l_run);
    else
      proc_tile<false>(ktA, lo, hi, qf, qbias, vbase0, ck0, ck1, ck2, ck3, acc0, acc1, m_run, l_run);
  }

  // merge the 4 waves' partial states
  if (hi == 0) { red_ml[wv][0][lo] = m_run; red_ml[wv][1][lo] = l_run; }
  if (wv >= 1) {
    #pragma unroll
    for (int r = 0; r < 16; ++r) {
      const int row = (r & 3) + 8*(r >> 2) + 4*hi;
      red_acc[wv-1][row][lo]      = acc0[r];
      red_acc[wv-1][row][32 + lo] = acc1[r];
    }
  }
  __syncthreads();
  if (wv == 0) {
    const int b = bh / NH_, h = bh % NH_;
    #pragma unroll
    for (int r = 0; r < 16; ++r) {
      const int row = (r & 3) + 8*(r >> 2) + 4*hi;
      const float m0 = red_ml[0][0][row], l0 = red_ml[0][1][row];
      const float m1 = red_ml[1][0][row], l1 = red_ml[1][1][row];
      const float m2 = red_ml[2][0][row], l2 = red_ml[2][1][row];
      const float m3 = red_ml[3][0][row], l3 = red_ml[3][1][row];
      const float M = fmaxf(fmaxf(m0, m1), fmaxf(m2, m3));
      const float w0 = exp2f(m0 - M), w1 = exp2f(m1 - M);
      const float w2 = exp2f(m2 - M), w3 = exp2f(m3 - M);
      const float inv = 1.0f / (l0*w0 + l1*w1 + l2*w2 + l3*w3);
      const float o0 = (acc0[r]*w0 + red_acc[0][row][lo]*w1 +
                        red_acc[1][row][lo]*w2 + red_acc[2][row][lo]*w3) * inv;
      const float o1 = (acc1[r]*w0 + red_acc[0][row][32+lo]*w1 +
                        red_acc[1][row][32+lo]*w2 + red_acc[2][row][32+lo]*w3) * inv;
      const size_t qoff = ((size_t)bh * L_ + q0 + row) * DP_ + lo;
      const size_t ooff = ((size_t)(b * L_ + q0 + row)) * C_ + h * 64 + lo;
      Abf[ooff]      = f2bf(o0 + bf2f(Qp2[qoff]));
      Abf[ooff + 32] = f2bf(o1 + bf2f(Qp2[qoff + 32]));
    }
  }
}

// ---------------------------------------------------------------------------
extern "C" void kernel_launch(void* const* d_in, const int* in_sizes, int n_in,
                              void* d_out, int out_size, void* d_ws, size_t ws_size,
                              hipStream_t stream) {
  const float* x         = (const float*)d_in[0];
  const float* qkv_w     = (const float*)d_in[1];
  const float* out_w     = (const float*)d_in[2];
  const float* out_b     = (const float*)d_in[3];
  const float* q_pool_w  = (const float*)d_in[4];
  const float* k_pool_w  = (const float*)d_in[5];
  const float* v_pool_w  = (const float*)d_in[6];
  const float* q_ln_g    = (const float*)d_in[7];
  const float* q_ln_b    = (const float*)d_in[8];
  const float* k_ln_g    = (const float*)d_in[9];
  const float* k_ln_b    = (const float*)d_in[10];
  const float* v_ln_g    = (const float*)d_in[11];
  const float* v_ln_b    = (const float*)d_in[12];
  const float* rel_pos_h = (const float*)d_in[13];
  const float* rel_pos_w = (const float*)d_in[14];

  float* R = (float*)d_ws;
  const size_t NQ = (size_t)B_ * NH_ * L_ * HD_;   // 2,408,448 f32 slots
  // region map (f32 slots), no live overlaps:
  // A [0,NQ): q_raw -> Abf (1,228,800)     B [NQ,2NQ): k_raw -> VpT (1,204,224)
  // C [2NQ,3NQ): v_raw
  // D [3NQ,+3,311,616): Xbf (1,228,800) -> Qp2
  // E: Kp2a (1,204,224)                    F: Wbf (884,736) -> Vtmp (1,204,224)
  // G: Wobf (294,912)
  float* q_raw = R;
  unsigned short* Abf = (unsigned short*)R;
  float* k_raw = R + NQ;
  unsigned short* VpT = (unsigned short*)(R + NQ);
  float* v_raw = R + 2*NQ;
  const size_t D_off = 3*NQ;
  unsigned short* Xbf = (unsigned short*)(R + D_off);
  unsigned short* Qp2 = (unsigned short*)(R + D_off);
  const size_t E_off = D_off + 3311616;
  unsigned short* Kp2a = (unsigned short*)(R + E_off);
  const size_t F_off = E_off + 1204224;
  unsigned short* Wbf  = (unsigned short*)(R + F_off);
  unsigned short* Vtmp = (unsigned short*)(R + F_off);
  const size_t G_off = F_off + 1204224;
  unsigned short* Wobf = (unsigned short*)(R + G_off);

  // fused f32->bf16: x (3136*768) + qkv_w (2304*768) + out_w (768*768)
  cvt_all<<<2328, 256, 0, stream>>>(x, 3136*768, Xbf,
                                    qkv_w, 2304*768, Wbf,
                                    out_w, 768*768, Wobf);
  qkv_gemm_mfma<<<dim3(18, 25), 256, 0, stream>>>(Xbf, Wbf, q_raw, k_raw, v_raw);
  pool_ln_fused<<<dim3(9408, 3), 256, 0, stream>>>(
      q_raw, k_raw, v_raw, q_pool_w, k_pool_w, v_pool_w,
      q_ln_g, q_ln_b, k_ln_g, k_ln_b, v_ln_g, v_ln_b, Qp2, Kp2a, Vtmp);
  transpose_v<<<dim3(49, 24), 256, 0, stream>>>(Vtmp, VpT);
  relpos_fused<<<4116, 256, 0, stream>>>(Qp2, rel_pos_h, rel_pos_w, Qp2);
  attn_mfma<<<1176, 256, 0, stream>>>(Qp2, Kp2a, VpT, Abf);
  proj_gemm_mfma<<<dim3(6, 25), 256, 0, stream>>>(Abf, Wobf, out_b, (float*)d_out);
}

// Round 9
// 242.657 us; speedup vs baseline: 1.1961x; 1.0086x over previous
//
#include <hip/hip_runtime.h>
#include <math.h>

#define B_ 2
#define T_ 2
#define H_ 28
#define W_ 28
#define S_ (H_*W_)      /* 784  */
#define L_ (T_*S_)      /* 1568 */
#define C_ 768
#define NH_ 12
#define HD_ 64
#define LN_EPS 1e-5f
#define LOG2E 1.4426950408889634f
#define SCALE_K (0.125f * LOG2E)   /* hd^-0.5 * log2e folded into K' */
#define DP_ 176                     /* augmented head dim: 64 + 2*2*28 */

typedef unsigned int uint_;
typedef unsigned int u32x4 __attribute__((ext_vector_type(4)));
typedef __bf16 bf16x8 __attribute__((ext_vector_type(8)));
typedef float f32x4 __attribute__((ext_vector_type(4)));
typedef float f32x16 __attribute__((ext_vector_type(16)));

#define BC8(x) __builtin_bit_cast(bf16x8, (x))

__device__ __forceinline__ unsigned short f2bf(float f) {
  uint_ u = __builtin_bit_cast(uint_, f);
  u += 0x7FFFu + ((u >> 16) & 1u);
  return (unsigned short)(u >> 16);
}
__device__ __forceinline__ float bf2f(unsigned short h) {
  return __builtin_bit_cast(float, ((uint_)h) << 16);
}
__device__ __forceinline__ float bflo(uint_ u) {
  return __builtin_bit_cast(float, u << 16);
}
__device__ __forceinline__ float bfhi(uint_ u) {
  return __builtin_bit_cast(float, u & 0xFFFF0000u);
}
__device__ __forceinline__ uint_ cvtpk(float a, float b) {
  uint_ r;
  asm("v_cvt_pk_bf16_f32 %0, %1, %2" : "=v"(r) : "v"(a), "v"(b));
  return r;
}
__device__ __forceinline__ void gload16(const void* g, void* l) {
  __builtin_amdgcn_global_load_lds(
      (const __attribute__((address_space(1))) unsigned int*)g,
      (__attribute__((address_space(3))) unsigned int*)l, 16, 0, 0);
}

// ---------------------------------------------------------------------------
// Fused f32 -> bf16 convert for x / qkv_w / out_w (range-dispatched)
// ---------------------------------------------------------------------------
__global__ __launch_bounds__(256) void cvt_all(
    const float* __restrict__ s0, int n0, unsigned short* __restrict__ d0,
    const float* __restrict__ s1, int n1, unsigned short* __restrict__ d1,
    const float* __restrict__ s2, int n2, unsigned short* __restrict__ d2) {
  int i = (blockIdx.x * 256 + threadIdx.x) * 8;
  const float* s; unsigned short* d;
  if (i < n0) { s = s0; d = d0; }
  else if (i < n0 + n1) { i -= n0; s = s1; d = d1; }
  else { i -= n0 + n1; if (i >= n2) return; s = s2; d = d2; }
  float4 a = *(const float4*)(s + i);
  float4 b = *(const float4*)(s + i + 4);
  u32x4 o;
  o.x = cvtpk(a.x, a.y); o.y = cvtpk(a.z, a.w);
  o.z = cvtpk(b.x, b.y); o.w = cvtpk(b.z, b.w);
  *(u32x4*)(d + i) = o;
}

// ---------------------------------------------------------------------------
// bf16 MFMA GEMM core: C = A * B^T, 128x128 tile, BK=32, 4 waves
// ---------------------------------------------------------------------------
__device__ __forceinline__ void gemm_core(
    const unsigned short* __restrict__ A, const unsigned short* __restrict__ Bm,
    int K, int m0, int n0, f32x4 (&acc)[4][4]) {
  __shared__ __align__(16) unsigned short As[128 * 32];
  __shared__ __align__(16) unsigned short Bs[128 * 32];
  const int tid = threadIdx.x;
  const int lane = tid & 63;
  const int wv = tid >> 6;
  const int wm = wv >> 1, wn = wv & 1;
  const int srow = tid >> 2, scol = (tid & 3) * 8;
  const int fr = lane & 15, fk = (lane >> 4) * 8;
  const unsigned short* ag = A + (size_t)(m0 + srow) * K + scol;
  const unsigned short* bg = Bm + (size_t)(n0 + srow) * K + scol;
  unsigned short* asd = As + tid * 8;
  unsigned short* bsd = Bs + tid * 8;
  const int arow = wm * 64 + fr;
  const int brow = wn * 64 + fr;
  for (int k0 = 0; k0 < K; k0 += 32) {
    __syncthreads();
    gload16(ag + k0, asd);
    gload16(ag + (size_t)64 * K + k0, asd + 2048);
    gload16(bg + k0, bsd);
    gload16(bg + (size_t)64 * K + k0, bsd + 2048);
    __syncthreads();
    bf16x8 af[4], bfr[4];
    #pragma unroll
    for (int m = 0; m < 4; ++m)
      af[m] = *(const bf16x8*)(As + (arow + m * 16) * 32 + fk);
    #pragma unroll
    for (int n = 0; n < 4; ++n)
      bfr[n] = *(const bf16x8*)(Bs + (brow + n * 16) * 32 + fk);
    #pragma unroll
    for (int m = 0; m < 4; ++m)
      #pragma unroll
      for (int n = 0; n < 4; ++n)
        acc[m][n] = __builtin_amdgcn_mfma_f32_16x16x32_bf16(af[m], bfr[n], acc[m][n], 0, 0, 0);
  }
}

// ---------------------------------------------------------------------------
// QKV GEMM: Xbf[3200][768] * Wbf[2304][768]^T -> scatter f32 q/k/v [B,NH,L,HD]
// ---------------------------------------------------------------------------
__global__ __launch_bounds__(256) void qkv_gemm_mfma(
    const unsigned short* __restrict__ Xbf, const unsigned short* __restrict__ Wbf,
    float* __restrict__ q_raw, float* __restrict__ k_raw, float* __restrict__ v_raw) {
  f32x4 acc[4][4] = {};
  const int m0 = blockIdx.y * 128;
  const int n0 = blockIdx.x * 128;
  gemm_core(Xbf, Wbf, C_, m0, n0, acc);
  const int lane = threadIdx.x & 63;
  const int wv = threadIdx.x >> 6;
  const int wm = wv >> 1, wn = wv & 1;
  const int fr = lane & 15, fj = (lane >> 4) * 4;
  #pragma unroll
  for (int n = 0; n < 4; ++n) {
    const int gn = n0 + wn * 64 + n * 16 + fr;
    const int which = (gn >= 2 * C_) ? 2 : ((gn >= C_) ? 1 : 0);
    const int rem = gn - which * C_;
    const int h = rem >> 6, d = rem & 63;
    float* dst = (which == 0) ? q_raw : ((which == 1) ? k_raw : v_raw);
    #pragma unroll
    for (int m = 0; m < 4; ++m) {
      #pragma unroll
      for (int j = 0; j < 4; ++j) {
        const int gm = m0 + wm * 64 + m * 16 + fj + j;
        if (gm < B_ * L_) {
          const int b = (gm >= L_) ? 1 : 0;
          const int l = gm - b * L_;
          dst[(((size_t)b * NH_ + h) * L_ + l) * HD_ + d] = acc[m][n][j];
        }
      }
    }
  }
}

// ---------------------------------------------------------------------------
// Proj GEMM: Abf[3200][768] * Wobf[768][768]^T + bo -> d_out f32
// ---------------------------------------------------------------------------
__global__ __launch_bounds__(256) void proj_gemm_mfma(
    const unsigned short* __restrict__ Abf, const unsigned short* __restrict__ Wobf,
    const float* __restrict__ bo, float* __restrict__ out) {
  f32x4 acc[4][4] = {};
  const int m0 = blockIdx.y * 128;
  const int n0 = blockIdx.x * 128;
  gemm_core(Abf, Wobf, C_, m0, n0, acc);
  const int lane = threadIdx.x & 63;
  const int wv = threadIdx.x >> 6;
  const int wm = wv >> 1, wn = wv & 1;
  const int fr = lane & 15, fj = (lane >> 4) * 4;
  #pragma unroll
  for (int n = 0; n < 4; ++n) {
    const int gn = n0 + wn * 64 + n * 16 + fr;
    const float bias = bo[gn];
    #pragma unroll
    for (int m = 0; m < 4; ++m) {
      #pragma unroll
      for (int j = 0; j < 4; ++j) {
        const int gm = m0 + wm * 64 + m * 16 + fj + j;
        if (gm < B_ * L_) out[(size_t)gm * C_ + gn] = acc[m][n][j] + bias;
      }
    }
  }
}

// ---------------------------------------------------------------------------
// Fused depthwise 3x3 conv + LayerNorm(64) for q/k/v (blockIdx.y selects).
// One-pass mean/var (two independent shuffle chains).
// ---------------------------------------------------------------------------
__global__ __launch_bounds__(256) void pool_ln_fused(
    const float* __restrict__ q_raw, const float* __restrict__ k_raw,
    const float* __restrict__ v_raw,
    const float* __restrict__ qw, const float* __restrict__ kw,
    const float* __restrict__ vw,
    const float* __restrict__ qg, const float* __restrict__ qb2,
    const float* __restrict__ kg, const float* __restrict__ kb2,
    const float* __restrict__ vg, const float* __restrict__ vb2,
    unsigned short* __restrict__ Qp2, unsigned short* __restrict__ Kp2a,
    unsigned short* __restrict__ Vtmp) {
  const int which = blockIdx.y;
  const float* in = (which == 0) ? q_raw : (which == 1) ? k_raw : v_raw;
  const float* w  = (which == 0) ? qw : (which == 1) ? kw : vw;
  const float* g  = (which == 0) ? qg : (which == 1) ? kg : vg;
  const float* bb = (which == 0) ? qb2 : (which == 1) ? kb2 : vb2;
  unsigned short* out = (which == 0) ? Qp2 : (which == 1) ? Kp2a : Vtmp;
  const int stride = (which == 0) ? DP_ : 64;
  const float scale = (which == 1) ? SCALE_K : 1.f;

  const int row = blockIdx.x * 4 + (threadIdx.x >> 6);
  const int d = threadIdx.x & 63;
  const int bh = row / L_;
  const int l  = row % L_;
  const int t  = l / S_;
  const int sq = l % S_;
  const int x = sq / W_, y = sq % W_;
  const float* base = in + ((size_t)bh * L_ + t * S_) * HD_;
  float acc = 0.f;
  #pragma unroll
  for (int dx = 0; dx < 3; ++dx) {
    const int xx = x + dx - 1;
    if (xx < 0 || xx >= H_) continue;
    #pragma unroll
    for (int dy = 0; dy < 3; ++dy) {
      const int yy = y + dy - 1;
      if (yy < 0 || yy >= W_) continue;
      acc += base[(size_t)(xx * W_ + yy) * HD_ + d] * w[(dx * 3 + dy) * HD_ + d];
    }
  }
  float s1 = acc, s2 = acc * acc;
  #pragma unroll
  for (int off = 32; off; off >>= 1) {
    s1 += __shfl_xor(s1, off);
    s2 += __shfl_xor(s2, off);
  }
  const float mu = s1 * (1.f / 64.f);
  const float var = s2 * (1.f / 64.f) - mu * mu;
  const float val = (acc - mu) * rsqrtf(var + LN_EPS) * g[d] + bb[d];
  out[(size_t)row * stride + d] = f2bf(val * scale);
}

// ---------------------------------------------------------------------------
// Transpose V per head: Vtmp [bh][L][64] bf16 -> VpT [bh][64][L] bf16
// ---------------------------------------------------------------------------
__global__ __launch_bounds__(256) void transpose_v(
    const unsigned short* __restrict__ Vtmp, unsigned short* __restrict__ VpT) {
  __shared__ unsigned short tile[32][72];
  const int bh = blockIdx.y;
  const int l0 = blockIdx.x * 32;
  const int t = threadIdx.x;
  {
    const int r = t >> 3, c8 = (t & 7) * 8;
    u32x4 v = *(const u32x4*)(Vtmp + ((size_t)bh * L_ + l0 + r) * 64 + c8);
    *(u32x4*)&tile[r][c8] = v;
  }
  __syncthreads();
  const int d = t >> 2, gq = t & 3;
  unsigned short o[8];
  #pragma unroll
  for (int i = 0; i < 8; ++i) o[i] = tile[gq*8 + i][d];
  u32x4 ov;
  ov.x = (uint_)o[0] | ((uint_)o[1] << 16);
  ov.y = (uint_)o[2] | ((uint_)o[3] << 16);
  ov.z = (uint_)o[4] | ((uint_)o[5] << 16);
  ov.w = (uint_)o[6] | ((uint_)o[7] << 16);
  *(u32x4*)(VpT + ((size_t)bh * 64 + d) * L_ + l0 + gq*8) = ov;
}

// ---------------------------------------------------------------------------
// rel-pos rows -> Qp2 dims 64..175 (log2e-scaled; other T-block zeroed)
// ---------------------------------------------------------------------------
__global__ void relpos_fused(
    const unsigned short* __restrict__ Qp2r, const float* __restrict__ rph,
    const float* __restrict__ rpw, unsigned short* __restrict__ Qp2) {
  const int idx = blockIdx.x * blockDim.x + threadIdx.x;
  const int k = idx % H_;
  const int rest = idx / H_;            // bh*L + t*S + sq
  const int sq = rest % S_;
  const int t = (rest % L_) / S_;
  const int x = sq / W_, y = sq % W_;
  const unsigned short* qrow = Qp2r + (size_t)rest * DP_;
  const float* rh = rph + (x - k + H_ - 1) * HD_;
  const float* rw = rpw + (y - k + W_ - 1) * HD_;
  float ah = 0.f, aw = 0.f;
  #pragma unroll
  for (int c = 0; c < HD_; c += 8) {
    u32x4 qv = *(const u32x4*)(qrow + c);
    float4 h0 = *(const float4*)(rh + c);
    float4 h1 = *(const float4*)(rh + c + 4);
    float4 w0 = *(const float4*)(rw + c);
    float4 w1 = *(const float4*)(rw + c + 4);
    const float q0 = bflo(qv.x), q1 = bfhi(qv.x), q2 = bflo(qv.y), q3 = bfhi(qv.y);
    const float q4 = bflo(qv.z), q5 = bfhi(qv.z), q6 = bflo(qv.w), q7 = bfhi(qv.w);
    ah += q0*h0.x + q1*h0.y + q2*h0.z + q3*h0.w + q4*h1.x + q5*h1.y + q6*h1.z + q7*h1.w;
    aw += q0*w0.x + q1*w0.y + q2*w0.z + q3*w0.w + q4*w1.x + q5*w1.y + q6*w1.z + q7*w1.w;
  }
  unsigned short* qd = Qp2 + (size_t)rest * DP_;
  qd[64 + t*56 + k]        = f2bf(ah * LOG2E);
  qd[64 + t*56 + 28 + k]   = f2bf(aw * LOG2E);
  qd[64 + (1-t)*56 + k]      = 0;
  qd[64 + (1-t)*56 + 28 + k] = 0;
}

// ---------------------------------------------------------------------------
// MFMA flash attention. 256 thr (4 waves), grid 1176 (XCD-swizzled).
// 2-tile software pipeline per wave: QK(j) MFMAs issue, then softmax+PV(j-1)
// runs under their latency. K double-buffered one tile ahead; V loads issued
// a full QK-phase before use.
// ---------------------------------------------------------------------------
__device__ __forceinline__ void load_k(
    const unsigned short* kbase, int kt,
    u32x4& k0, u32x4& k1, u32x4& k2, u32x4& k3) {
  const unsigned short* kr = kbase + (size_t)kt * 2048;
  k0 = *(const u32x4*)(kr);
  k1 = *(const u32x4*)(kr + 16);
  k2 = *(const u32x4*)(kr + 32);
  k3 = *(const u32x4*)(kr + 48);
}

__device__ __forceinline__ void load_v(
    const unsigned short* vbase0, int kt,
    u32x4& va, u32x4& vb, u32x4& vc, u32x4& vd) {
  const unsigned short* vr = vbase0 + kt * 32;
  va = *(const u32x4*)(vr);
  vb = *(const u32x4*)(vr + 16);
  vc = *(const u32x4*)(vr + 32 * L_);
  vd = *(const u32x4*)(vr + 32 * L_ + 16);
}

template<bool BIAS>
__device__ __forceinline__ f32x16 qk_tile(
    int kt, int lo, int hi, const u32x4 (&qf)[4],
    const unsigned short* __restrict__ qbias,
    u32x4 k0, u32x4 k1, u32x4 k2, u32x4 k3) {
  f32x16 s = {};
  s = __builtin_amdgcn_mfma_f32_32x32x16_bf16(BC8(k0), BC8(qf[0]), s, 0, 0, 0);
  s = __builtin_amdgcn_mfma_f32_32x32x16_bf16(BC8(k1), BC8(qf[1]), s, 0, 0, 0);
  s = __builtin_amdgcn_mfma_f32_32x32x16_bf16(BC8(k2), BC8(qf[2]), s, 0, 0, 0);
  s = __builtin_amdgcn_mfma_f32_32x32x16_bf16(BC8(k3), BC8(qf[3]), s, 0, 0, 0);
  if (BIAS) {
    const int kr = kt * 32 + lo;
    const int t = (kr >= S_) ? 1 : 0;
    const int sk = kr - t * S_;
    const int x = sk / W_, y = sk - x * W_;
    const int p1 = 64 + t*56 + x;
    const int p2 = 64 + t*56 + 28 + y;
    const uint_ v1 = 0x3F80u << ((p1 & 1) << 4);
    const uint_ v2 = 0x3F80u << ((p2 & 1) << 4);
    const int g1 = p1 >> 3, g2 = p2 >> 3;
    const int w1 = (p1 >> 1) & 3, w2 = (p2 >> 1) & 3;
    #pragma unroll
    for (int c = 4; c < 11; ++c) {
      const int gg = 2*c + hi;
      u32x4 oh;
      oh.x = ((g1 == gg && w1 == 0) ? v1 : 0u) | ((g2 == gg && w2 == 0) ? v2 : 0u);
      oh.y = ((g1 == gg && w1 == 1) ? v1 : 0u) | ((g2 == gg && w2 == 1) ? v2 : 0u);
      oh.z = ((g1 == gg && w1 == 2) ? v1 : 0u) | ((g2 == gg && w2 == 2) ? v2 : 0u);
      oh.w = ((g1 == gg && w1 == 3) ? v1 : 0u) | ((g2 == gg && w2 == 3) ? v2 : 0u);
      const u32x4 qb = *(const u32x4*)(qbias + (c - 4) * 16);
      s = __builtin_amdgcn_mfma_f32_32x32x16_bf16(BC8(oh), BC8(qb), s, 0, 0, 0);
    }
  }
  return s;
}

__device__ __forceinline__ void sm_pv(
    int lo, int hi, const f32x16& s,
    u32x4 va, u32x4 vb, u32x4 vc, u32x4 vd,
    f32x16& acc0, f32x16& acc1, float& m_run, float& l_run) {
  float m01 = fmaxf(s[0], s[1]),  m23 = fmaxf(s[2], s[3]);
  float m45 = fmaxf(s[4], s[5]),  m67 = fmaxf(s[6], s[7]);
  float m89 = fmaxf(s[8], s[9]),  mab = fmaxf(s[10], s[11]);
  float mcd = fmaxf(s[12], s[13]), mef = fmaxf(s[14], s[15]);
  float pmax = fmaxf(fmaxf(fmaxf(m01, m23), fmaxf(m45, m67)),
                     fmaxf(fmaxf(m89, mab), fmaxf(mcd, mef)));
  pmax = fmaxf(pmax, __shfl_xor(pmax, 32));
  if (__any(pmax > m_run + 8.f)) {            // defer-max (log2 units)
    const float mn = fmaxf(m_run, pmax);
    const float f = exp2f(m_run - mn);
    m_run = mn; l_run *= f;
    #pragma unroll
    for (int r = 0; r < 16; ++r) {
      const float fr = __shfl(f, (r & 3) + 8*(r >> 2) + 4*hi);
      acc0[r] *= fr; acc1[r] *= fr;
    }
  }
  float ps = 0.f;
  uint_ pw0, pw1, pw2, pw3, pw4, pw5, pw6, pw7;
  {
    float a, b;
    a = exp2f(s[0]-m_run);  b = exp2f(s[1]-m_run);  ps += a+b; pw0 = cvtpk(a,b);
    a = exp2f(s[2]-m_run);  b = exp2f(s[3]-m_run);  ps += a+b; pw1 = cvtpk(a,b);
    a = exp2f(s[4]-m_run);  b = exp2f(s[5]-m_run);  ps += a+b; pw2 = cvtpk(a,b);
    a = exp2f(s[6]-m_run);  b = exp2f(s[7]-m_run);  ps += a+b; pw3 = cvtpk(a,b);
    a = exp2f(s[8]-m_run);  b = exp2f(s[9]-m_run);  ps += a+b; pw4 = cvtpk(a,b);
    a = exp2f(s[10]-m_run); b = exp2f(s[11]-m_run); ps += a+b; pw5 = cvtpk(a,b);
    a = exp2f(s[12]-m_run); b = exp2f(s[13]-m_run); ps += a+b; pw6 = cvtpk(a,b);
    a = exp2f(s[14]-m_run); b = exp2f(s[15]-m_run); ps += a+b; pw7 = cvtpk(a,b);
  }
  ps += __shfl_xor(ps, 32);
  l_run += ps;

  auto sA = __builtin_amdgcn_permlane32_swap(pw0, pw2, false, false);
  auto sB = __builtin_amdgcn_permlane32_swap(pw1, pw3, false, false);
  auto sC = __builtin_amdgcn_permlane32_swap(pw4, pw6, false, false);
  auto sD = __builtin_amdgcn_permlane32_swap(pw5, pw7, false, false);
  u32x4 pa0, pa1;
  pa0.x = sA[0]; pa0.y = sB[0]; pa0.z = sA[1]; pa0.w = sB[1];
  pa1.x = sC[0]; pa1.y = sD[0]; pa1.z = sC[1]; pa1.w = sD[1];

  acc0 = __builtin_amdgcn_mfma_f32_32x32x16_bf16(BC8(pa0), BC8(va), acc0, 0, 0, 0);
  acc0 = __builtin_amdgcn_mfma_f32_32x32x16_bf16(BC8(pa1), BC8(vb), acc0, 0, 0, 0);
  acc1 = __builtin_amdgcn_mfma_f32_32x32x16_bf16(BC8(pa0), BC8(vc), acc1, 0, 0, 0);
  acc1 = __builtin_amdgcn_mfma_f32_32x32x16_bf16(BC8(pa1), BC8(vd), acc1, 0, 0, 0);
}

__device__ __forceinline__ bool bias_needed(int kt, int qt) {
  const int kmin = (kt * 32 >= S_) ? 1 : 0;
  const int kmax = (kt * 32 + 31 >= S_) ? 1 : 0;
  const int qmin = (qt * 32 >= S_) ? 1 : 0;
  const int qmax = (qt * 32 + 31 >= S_) ? 1 : 0;
  return (kmin <= qmax) && (qmin <= kmax);
}

__global__ __launch_bounds__(256) void attn_mfma(
    const unsigned short* __restrict__ Qp2, const unsigned short* __restrict__ Kp2a,
    const unsigned short* __restrict__ VpT,
    unsigned short* __restrict__ Abf) {
  __shared__ float red_acc[3][32][64];
  __shared__ float red_ml[4][2][32];

  const int id0 = blockIdx.x;                  // 1176 = 8 * 147
  const int swz = (id0 & 7) * 147 + (id0 >> 3);
  const int qt = swz % 49;
  const int bh = swz / 49;

  const int lane = threadIdx.x & 63;
  const int wv = threadIdx.x >> 6;             // 0..3
  const int lo = lane & 31, hi = lane >> 5;
  const int q0 = qt * 32;

  const unsigned short* qrow = Qp2 + ((size_t)bh * L_ + q0 + lo) * DP_ + hi * 8;
  u32x4 qf[4];
  #pragma unroll
  for (int c = 0; c < 4; ++c) qf[c] = *(const u32x4*)(qrow + c * 16);
  const unsigned short* qbias = qrow + 64;

  const unsigned short* kbase = Kp2a + ((size_t)bh * L_ + lo) * 64 + hi * 8;
  const unsigned short* vbase0 = VpT + (size_t)bh * 64 * L_ + (size_t)lo * L_ + hi * 8;

  f32x16 acc0 = {}, acc1 = {};
  float m_run = -1e30f, l_run = 0.f;
  const int nt = (49 - wv + 3) >> 2;           // wave wv: tiles kt = wv + 4*j

  #define KT(j) (wv + 4 * (j))
  #define QK(j, K0, K1, K2, K3) \
    (bias_needed(KT(j), qt) \
      ? qk_tile<true>(KT(j), lo, hi, qf, qbias, K0, K1, K2, K3) \
      : qk_tile<false>(KT(j), lo, hi, qf, qbias, K0, K1, K2, K3))

  u32x4 kA0, kA1, kA2, kA3, kB0, kB1, kB2, kB3;
  u32x4 va, vb, vc, vd;

  // prologue: K for tiles 0,1; QK(0)
  load_k(kbase, KT(0), kA0, kA1, kA2, kA3);
  load_k(kbase, KT(1), kB0, kB1, kB2, kB3);   // nt >= 12 always
  f32x16 s_prev = QK(0, kA0, kA1, kA2, kA3);

  int j = 1;
  for (; j + 1 < nt; j += 2) {
    // half 1: QK(j) from kB; prefetch K(j+1) -> kA; finish tile j-1
    load_v(vbase0, KT(j - 1), va, vb, vc, vd);
    f32x16 s_cur = QK(j, kB0, kB1, kB2, kB3);
    load_k(kbase, KT(j + 1), kA0, kA1, kA2, kA3);
    sm_pv(lo, hi, s_prev, va, vb, vc, vd, acc0, acc1, m_run, l_run);
    s_prev = s_cur;
    // half 2: QK(j+1) from kA; prefetch K(min(j+2, nt-1)) -> kB; finish tile j
    load_v(vbase0, KT(j), va, vb, vc, vd);
    f32x16 s_cur2 = QK(j + 1, kA0, kA1, kA2, kA3);
    const int pf = (j + 2 < nt) ? j + 2 : nt - 1;
    load_k(kbase, KT(pf), kB0, kB1, kB2, kB3);
    sm_pv(lo, hi, s_prev, va, vb, vc, vd, acc0, acc1, m_run, l_run);
    s_prev = s_cur2;
  }
  if (j < nt) {   // one remaining tile (j == nt-1), K in kB
    load_v(vbase0, KT(j - 1), va, vb, vc, vd);
    f32x16 s_cur = QK(j, kB0, kB1, kB2, kB3);
    sm_pv(lo, hi, s_prev, va, vb, vc, vd, acc0, acc1, m_run, l_run);
    s_prev = s_cur;
  }
  load_v(vbase0, KT(nt - 1), va, vb, vc, vd);
  sm_pv(lo, hi, s_prev, va, vb, vc, vd, acc0, acc1, m_run, l_run);
  #undef QK
  #undef KT

  // merge the 4 waves' partial states
  if (hi == 0) { red_ml[wv][0][lo] = m_run; red_ml[wv][1][lo] = l_run; }
  if (wv >= 1) {
    #pragma unroll
    for (int r = 0; r < 16; ++r) {
      const int row = (r & 3) + 8*(r >> 2) + 4*hi;
      red_acc[wv-1][row][lo]      = acc0[r];
      red_acc[wv-1][row][32 + lo] = acc1[r];
    }
  }
  __syncthreads();
  if (wv == 0) {
    const int b = bh / NH_, h = bh % NH_;
    #pragma unroll
    for (int r = 0; r < 16; ++r) {
      const int row = (r & 3) + 8*(r >> 2) + 4*hi;
      const float m0 = red_ml[0][0][row], l0 = red_ml[0][1][row];
      const float m1 = red_ml[1][0][row], l1 = red_ml[1][1][row];
      const float m2 = red_ml[2][0][row], l2 = red_ml[2][1][row];
      const float m3 = red_ml[3][0][row], l3 = red_ml[3][1][row];
      const float M = fmaxf(fmaxf(m0, m1), fmaxf(m2, m3));
      const float w0 = exp2f(m0 - M), w1 = exp2f(m1 - M);
      const float w2 = exp2f(m2 - M), w3 = exp2f(m3 - M);
      const float inv = 1.0f / (l0*w0 + l1*w1 + l2*w2 + l3*w3);
      const float o0 = (acc0[r]*w0 + red_acc[0][row][lo]*w1 +
                        red_acc[1][row][lo]*w2 + red_acc[2][row][lo]*w3) * inv;
      const float o1 = (acc1[r]*w0 + red_acc[0][row][32+lo]*w1 +
                        red_acc[1][row][32+lo]*w2 + red_acc[2][row][32+lo]*w3) * inv;
      const size_t qoff = ((size_t)bh * L_ + q0 + row) * DP_ + lo;
      const size_t ooff = ((size_t)(b * L_ + q0 + row)) * C_ + h * 64 + lo;
      Abf[ooff]      = f2bf(o0 + bf2f(Qp2[qoff]));
      Abf[ooff + 32] = f2bf(o1 + bf2f(Qp2[qoff + 32]));
    }
  }
}

// ---------------------------------------------------------------------------
extern "C" void kernel_launch(void* const* d_in, const int* in_sizes, int n_in,
                              void* d_out, int out_size, void* d_ws, size_t ws_size,
                              hipStream_t stream) {
  const float* x         = (const float*)d_in[0];
  const float* qkv_w     = (const float*)d_in[1];
  const float* out_w     = (const float*)d_in[2];
  const float* out_b     = (const float*)d_in[3];
  const float* q_pool_w  = (const float*)d_in[4];
  const float* k_pool_w  = (const float*)d_in[5];
  const float* v_pool_w  = (const float*)d_in[6];
  const float* q_ln_g    = (const float*)d_in[7];
  const float* q_ln_b    = (const float*)d_in[8];
  const float* k_ln_g    = (const float*)d_in[9];
  const float* k_ln_b    = (const float*)d_in[10];
  const float* v_ln_g    = (const float*)d_in[11];
  const float* v_ln_b    = (const float*)d_in[12];
  const float* rel_pos_h = (const float*)d_in[13];
  const float* rel_pos_w = (const float*)d_in[14];

  float* R = (float*)d_ws;
  const size_t NQ = (size_t)B_ * NH_ * L_ * HD_;   // 2,408,448 f32 slots
  float* q_raw = R;
  unsigned short* Abf = (unsigned short*)R;
  float* k_raw = R + NQ;
  unsigned short* VpT = (unsigned short*)(R + NQ);
  float* v_raw = R + 2*NQ;
  const size_t D_off = 3*NQ;
  unsigned short* Xbf = (unsigned short*)(R + D_off);
  unsigned short* Qp2 = (unsigned short*)(R + D_off);
  const size_t E_off = D_off + 3311616;
  unsigned short* Kp2a = (unsigned short*)(R + E_off);
  const size_t F_off = E_off + 1204224;
  unsigned short* Wbf  = (unsigned short*)(R + F_off);
  unsigned short* Vtmp = (unsigned short*)(R + F_off);
  const size_t G_off = F_off + 1204224;
  unsigned short* Wobf = (unsigned short*)(R + G_off);

  // fused f32->bf16: x (3136*768) + qkv_w (2304*768) + out_w (768*768)
  cvt_all<<<2328, 256, 0, stream>>>(x, 3136*768, Xbf,
                                    qkv_w, 2304*768, Wbf,
                                    out_w, 768*768, Wobf);
  qkv_gemm_mfma<<<dim3(18, 25), 256, 0, stream>>>(Xbf, Wbf, q_raw, k_raw, v_raw);
  pool_ln_fused<<<dim3(9408, 3), 256, 0, stream>>>(
      q_raw, k_raw, v_raw, q_pool_w, k_pool_w, v_pool_w,
      q_ln_g, q_ln_b, k_ln_g, k_ln_b, v_ln_g, v_ln_b, Qp2, Kp2a, Vtmp);
  transpose_v<<<dim3(49, 24), 256, 0, stream>>>(Vtmp, VpT);
  relpos_fused<<<4116, 256, 0, stream>>>(Qp2, rel_pos_h, rel_pos_w, Qp2);
  attn_mfma<<<1176, 256, 0, stream>>>(Qp2, Kp2a, VpT, Abf);
  proj_gemm_mfma<<<dim3(6, 25), 256, 0, stream>>>(Abf, Wobf, out_b, (float*)d_out);
}

// Round 10
// 238.652 us; speedup vs baseline: 1.2161x; 1.0168x over previous
//
#include <hip/hip_runtime.h>
#include <math.h>

#define B_ 2
#define T_ 2
#define H_ 28
#define W_ 28
#define S_ (H_*W_)      /* 784  */
#define L_ (T_*S_)      /* 1568 */
#define C_ 768
#define NH_ 12
#define HD_ 64
#define LN_EPS 1e-5f
#define LOG2E 1.4426950408889634f
#define SCALE_K (0.125f * LOG2E)   /* hd^-0.5 * log2e folded into K' */
#define DP_ 176                     /* augmented head dim: 64 + 2*2*28 */

typedef unsigned int uint_;
typedef unsigned int u32x4 __attribute__((ext_vector_type(4)));
typedef __bf16 bf16x8 __attribute__((ext_vector_type(8)));
typedef float f32x4 __attribute__((ext_vector_type(4)));
typedef float f32x16 __attribute__((ext_vector_type(16)));

#define BC8(x) __builtin_bit_cast(bf16x8, (x))

__device__ __forceinline__ unsigned short f2bf(float f) {
  uint_ u = __builtin_bit_cast(uint_, f);
  u += 0x7FFFu + ((u >> 16) & 1u);
  return (unsigned short)(u >> 16);
}
__device__ __forceinline__ float bf2f(unsigned short h) {
  return __builtin_bit_cast(float, ((uint_)h) << 16);
}
__device__ __forceinline__ float bflo(uint_ u) {
  return __builtin_bit_cast(float, u << 16);
}
__device__ __forceinline__ float bfhi(uint_ u) {
  return __builtin_bit_cast(float, u & 0xFFFF0000u);
}
__device__ __forceinline__ uint_ cvtpk(float a, float b) {
  uint_ r;
  asm("v_cvt_pk_bf16_f32 %0, %1, %2" : "=v"(r) : "v"(a), "v"(b));
  return r;
}
__device__ __forceinline__ void gload16(const void* g, void* l) {
  __builtin_amdgcn_global_load_lds(
      (const __attribute__((address_space(1))) unsigned int*)g,
      (__attribute__((address_space(3))) unsigned int*)l, 16, 0, 0);
}

// ---------------------------------------------------------------------------
// Fused f32 -> bf16 convert for x / qkv_w / out_w (range-dispatched)
// ---------------------------------------------------------------------------
__global__ __launch_bounds__(256) void cvt_all(
    const float* __restrict__ s0, int n0, unsigned short* __restrict__ d0,
    const float* __restrict__ s1, int n1, unsigned short* __restrict__ d1,
    const float* __restrict__ s2, int n2, unsigned short* __restrict__ d2) {
  int i = (blockIdx.x * 256 + threadIdx.x) * 8;
  const float* s; unsigned short* d;
  if (i < n0) { s = s0; d = d0; }
  else if (i < n0 + n1) { i -= n0; s = s1; d = d1; }
  else { i -= n0 + n1; if (i >= n2) return; s = s2; d = d2; }
  float4 a = *(const float4*)(s + i);
  float4 b = *(const float4*)(s + i + 4);
  u32x4 o;
  o.x = cvtpk(a.x, a.y); o.y = cvtpk(a.z, a.w);
  o.z = cvtpk(b.x, b.y); o.w = cvtpk(b.z, b.w);
  *(u32x4*)(d + i) = o;
}

// ---------------------------------------------------------------------------
// bf16 MFMA GEMM core: C = A * B^T, 128x128 tile, BK=32, 4 waves
// ---------------------------------------------------------------------------
__device__ __forceinline__ void gemm_core(
    const unsigned short* __restrict__ A, const unsigned short* __restrict__ Bm,
    int K, int m0, int n0, f32x4 (&acc)[4][4]) {
  __shared__ __align__(16) unsigned short As[128 * 32];
  __shared__ __align__(16) unsigned short Bs[128 * 32];
  const int tid = threadIdx.x;
  const int lane = tid & 63;
  const int wv = tid >> 6;
  const int wm = wv >> 1, wn = wv & 1;
  const int srow = tid >> 2, scol = (tid & 3) * 8;
  const int fr = lane & 15, fk = (lane >> 4) * 8;
  const unsigned short* ag = A + (size_t)(m0 + srow) * K + scol;
  const unsigned short* bg = Bm + (size_t)(n0 + srow) * K + scol;
  unsigned short* asd = As + tid * 8;
  unsigned short* bsd = Bs + tid * 8;
  const int arow = wm * 64 + fr;
  const int brow = wn * 64 + fr;
  for (int k0 = 0; k0 < K; k0 += 32) {
    __syncthreads();
    gload16(ag + k0, asd);
    gload16(ag + (size_t)64 * K + k0, asd + 2048);
    gload16(bg + k0, bsd);
    gload16(bg + (size_t)64 * K + k0, bsd + 2048);
    __syncthreads();
    bf16x8 af[4], bfr[4];
    #pragma unroll
    for (int m = 0; m < 4; ++m)
      af[m] = *(const bf16x8*)(As + (arow + m * 16) * 32 + fk);
    #pragma unroll
    for (int n = 0; n < 4; ++n)
      bfr[n] = *(const bf16x8*)(Bs + (brow + n * 16) * 32 + fk);
    #pragma unroll
    for (int m = 0; m < 4; ++m)
      #pragma unroll
      for (int n = 0; n < 4; ++n)
        acc[m][n] = __builtin_amdgcn_mfma_f32_16x16x32_bf16(af[m], bfr[n], acc[m][n], 0, 0, 0);
  }
}

// ---------------------------------------------------------------------------
// QKV GEMM: Xbf[3200][768] * Wbf[2304][768]^T -> scatter f32 q/k/v [B,NH,L,HD]
// ---------------------------------------------------------------------------
__global__ __launch_bounds__(256) void qkv_gemm_mfma(
    const unsigned short* __restrict__ Xbf, const unsigned short* __restrict__ Wbf,
    float* __restrict__ q_raw, float* __restrict__ k_raw, float* __restrict__ v_raw) {
  f32x4 acc[4][4] = {};
  const int m0 = blockIdx.y * 128;
  const int n0 = blockIdx.x * 128;
  gemm_core(Xbf, Wbf, C_, m0, n0, acc);
  const int lane = threadIdx.x & 63;
  const int wv = threadIdx.x >> 6;
  const int wm = wv >> 1, wn = wv & 1;
  const int fr = lane & 15, fj = (lane >> 4) * 4;
  #pragma unroll
  for (int n = 0; n < 4; ++n) {
    const int gn = n0 + wn * 64 + n * 16 + fr;
    const int which = (gn >= 2 * C_) ? 2 : ((gn >= C_) ? 1 : 0);
    const int rem = gn - which * C_;
    const int h = rem >> 6, d = rem & 63;
    float* dst = (which == 0) ? q_raw : ((which == 1) ? k_raw : v_raw);
    #pragma unroll
    for (int m = 0; m < 4; ++m) {
      #pragma unroll
      for (int j = 0; j < 4; ++j) {
        const int gm = m0 + wm * 64 + m * 16 + fj + j;
        if (gm < B_ * L_) {
          const int b = (gm >= L_) ? 1 : 0;
          const int l = gm - b * L_;
          dst[(((size_t)b * NH_ + h) * L_ + l) * HD_ + d] = acc[m][n][j];
        }
      }
    }
  }
}

// ---------------------------------------------------------------------------
// Proj GEMM: Abf[3200][768] * Wobf[768][768]^T + bo -> d_out f32
// ---------------------------------------------------------------------------
__global__ __launch_bounds__(256) void proj_gemm_mfma(
    const unsigned short* __restrict__ Abf, const unsigned short* __restrict__ Wobf,
    const float* __restrict__ bo, float* __restrict__ out) {
  f32x4 acc[4][4] = {};
  const int m0 = blockIdx.y * 128;
  const int n0 = blockIdx.x * 128;
  gemm_core(Abf, Wobf, C_, m0, n0, acc);
  const int lane = threadIdx.x & 63;
  const int wv = threadIdx.x >> 6;
  const int wm = wv >> 1, wn = wv & 1;
  const int fr = lane & 15, fj = (lane >> 4) * 4;
  #pragma unroll
  for (int n = 0; n < 4; ++n) {
    const int gn = n0 + wn * 64 + n * 16 + fr;
    const float bias = bo[gn];
    #pragma unroll
    for (int m = 0; m < 4; ++m) {
      #pragma unroll
      for (int j = 0; j < 4; ++j) {
        const int gm = m0 + wm * 64 + m * 16 + fj + j;
        if (gm < B_ * L_) out[(size_t)gm * C_ + gn] = acc[m][n][j] + bias;
      }
    }
  }
}

// ---------------------------------------------------------------------------
// Fused depthwise 3x3 conv + LayerNorm(64) for q/k/v (blockIdx.y selects).
// One-pass mean/var (two independent shuffle chains).
// ---------------------------------------------------------------------------
__global__ __launch_bounds__(256) void pool_ln_fused(
    const float* __restrict__ q_raw, const float* __restrict__ k_raw,
    const float* __restrict__ v_raw,
    const float* __restrict__ qw, const float* __restrict__ kw,
    const float* __restrict__ vw,
    const float* __restrict__ qg, const float* __restrict__ qb2,
    const float* __restrict__ kg, const float* __restrict__ kb2,
    const float* __restrict__ vg, const float* __restrict__ vb2,
    unsigned short* __restrict__ Qp2, unsigned short* __restrict__ Kp2a,
    unsigned short* __restrict__ Vtmp) {
  const int which = blockIdx.y;
  const float* in = (which == 0) ? q_raw : (which == 1) ? k_raw : v_raw;
  const float* w  = (which == 0) ? qw : (which == 1) ? kw : vw;
  const float* g  = (which == 0) ? qg : (which == 1) ? kg : vg;
  const float* bb = (which == 0) ? qb2 : (which == 1) ? kb2 : vb2;
  unsigned short* out = (which == 0) ? Qp2 : (which == 1) ? Kp2a : Vtmp;
  const int stride = (which == 0) ? DP_ : 64;
  const float scale = (which == 1) ? SCALE_K : 1.f;

  const int row = blockIdx.x * 4 + (threadIdx.x >> 6);
  const int d = threadIdx.x & 63;
  const int bh = row / L_;
  const int l  = row % L_;
  const int t  = l / S_;
  const int sq = l % S_;
  const int x = sq / W_, y = sq % W_;
  const float* base = in + ((size_t)bh * L_ + t * S_) * HD_;
  float acc = 0.f;
  #pragma unroll
  for (int dx = 0; dx < 3; ++dx) {
    const int xx = x + dx - 1;
    if (xx < 0 || xx >= H_) continue;
    #pragma unroll
    for (int dy = 0; dy < 3; ++dy) {
      const int yy = y + dy - 1;
      if (yy < 0 || yy >= W_) continue;
      acc += base[(size_t)(xx * W_ + yy) * HD_ + d] * w[(dx * 3 + dy) * HD_ + d];
    }
  }
  float s1 = acc, s2 = acc * acc;
  #pragma unroll
  for (int off = 32; off; off >>= 1) {
    s1 += __shfl_xor(s1, off);
    s2 += __shfl_xor(s2, off);
  }
  const float mu = s1 * (1.f / 64.f);
  const float var = s2 * (1.f / 64.f) - mu * mu;
  const float val = (acc - mu) * rsqrtf(var + LN_EPS) * g[d] + bb[d];
  out[(size_t)row * stride + d] = f2bf(val * scale);
}

// ---------------------------------------------------------------------------
// Transpose V per head: Vtmp [bh][L][64] bf16 -> VpT [bh][64][L] bf16
// ---------------------------------------------------------------------------
__global__ __launch_bounds__(256) void transpose_v(
    const unsigned short* __restrict__ Vtmp, unsigned short* __restrict__ VpT) {
  __shared__ unsigned short tile[32][72];
  const int bh = blockIdx.y;
  const int l0 = blockIdx.x * 32;
  const int t = threadIdx.x;
  {
    const int r = t >> 3, c8 = (t & 7) * 8;
    u32x4 v = *(const u32x4*)(Vtmp + ((size_t)bh * L_ + l0 + r) * 64 + c8);
    *(u32x4*)&tile[r][c8] = v;
  }
  __syncthreads();
  const int d = t >> 2, gq = t & 3;
  unsigned short o[8];
  #pragma unroll
  for (int i = 0; i < 8; ++i) o[i] = tile[gq*8 + i][d];
  u32x4 ov;
  ov.x = (uint_)o[0] | ((uint_)o[1] << 16);
  ov.y = (uint_)o[2] | ((uint_)o[3] << 16);
  ov.z = (uint_)o[4] | ((uint_)o[5] << 16);
  ov.w = (uint_)o[6] | ((uint_)o[7] << 16);
  *(u32x4*)(VpT + ((size_t)bh * 64 + d) * L_ + l0 + gq*8) = ov;
}

// ---------------------------------------------------------------------------
// rel-pos rows -> Qp2 dims 64..175 (log2e-scaled; other T-block zeroed)
// ---------------------------------------------------------------------------
__global__ void relpos_fused(
    const unsigned short* __restrict__ Qp2r, const float* __restrict__ rph,
    const float* __restrict__ rpw, unsigned short* __restrict__ Qp2) {
  const int idx = blockIdx.x * blockDim.x + threadIdx.x;
  const int k = idx % H_;
  const int rest = idx / H_;            // bh*L + t*S + sq
  const int sq = rest % S_;
  const int t = (rest % L_) / S_;
  const int x = sq / W_, y = sq % W_;
  const unsigned short* qrow = Qp2r + (size_t)rest * DP_;
  const float* rh = rph + (x - k + H_ - 1) * HD_;
  const float* rw = rpw + (y - k + W_ - 1) * HD_;
  float ah = 0.f, aw = 0.f;
  #pragma unroll
  for (int c = 0; c < HD_; c += 8) {
    u32x4 qv = *(const u32x4*)(qrow + c);
    float4 h0 = *(const float4*)(rh + c);
    float4 h1 = *(const float4*)(rh + c + 4);
    float4 w0 = *(const float4*)(rw + c);
    float4 w1 = *(const float4*)(rw + c + 4);
    const float q0 = bflo(qv.x), q1 = bfhi(qv.x), q2 = bflo(qv.y), q3 = bfhi(qv.y);
    const float q4 = bflo(qv.z), q5 = bfhi(qv.z), q6 = bflo(qv.w), q7 = bfhi(qv.w);
    ah += q0*h0.x + q1*h0.y + q2*h0.z + q3*h0.w + q4*h1.x + q5*h1.y + q6*h1.z + q7*h1.w;
    aw += q0*w0.x + q1*w0.y + q2*w0.z + q3*w0.w + q4*w1.x + q5*w1.y + q6*w1.z + q7*w1.w;
  }
  unsigned short* qd = Qp2 + (size_t)rest * DP_;
  qd[64 + t*56 + k]        = f2bf(ah * LOG2E);
  qd[64 + t*56 + 28 + k]   = f2bf(aw * LOG2E);
  qd[64 + (1-t)*56 + k]      = 0;
  qd[64 + (1-t)*56 + 28 + k] = 0;
}

// ---------------------------------------------------------------------------
// MFMA flash attention. 256 thr (4 waves), grid 1176 (XCD-swizzled).
// Fixed-base softmax: P = exp2(s) directly (scores bounded, no running max,
// no rescale). 2-tile pipeline; K double-buffered, V issued a phase early.
// ---------------------------------------------------------------------------
__device__ __forceinline__ void load_k(
    const unsigned short* kbase, int kt,
    u32x4& k0, u32x4& k1, u32x4& k2, u32x4& k3) {
  const unsigned short* kr = kbase + (size_t)kt * 2048;
  k0 = *(const u32x4*)(kr);
  k1 = *(const u32x4*)(kr + 16);
  k2 = *(const u32x4*)(kr + 32);
  k3 = *(const u32x4*)(kr + 48);
}

__device__ __forceinline__ void load_v(
    const unsigned short* vbase0, int kt,
    u32x4& va, u32x4& vb, u32x4& vc, u32x4& vd) {
  const unsigned short* vr = vbase0 + kt * 32;
  va = *(const u32x4*)(vr);
  vb = *(const u32x4*)(vr + 16);
  vc = *(const u32x4*)(vr + 32 * L_);
  vd = *(const u32x4*)(vr + 32 * L_ + 16);
}

template<bool BIAS>
__device__ __forceinline__ f32x16 qk_tile(
    int kt, int lo, int hi, const u32x4 (&qf)[4],
    const unsigned short* __restrict__ qbias,
    u32x4 k0, u32x4 k1, u32x4 k2, u32x4 k3) {
  f32x16 s = {};
  s = __builtin_amdgcn_mfma_f32_32x32x16_bf16(BC8(k0), BC8(qf[0]), s, 0, 0, 0);
  s = __builtin_amdgcn_mfma_f32_32x32x16_bf16(BC8(k1), BC8(qf[1]), s, 0, 0, 0);
  s = __builtin_amdgcn_mfma_f32_32x32x16_bf16(BC8(k2), BC8(qf[2]), s, 0, 0, 0);
  s = __builtin_amdgcn_mfma_f32_32x32x16_bf16(BC8(k3), BC8(qf[3]), s, 0, 0, 0);
  if (BIAS) {
    const int kr = kt * 32 + lo;
    const int t = (kr >= S_) ? 1 : 0;
    const int sk = kr - t * S_;
    const int x = sk / W_, y = sk - x * W_;
    const int p1 = 64 + t*56 + x;
    const int p2 = 64 + t*56 + 28 + y;
    const uint_ v1 = 0x3F80u << ((p1 & 1) << 4);
    const uint_ v2 = 0x3F80u << ((p2 & 1) << 4);
    const int g1 = p1 >> 3, g2 = p2 >> 3;
    const int w1 = (p1 >> 1) & 3, w2 = (p2 >> 1) & 3;
    #pragma unroll
    for (int c = 4; c < 11; ++c) {
      const int gg = 2*c + hi;
      u32x4 oh;
      oh.x = ((g1 == gg && w1 == 0) ? v1 : 0u) | ((g2 == gg && w2 == 0) ? v2 : 0u);
      oh.y = ((g1 == gg && w1 == 1) ? v1 : 0u) | ((g2 == gg && w2 == 1) ? v2 : 0u);
      oh.z = ((g1 == gg && w1 == 2) ? v1 : 0u) | ((g2 == gg && w2 == 2) ? v2 : 0u);
      oh.w = ((g1 == gg && w1 == 3) ? v1 : 0u) | ((g2 == gg && w2 == 3) ? v2 : 0u);
      const u32x4 qb = *(const u32x4*)(qbias + (c - 4) * 16);
      s = __builtin_amdgcn_mfma_f32_32x32x16_bf16(BC8(oh), BC8(qb), s, 0, 0, 0);
    }
  }
  return s;
}

__device__ __forceinline__ void sm_pv(
    const f32x16& s,
    u32x4 va, u32x4 vb, u32x4 vc, u32x4 vd,
    f32x16& acc0, f32x16& acc1, float& l_run) {
  // fixed-base softmax: P = exp2(s), no max subtraction (scores bounded).
  uint_ pw0, pw1, pw2, pw3, pw4, pw5, pw6, pw7;
  {
    float a, b;
    a = exp2f(s[0]);  b = exp2f(s[1]);  l_run += a+b; pw0 = cvtpk(a,b);
    a = exp2f(s[2]);  b = exp2f(s[3]);  l_run += a+b; pw1 = cvtpk(a,b);
    a = exp2f(s[4]);  b = exp2f(s[5]);  l_run += a+b; pw2 = cvtpk(a,b);
    a = exp2f(s[6]);  b = exp2f(s[7]);  l_run += a+b; pw3 = cvtpk(a,b);
    a = exp2f(s[8]);  b = exp2f(s[9]);  l_run += a+b; pw4 = cvtpk(a,b);
    a = exp2f(s[10]); b = exp2f(s[11]); l_run += a+b; pw5 = cvtpk(a,b);
    a = exp2f(s[12]); b = exp2f(s[13]); l_run += a+b; pw6 = cvtpk(a,b);
    a = exp2f(s[14]); b = exp2f(s[15]); l_run += a+b; pw7 = cvtpk(a,b);
  }
  auto sA = __builtin_amdgcn_permlane32_swap(pw0, pw2, false, false);
  auto sB = __builtin_amdgcn_permlane32_swap(pw1, pw3, false, false);
  auto sC = __builtin_amdgcn_permlane32_swap(pw4, pw6, false, false);
  auto sD = __builtin_amdgcn_permlane32_swap(pw5, pw7, false, false);
  u32x4 pa0, pa1;
  pa0.x = sA[0]; pa0.y = sB[0]; pa0.z = sA[1]; pa0.w = sB[1];
  pa1.x = sC[0]; pa1.y = sD[0]; pa1.z = sC[1]; pa1.w = sD[1];

  acc0 = __builtin_amdgcn_mfma_f32_32x32x16_bf16(BC8(pa0), BC8(va), acc0, 0, 0, 0);
  acc0 = __builtin_amdgcn_mfma_f32_32x32x16_bf16(BC8(pa1), BC8(vb), acc0, 0, 0, 0);
  acc1 = __builtin_amdgcn_mfma_f32_32x32x16_bf16(BC8(pa0), BC8(vc), acc1, 0, 0, 0);
  acc1 = __builtin_amdgcn_mfma_f32_32x32x16_bf16(BC8(pa1), BC8(vd), acc1, 0, 0, 0);
}

__device__ __forceinline__ bool bias_needed(int kt, int qt) {
  const int kmin = (kt * 32 >= S_) ? 1 : 0;
  const int kmax = (kt * 32 + 31 >= S_) ? 1 : 0;
  const int qmin = (qt * 32 >= S_) ? 1 : 0;
  const int qmax = (qt * 32 + 31 >= S_) ? 1 : 0;
  return (kmin <= qmax) && (qmin <= kmax);
}

__global__ __launch_bounds__(256) void attn_mfma(
    const unsigned short* __restrict__ Qp2, const unsigned short* __restrict__ Kp2a,
    const unsigned short* __restrict__ VpT,
    unsigned short* __restrict__ Abf) {
  __shared__ float red_acc[3][32][64];
  __shared__ float red_l[4][32];

  const int id0 = blockIdx.x;                  // 1176 = 8 * 147
  const int swz = (id0 & 7) * 147 + (id0 >> 3);
  const int qt = swz % 49;
  const int bh = swz / 49;

  const int lane = threadIdx.x & 63;
  const int wv = threadIdx.x >> 6;             // 0..3
  const int lo = lane & 31, hi = lane >> 5;
  const int q0 = qt * 32;

  const unsigned short* qrow = Qp2 + ((size_t)bh * L_ + q0 + lo) * DP_ + hi * 8;
  u32x4 qf[4];
  #pragma unroll
  for (int c = 0; c < 4; ++c) qf[c] = *(const u32x4*)(qrow + c * 16);
  const unsigned short* qbias = qrow + 64;

  const unsigned short* kbase = Kp2a + ((size_t)bh * L_ + lo) * 64 + hi * 8;
  const unsigned short* vbase0 = VpT + (size_t)bh * 64 * L_ + (size_t)lo * L_ + hi * 8;

  f32x16 acc0 = {}, acc1 = {};
  float l_run = 0.f;
  const int nt = (49 - wv + 3) >> 2;           // wave wv: tiles kt = wv + 4*j

  #define KT(j) (wv + 4 * (j))
  #define QK(j, K0, K1, K2, K3) \
    (bias_needed(KT(j), qt) \
      ? qk_tile<true>(KT(j), lo, hi, qf, qbias, K0, K1, K2, K3) \
      : qk_tile<false>(KT(j), lo, hi, qf, qbias, K0, K1, K2, K3))

  u32x4 kA0, kA1, kA2, kA3, kB0, kB1, kB2, kB3;
  u32x4 va, vb, vc, vd;

  // prologue: K for tiles 0,1; QK(0)
  load_k(kbase, KT(0), kA0, kA1, kA2, kA3);
  load_k(kbase, KT(1), kB0, kB1, kB2, kB3);   // nt >= 12 always
  f32x16 s_prev = QK(0, kA0, kA1, kA2, kA3);

  int j = 1;
  for (; j + 1 < nt; j += 2) {
    // half 1: QK(j) from kB; prefetch K(j+1) -> kA; finish tile j-1
    load_v(vbase0, KT(j - 1), va, vb, vc, vd);
    f32x16 s_cur = QK(j, kB0, kB1, kB2, kB3);
    load_k(kbase, KT(j + 1), kA0, kA1, kA2, kA3);
    sm_pv(s_prev, va, vb, vc, vd, acc0, acc1, l_run);
    s_prev = s_cur;
    // half 2: QK(j+1) from kA; prefetch K(min(j+2, nt-1)) -> kB; finish tile j
    load_v(vbase0, KT(j), va, vb, vc, vd);
    f32x16 s_cur2 = QK(j + 1, kA0, kA1, kA2, kA3);
    const int pf = (j + 2 < nt) ? j + 2 : nt - 1;
    load_k(kbase, KT(pf), kB0, kB1, kB2, kB3);
    sm_pv(s_prev, va, vb, vc, vd, acc0, acc1, l_run);
    s_prev = s_cur2;
  }
  if (j < nt) {   // one remaining tile (j == nt-1), K in kB
    load_v(vbase0, KT(j - 1), va, vb, vc, vd);
    f32x16 s_cur = QK(j, kB0, kB1, kB2, kB3);
    sm_pv(s_prev, va, vb, vc, vd, acc0, acc1, l_run);
    s_prev = s_cur;
  }
  load_v(vbase0, KT(nt - 1), va, vb, vc, vd);
  sm_pv(s_prev, va, vb, vc, vd, acc0, acc1, l_run);
  #undef QK
  #undef KT

  // full row-sum for this wave's partial l (lanes lo and lo+32 hold halves)
  l_run += __shfl_xor(l_run, 32);

  // merge the 4 waves' partial states (plain sums — no max weighting)
  if (hi == 0) red_l[wv][lo] = l_run;
  if (wv >= 1) {
    #pragma unroll
    for (int r = 0; r < 16; ++r) {
      const int row = (r & 3) + 8*(r >> 2) + 4*hi;
      red_acc[wv-1][row][lo]      = acc0[r];
      red_acc[wv-1][row][32 + lo] = acc1[r];
    }
  }
  __syncthreads();
  if (wv == 0) {
    const int b = bh / NH_, h = bh % NH_;
    #pragma unroll
    for (int r = 0; r < 16; ++r) {
      const int row = (r & 3) + 8*(r >> 2) + 4*hi;
      const float inv = 1.0f / (red_l[0][row] + red_l[1][row] +
                                red_l[2][row] + red_l[3][row]);
      const float o0 = (acc0[r] + red_acc[0][row][lo] +
                        red_acc[1][row][lo] + red_acc[2][row][lo]) * inv;
      const float o1 = (acc1[r] + red_acc[0][row][32+lo] +
                        red_acc[1][row][32+lo] + red_acc[2][row][32+lo]) * inv;
      const size_t qoff = ((size_t)bh * L_ + q0 + row) * DP_ + lo;
      const size_t ooff = ((size_t)(b * L_ + q0 + row)) * C_ + h * 64 + lo;
      Abf[ooff]      = f2bf(o0 + bf2f(Qp2[qoff]));
      Abf[ooff + 32] = f2bf(o1 + bf2f(Qp2[qoff + 32]));
    }
  }
}

// ---------------------------------------------------------------------------
extern "C" void kernel_launch(void* const* d_in, const int* in_sizes, int n_in,
                              void* d_out, int out_size, void* d_ws, size_t ws_size,
                              hipStream_t stream) {
  const float* x         = (const float*)d_in[0];
  const float* qkv_w     = (const float*)d_in[1];
  const float* out_w     = (const float*)d_in[2];
  const float* out_b     = (const float*)d_in[3];
  const float* q_pool_w  = (const float*)d_in[4];
  const float* k_pool_w  = (const float*)d_in[5];
  const float* v_pool_w  = (const float*)d_in[6];
  const float* q_ln_g    = (const float*)d_in[7];
  const float* q_ln_b    = (const float*)d_in[8];
  const float* k_ln_g    = (const float*)d_in[9];
  const float* k_ln_b    = (const float*)d_in[10];
  const float* v_ln_g    = (const float*)d_in[11];
  const float* v_ln_b    = (const float*)d_in[12];
  const float* rel_pos_h = (const float*)d_in[13];
  const float* rel_pos_w = (const float*)d_in[14];

  float* R = (float*)d_ws;
  const size_t NQ = (size_t)B_ * NH_ * L_ * HD_;   // 2,408,448 f32 slots
  float* q_raw = R;
  unsigned short* Abf = (unsigned short*)R;
  float* k_raw = R + NQ;
  unsigned short* VpT = (unsigned short*)(R + NQ);
  float* v_raw = R + 2*NQ;
  const size_t D_off = 3*NQ;
  unsigned short* Xbf = (unsigned short*)(R + D_off);
  unsigned short* Qp2 = (unsigned short*)(R + D_off);
  const size_t E_off = D_off + 3311616;
  unsigned short* Kp2a = (unsigned short*)(R + E_off);
  const size_t F_off = E_off + 1204224;
  unsigned short* Wbf  = (unsigned short*)(R + F_off);
  unsigned short* Vtmp = (unsigned short*)(R + F_off);
  const size_t G_off = F_off + 1204224;
  unsigned short* Wobf = (unsigned short*)(R + G_off);

  // fused f32->bf16: x (3136*768) + qkv_w (2304*768) + out_w (768*768)
  cvt_all<<<2328, 256, 0, stream>>>(x, 3136*768, Xbf,
                                    qkv_w, 2304*768, Wbf,
                                    out_w, 768*768, Wobf);
  qkv_gemm_mfma<<<dim3(18, 25), 256, 0, stream>>>(Xbf, Wbf, q_raw, k_raw, v_raw);
  pool_ln_fused<<<dim3(9408, 3), 256, 0, stream>>>(
      q_raw, k_raw, v_raw, q_pool_w, k_pool_w, v_pool_w,
      q_ln_g, q_ln_b, k_ln_g, k_ln_b, v_ln_g, v_ln_b, Qp2, Kp2a, Vtmp);
  transpose_v<<<dim3(49, 24), 256, 0, stream>>>(Vtmp, VpT);
  relpos_fused<<<4116, 256, 0, stream>>>(Qp2, rel_pos_h, rel_pos_w, Qp2);
  attn_mfma<<<1176, 256, 0, stream>>>(Qp2, Kp2a, VpT, Abf);
  proj_gemm_mfma<<<dim3(6, 25), 256, 0, stream>>>(Abf, Wobf, out_b, (float*)d_out);
}

// Round 11
// 184.452 us; speedup vs baseline: 1.5735x; 1.2938x over previous
//
#include <hip/hip_runtime.h>
#include <math.h>

#define B_ 2
#define T_ 2
#define H_ 28
#define W_ 28
#define S_ (H_*W_)      /* 784  */
#define L_ (T_*S_)      /* 1568 */
#define C_ 768
#define NH_ 12
#define HD_ 64
#define LN_EPS 1e-5f
#define LOG2E 1.4426950408889634f
#define SCALE_K (0.125f * LOG2E)   /* hd^-0.5 * log2e folded into K' */
#define DP_ 176                     /* augmented head dim: 64 + 2*2*28 */

typedef unsigned int uint_;
typedef unsigned int u32x4 __attribute__((ext_vector_type(4)));
typedef __bf16 bf16x8 __attribute__((ext_vector_type(8)));
typedef float f32x4 __attribute__((ext_vector_type(4)));
typedef float f32x16 __attribute__((ext_vector_type(16)));

#define BC8(x) __builtin_bit_cast(bf16x8, (x))

__device__ __forceinline__ unsigned short f2bf(float f) {
  uint_ u = __builtin_bit_cast(uint_, f);
  u += 0x7FFFu + ((u >> 16) & 1u);
  return (unsigned short)(u >> 16);
}
__device__ __forceinline__ float bf2f(unsigned short h) {
  return __builtin_bit_cast(float, ((uint_)h) << 16);
}
__device__ __forceinline__ uint_ cvtpk(float a, float b) {
  uint_ r;
  asm("v_cvt_pk_bf16_f32 %0, %1, %2" : "=v"(r) : "v"(a), "v"(b));
  return r;
}
__device__ __forceinline__ void gload16(const void* g, void* l) {
  __builtin_amdgcn_global_load_lds(
      (const __attribute__((address_space(1))) unsigned int*)g,
      (__attribute__((address_space(3))) unsigned int*)l, 16, 0, 0);
}

// ---------------------------------------------------------------------------
// Fused f32 -> bf16 convert for x / qkv_w / out_w (range-dispatched)
// ---------------------------------------------------------------------------
__global__ __launch_bounds__(256) void cvt_all(
    const float* __restrict__ s0, int n0, unsigned short* __restrict__ d0,
    const float* __restrict__ s1, int n1, unsigned short* __restrict__ d1,
    const float* __restrict__ s2, int n2, unsigned short* __restrict__ d2) {
  int i = (blockIdx.x * 256 + threadIdx.x) * 8;
  const float* s; unsigned short* d;
  if (i < n0) { s = s0; d = d0; }
  else if (i < n0 + n1) { i -= n0; s = s1; d = d1; }
  else { i -= n0 + n1; if (i >= n2) return; s = s2; d = d2; }
  float4 a = *(const float4*)(s + i);
  float4 b = *(const float4*)(s + i + 4);
  u32x4 o;
  o.x = cvtpk(a.x, a.y); o.y = cvtpk(a.z, a.w);
  o.z = cvtpk(b.x, b.y); o.w = cvtpk(b.z, b.w);
  *(u32x4*)(d + i) = o;
}

// ---------------------------------------------------------------------------
// rel-pos tables -> bf16, LOG2E folded, padded to [64][64] (rows 55.. zero)
// ---------------------------------------------------------------------------
__global__ __launch_bounds__(256) void cvt_rel(
    const float* __restrict__ rph, const float* __restrict__ rpw,
    unsigned short* __restrict__ Rhb, unsigned short* __restrict__ Rwb) {
  const int i = blockIdx.x * 256 + threadIdx.x;   // 0..4095
  if (i >= 4096) return;
  const int j = i >> 6;
  const unsigned short vh = (j < 2*H_-1) ? f2bf(rph[i] * LOG2E) : 0;
  const unsigned short vw = (j < 2*W_-1) ? f2bf(rpw[i] * LOG2E) : 0;
  Rhb[i] = vh;
  Rwb[i] = vw;
}

// ---------------------------------------------------------------------------
// bf16 MFMA GEMM core: C = A * B^T, 128x128 tile, BK=32, 4 waves
// ---------------------------------------------------------------------------
__device__ __forceinline__ void gemm_core(
    const unsigned short* __restrict__ A, const unsigned short* __restrict__ Bm,
    int K, int m0, int n0, f32x4 (&acc)[4][4]) {
  __shared__ __align__(16) unsigned short As[128 * 32];
  __shared__ __align__(16) unsigned short Bs[128 * 32];
  const int tid = threadIdx.x;
  const int lane = tid & 63;
  const int wv = tid >> 6;
  const int wm = wv >> 1, wn = wv & 1;
  const int srow = tid >> 2, scol = (tid & 3) * 8;
  const int fr = lane & 15, fk = (lane >> 4) * 8;
  const unsigned short* ag = A + (size_t)(m0 + srow) * K + scol;
  const unsigned short* bg = Bm + (size_t)(n0 + srow) * K + scol;
  unsigned short* asd = As + tid * 8;
  unsigned short* bsd = Bs + tid * 8;
  const int arow = wm * 64 + fr;
  const int brow = wn * 64 + fr;
  for (int k0 = 0; k0 < K; k0 += 32) {
    __syncthreads();
    gload16(ag + k0, asd);
    gload16(ag + (size_t)64 * K + k0, asd + 2048);
    gload16(bg + k0, bsd);
    gload16(bg + (size_t)64 * K + k0, bsd + 2048);
    __syncthreads();
    bf16x8 af[4], bfr[4];
    #pragma unroll
    for (int m = 0; m < 4; ++m)
      af[m] = *(const bf16x8*)(As + (arow + m * 16) * 32 + fk);
    #pragma unroll
    for (int n = 0; n < 4; ++n)
      bfr[n] = *(const bf16x8*)(Bs + (brow + n * 16) * 32 + fk);
    #pragma unroll
    for (int m = 0; m < 4; ++m)
      #pragma unroll
      for (int n = 0; n < 4; ++n)
        acc[m][n] = __builtin_amdgcn_mfma_f32_16x16x32_bf16(af[m], bfr[n], acc[m][n], 0, 0, 0);
  }
}

// ---------------------------------------------------------------------------
// QKV GEMM: Xbf[3200][768] * Wbf[2304][768]^T -> scatter f32 q/k/v [B,NH,L,HD]
// ---------------------------------------------------------------------------
__global__ __launch_bounds__(256) void qkv_gemm_mfma(
    const unsigned short* __restrict__ Xbf, const unsigned short* __restrict__ Wbf,
    float* __restrict__ q_raw, float* __restrict__ k_raw, float* __restrict__ v_raw) {
  f32x4 acc[4][4] = {};
  const int m0 = blockIdx.y * 128;
  const int n0 = blockIdx.x * 128;
  gemm_core(Xbf, Wbf, C_, m0, n0, acc);
  const int lane = threadIdx.x & 63;
  const int wv = threadIdx.x >> 6;
  const int wm = wv >> 1, wn = wv & 1;
  const int fr = lane & 15, fj = (lane >> 4) * 4;
  #pragma unroll
  for (int n = 0; n < 4; ++n) {
    const int gn = n0 + wn * 64 + n * 16 + fr;
    const int which = (gn >= 2 * C_) ? 2 : ((gn >= C_) ? 1 : 0);
    const int rem = gn - which * C_;
    const int h = rem >> 6, d = rem & 63;
    float* dst = (which == 0) ? q_raw : ((which == 1) ? k_raw : v_raw);
    #pragma unroll
    for (int m = 0; m < 4; ++m) {
      #pragma unroll
      for (int j = 0; j < 4; ++j) {
        const int gm = m0 + wm * 64 + m * 16 + fj + j;
        if (gm < B_ * L_) {
          const int b = (gm >= L_) ? 1 : 0;
          const int l = gm - b * L_;
          dst[(((size_t)b * NH_ + h) * L_ + l) * HD_ + d] = acc[m][n][j];
        }
      }
    }
  }
}

// ---------------------------------------------------------------------------
// Proj GEMM: Abf[3200][768] * Wobf[768][768]^T + bo -> d_out f32
// ---------------------------------------------------------------------------
__global__ __launch_bounds__(256) void proj_gemm_mfma(
    const unsigned short* __restrict__ Abf, const unsigned short* __restrict__ Wobf,
    const float* __restrict__ bo, float* __restrict__ out) {
  f32x4 acc[4][4] = {};
  const int m0 = blockIdx.y * 128;
  const int n0 = blockIdx.x * 128;
  gemm_core(Abf, Wobf, C_, m0, n0, acc);
  const int lane = threadIdx.x & 63;
  const int wv = threadIdx.x >> 6;
  const int wm = wv >> 1, wn = wv & 1;
  const int fr = lane & 15, fj = (lane >> 4) * 4;
  #pragma unroll
  for (int n = 0; n < 4; ++n) {
    const int gn = n0 + wn * 64 + n * 16 + fr;
    const float bias = bo[gn];
    #pragma unroll
    for (int m = 0; m < 4; ++m) {
      #pragma unroll
      for (int j = 0; j < 4; ++j) {
        const int gm = m0 + wm * 64 + m * 16 + fj + j;
        if (gm < B_ * L_) out[(size_t)gm * C_ + gn] = acc[m][n][j] + bias;
      }
    }
  }
}

// ---------------------------------------------------------------------------
// Fused depthwise 3x3 conv + LayerNorm(64) for q/k/v (blockIdx.y selects).
// ---------------------------------------------------------------------------
__global__ __launch_bounds__(256) void pool_ln_fused(
    const float* __restrict__ q_raw, const float* __restrict__ k_raw,
    const float* __restrict__ v_raw,
    const float* __restrict__ qw, const float* __restrict__ kw,
    const float* __restrict__ vw,
    const float* __restrict__ qg, const float* __restrict__ qb2,
    const float* __restrict__ kg, const float* __restrict__ kb2,
    const float* __restrict__ vg, const float* __restrict__ vb2,
    unsigned short* __restrict__ Qp2, unsigned short* __restrict__ Kp2a,
    unsigned short* __restrict__ Vtmp) {
  const int which = blockIdx.y;
  const float* in = (which == 0) ? q_raw : (which == 1) ? k_raw : v_raw;
  const float* w  = (which == 0) ? qw : (which == 1) ? kw : vw;
  const float* g  = (which == 0) ? qg : (which == 1) ? kg : vg;
  const float* bb = (which == 0) ? qb2 : (which == 1) ? kb2 : vb2;
  unsigned short* out = (which == 0) ? Qp2 : (which == 1) ? Kp2a : Vtmp;
  const int stride = (which == 0) ? DP_ : 64;
  const float scale = (which == 1) ? SCALE_K : 1.f;

  const int row = blockIdx.x * 4 + (threadIdx.x >> 6);
  const int d = threadIdx.x & 63;
  const int bh = row / L_;
  const int l  = row % L_;
  const int t  = l / S_;
  const int sq = l % S_;
  const int x = sq / W_, y = sq % W_;
  const float* base = in + ((size_t)bh * L_ + t * S_) * HD_;
  float acc = 0.f;
  #pragma unroll
  for (int dx = 0; dx < 3; ++dx) {
    const int xx = x + dx - 1;
    if (xx < 0 || xx >= H_) continue;
    #pragma unroll
    for (int dy = 0; dy < 3; ++dy) {
      const int yy = y + dy - 1;
      if (yy < 0 || yy >= W_) continue;
      acc += base[(size_t)(xx * W_ + yy) * HD_ + d] * w[(dx * 3 + dy) * HD_ + d];
    }
  }
  float s1 = acc, s2 = acc * acc;
  #pragma unroll
  for (int off = 32; off; off >>= 1) {
    s1 += __shfl_xor(s1, off);
    s2 += __shfl_xor(s2, off);
  }
  const float mu = s1 * (1.f / 64.f);
  const float var = s2 * (1.f / 64.f) - mu * mu;
  const float val = (acc - mu) * rsqrtf(var + LN_EPS) * g[d] + bb[d];
  out[(size_t)row * stride + d] = f2bf(val * scale);
}

// ---------------------------------------------------------------------------
// Transpose V per head: Vtmp [bh][L][64] bf16 -> VpT [bh][64][L] bf16
// ---------------------------------------------------------------------------
__global__ __launch_bounds__(256) void transpose_v(
    const unsigned short* __restrict__ Vtmp, unsigned short* __restrict__ VpT) {
  __shared__ unsigned short tile[32][72];
  const int bh = blockIdx.y;
  const int l0 = blockIdx.x * 32;
  const int t = threadIdx.x;
  {
    const int r = t >> 3, c8 = (t & 7) * 8;
    u32x4 v = *(const u32x4*)(Vtmp + ((size_t)bh * L_ + l0 + r) * 64 + c8);
    *(u32x4*)&tile[r][c8] = v;
  }
  __syncthreads();
  const int d = t >> 2, gq = t & 3;
  unsigned short o[8];
  #pragma unroll
  for (int i = 0; i < 8; ++i) o[i] = tile[gq*8 + i][d];
  u32x4 ov;
  ov.x = (uint_)o[0] | ((uint_)o[1] << 16);
  ov.y = (uint_)o[2] | ((uint_)o[3] << 16);
  ov.z = (uint_)o[4] | ((uint_)o[5] << 16);
  ov.w = (uint_)o[6] | ((uint_)o[7] << 16);
  *(u32x4*)(VpT + ((size_t)bh * 64 + d) * L_ + l0 + gq*8) = ov;
}

// ---------------------------------------------------------------------------
// rel-pos via MFMA: per (bh,t), P_h = Q * Rhb^T, P_w = Q * Rwb^T (tables
// LOG2E-folded). Bias row segments are contiguous reversed slices of P.
// 1 wave per 16-row M-tile; grid (49, 48).
// ---------------------------------------------------------------------------
__global__ __launch_bounds__(64) void relpos_mfma(
    unsigned short* __restrict__ Qp2,
    const unsigned short* __restrict__ Rhb,
    const unsigned short* __restrict__ Rwb) {
  __shared__ float P[16][128];
  const int qt = blockIdx.x;          // 0..48
  const int bt = blockIdx.y;          // 0..47
  const int bh = bt >> 1, t = bt & 1;
  const int lane = threadIdx.x;
  const int fr = lane & 15, fk = (lane >> 4) * 8;

  const size_t rowbase = (size_t)bh * L_ + t * S_ + qt * 16;
  const unsigned short* arow = Qp2 + (rowbase + fr) * DP_ + fk;
  const bf16x8 a0 = *(const bf16x8*)(arow);
  const bf16x8 a1 = *(const bf16x8*)(arow + 32);

  f32x4 acch[4] = {}, accw[4] = {};
  #pragma unroll
  for (int n = 0; n < 4; ++n) {
    const unsigned short* bh_ = Rhb + (n * 16 + fr) * 64 + fk;
    const unsigned short* bw_ = Rwb + (n * 16 + fr) * 64 + fk;
    acch[n] = __builtin_amdgcn_mfma_f32_16x16x32_bf16(a0, *(const bf16x8*)bh_, acch[n], 0, 0, 0);
    acch[n] = __builtin_amdgcn_mfma_f32_16x16x32_bf16(a1, *(const bf16x8*)(bh_ + 32), acch[n], 0, 0, 0);
    accw[n] = __builtin_amdgcn_mfma_f32_16x16x32_bf16(a0, *(const bf16x8*)bw_, accw[n], 0, 0, 0);
    accw[n] = __builtin_amdgcn_mfma_f32_16x16x32_bf16(a1, *(const bf16x8*)(bw_ + 32), accw[n], 0, 0, 0);
  }
  // C layout: row = (lane>>4)*4 + j, col = n*16 + (lane&15)
  #pragma unroll
  for (int n = 0; n < 4; ++n)
    #pragma unroll
    for (int j = 0; j < 4; ++j) {
      P[(lane >> 4) * 4 + j][n * 16 + fr]      = acch[n][j];
      P[(lane >> 4) * 4 + j][64 + n * 16 + fr] = accw[n][j];
    }
  __syncthreads();

  // gather (row-local, contiguous reversed) + coalesced u32 writes
  if (lane < 56) {
    const int e0 = lane * 2;          // u16 index pair (e0, e0+1), same half
    const int tb = e0 / 56;
    const int tw0 = e0 % 56;
    #pragma unroll
    for (int r = 0; r < 16; ++r) {
      const int sq = qt * 16 + r;
      const int x = sq / W_, y = sq % W_;
      float v0 = 0.f, v1 = 0.f;
      if (tb == t) {
        if (tw0 < 28) {
          v0 = P[r][x - tw0 + 27];
          v1 = P[r][x - tw0 + 26];
        } else {
          const int k0 = tw0 - 28;
          v0 = P[r][64 + y - k0 + 27];
          v1 = P[r][64 + y - k0 + 26];
        }
      }
      *(uint_*)(Qp2 + (rowbase + r) * DP_ + 64 + e0) = cvtpk(v0, v1);
    }
  }
}

// ---------------------------------------------------------------------------
// MFMA flash attention. 256 thr (4 waves), grid 1176 (XCD-swizzled).
// Fixed-base softmax: P = exp2(s) directly (scores bounded, no running max).
// 2-tile pipeline; K double-buffered, V issued a phase early.
// ---------------------------------------------------------------------------
__device__ __forceinline__ void load_k(
    const unsigned short* kbase, int kt,
    u32x4& k0, u32x4& k1, u32x4& k2, u32x4& k3) {
  const unsigned short* kr = kbase + (size_t)kt * 2048;
  k0 = *(const u32x4*)(kr);
  k1 = *(const u32x4*)(kr + 16);
  k2 = *(const u32x4*)(kr + 32);
  k3 = *(const u32x4*)(kr + 48);
}

__device__ __forceinline__ void load_v(
    const unsigned short* vbase0, int kt,
    u32x4& va, u32x4& vb, u32x4& vc, u32x4& vd) {
  const unsigned short* vr = vbase0 + kt * 32;
  va = *(const u32x4*)(vr);
  vb = *(const u32x4*)(vr + 16);
  vc = *(const u32x4*)(vr + 32 * L_);
  vd = *(const u32x4*)(vr + 32 * L_ + 16);
}

template<bool BIAS>
__device__ __forceinline__ f32x16 qk_tile(
    int kt, int lo, int hi, const u32x4 (&qf)[4],
    const unsigned short* __restrict__ qbias,
    u32x4 k0, u32x4 k1, u32x4 k2, u32x4 k3) {
  f32x16 s = {};
  s = __builtin_amdgcn_mfma_f32_32x32x16_bf16(BC8(k0), BC8(qf[0]), s, 0, 0, 0);
  s = __builtin_amdgcn_mfma_f32_32x32x16_bf16(BC8(k1), BC8(qf[1]), s, 0, 0, 0);
  s = __builtin_amdgcn_mfma_f32_32x32x16_bf16(BC8(k2), BC8(qf[2]), s, 0, 0, 0);
  s = __builtin_amdgcn_mfma_f32_32x32x16_bf16(BC8(k3), BC8(qf[3]), s, 0, 0, 0);
  if (BIAS) {
    const int kr = kt * 32 + lo;
    const int t = (kr >= S_) ? 1 : 0;
    const int sk = kr - t * S_;
    const int x = sk / W_, y = sk - x * W_;
    const int p1 = 64 + t*56 + x;
    const int p2 = 64 + t*56 + 28 + y;
    const uint_ v1 = 0x3F80u << ((p1 & 1) << 4);
    const uint_ v2 = 0x3F80u << ((p2 & 1) << 4);
    const int g1 = p1 >> 3, g2 = p2 >> 3;
    const int w1 = (p1 >> 1) & 3, w2 = (p2 >> 1) & 3;
    #pragma unroll
    for (int c = 4; c < 11; ++c) {
      const int gg = 2*c + hi;
      u32x4 oh;
      oh.x = ((g1 == gg && w1 == 0) ? v1 : 0u) | ((g2 == gg && w2 == 0) ? v2 : 0u);
      oh.y = ((g1 == gg && w1 == 1) ? v1 : 0u) | ((g2 == gg && w2 == 1) ? v2 : 0u);
      oh.z = ((g1 == gg && w1 == 2) ? v1 : 0u) | ((g2 == gg && w2 == 2) ? v2 : 0u);
      oh.w = ((g1 == gg && w1 == 3) ? v1 : 0u) | ((g2 == gg && w2 == 3) ? v2 : 0u);
      const u32x4 qb = *(const u32x4*)(qbias + (c - 4) * 16);
      s = __builtin_amdgcn_mfma_f32_32x32x16_bf16(BC8(oh), BC8(qb), s, 0, 0, 0);
    }
  }
  return s;
}

__device__ __forceinline__ void sm_pv(
    const f32x16& s,
    u32x4 va, u32x4 vb, u32x4 vc, u32x4 vd,
    f32x16& acc0, f32x16& acc1, float& l_run) {
  uint_ pw0, pw1, pw2, pw3, pw4, pw5, pw6, pw7;
  {
    float a, b;
    a = exp2f(s[0]);  b = exp2f(s[1]);  l_run += a+b; pw0 = cvtpk(a,b);
    a = exp2f(s[2]);  b = exp2f(s[3]);  l_run += a+b; pw1 = cvtpk(a,b);
    a = exp2f(s[4]);  b = exp2f(s[5]);  l_run += a+b; pw2 = cvtpk(a,b);
    a = exp2f(s[6]);  b = exp2f(s[7]);  l_run += a+b; pw3 = cvtpk(a,b);
    a = exp2f(s[8]);  b = exp2f(s[9]);  l_run += a+b; pw4 = cvtpk(a,b);
    a = exp2f(s[10]); b = exp2f(s[11]); l_run += a+b; pw5 = cvtpk(a,b);
    a = exp2f(s[12]); b = exp2f(s[13]); l_run += a+b; pw6 = cvtpk(a,b);
    a = exp2f(s[14]); b = exp2f(s[15]); l_run += a+b; pw7 = cvtpk(a,b);
  }
  auto sA = __builtin_amdgcn_permlane32_swap(pw0, pw2, false, false);
  auto sB = __builtin_amdgcn_permlane32_swap(pw1, pw3, false, false);
  auto sC = __builtin_amdgcn_permlane32_swap(pw4, pw6, false, false);
  auto sD = __builtin_amdgcn_permlane32_swap(pw5, pw7, false, false);
  u32x4 pa0, pa1;
  pa0.x = sA[0]; pa0.y = sB[0]; pa0.z = sA[1]; pa0.w = sB[1];
  pa1.x = sC[0]; pa1.y = sD[0]; pa1.z = sC[1]; pa1.w = sD[1];

  acc0 = __builtin_amdgcn_mfma_f32_32x32x16_bf16(BC8(pa0), BC8(va), acc0, 0, 0, 0);
  acc0 = __builtin_amdgcn_mfma_f32_32x32x16_bf16(BC8(pa1), BC8(vb), acc0, 0, 0, 0);
  acc1 = __builtin_amdgcn_mfma_f32_32x32x16_bf16(BC8(pa0), BC8(vc), acc1, 0, 0, 0);
  acc1 = __builtin_amdgcn_mfma_f32_32x32x16_bf16(BC8(pa1), BC8(vd), acc1, 0, 0, 0);
}

__device__ __forceinline__ bool bias_needed(int kt, int qt) {
  const int kmin = (kt * 32 >= S_) ? 1 : 0;
  const int kmax = (kt * 32 + 31 >= S_) ? 1 : 0;
  const int qmin = (qt * 32 >= S_) ? 1 : 0;
  const int qmax = (qt * 32 + 31 >= S_) ? 1 : 0;
  return (kmin <= qmax) && (qmin <= kmax);
}

__global__ __launch_bounds__(256) void attn_mfma(
    const unsigned short* __restrict__ Qp2, const unsigned short* __restrict__ Kp2a,
    const unsigned short* __restrict__ VpT,
    unsigned short* __restrict__ Abf) {
  __shared__ float red_acc[3][32][64];
  __shared__ float red_l[4][32];

  const int id0 = blockIdx.x;                  // 1176 = 8 * 147
  const int swz = (id0 & 7) * 147 + (id0 >> 3);
  const int qt = swz % 49;
  const int bh = swz / 49;

  const int lane = threadIdx.x & 63;
  const int wv = threadIdx.x >> 6;             // 0..3
  const int lo = lane & 31, hi = lane >> 5;
  const int q0 = qt * 32;

  const unsigned short* qrow = Qp2 + ((size_t)bh * L_ + q0 + lo) * DP_ + hi * 8;
  u32x4 qf[4];
  #pragma unroll
  for (int c = 0; c < 4; ++c) qf[c] = *(const u32x4*)(qrow + c * 16);
  const unsigned short* qbias = qrow + 64;

  const unsigned short* kbase = Kp2a + ((size_t)bh * L_ + lo) * 64 + hi * 8;
  const unsigned short* vbase0 = VpT + (size_t)bh * 64 * L_ + (size_t)lo * L_ + hi * 8;

  f32x16 acc0 = {}, acc1 = {};
  float l_run = 0.f;
  const int nt = (49 - wv + 3) >> 2;           // wave wv: tiles kt = wv + 4*j

  #define KT(j) (wv + 4 * (j))
  #define QK(j, K0, K1, K2, K3) \
    (bias_needed(KT(j), qt) \
      ? qk_tile<true>(KT(j), lo, hi, qf, qbias, K0, K1, K2, K3) \
      : qk_tile<false>(KT(j), lo, hi, qf, qbias, K0, K1, K2, K3))

  u32x4 kA0, kA1, kA2, kA3, kB0, kB1, kB2, kB3;
  u32x4 va, vb, vc, vd;

  load_k(kbase, KT(0), kA0, kA1, kA2, kA3);
  load_k(kbase, KT(1), kB0, kB1, kB2, kB3);
  f32x16 s_prev = QK(0, kA0, kA1, kA2, kA3);

  int j = 1;
  for (; j + 1 < nt; j += 2) {
    load_v(vbase0, KT(j - 1), va, vb, vc, vd);
    f32x16 s_cur = QK(j, kB0, kB1, kB2, kB3);
    load_k(kbase, KT(j + 1), kA0, kA1, kA2, kA3);
    sm_pv(s_prev, va, vb, vc, vd, acc0, acc1, l_run);
    s_prev = s_cur;
    load_v(vbase0, KT(j), va, vb, vc, vd);
    f32x16 s_cur2 = QK(j + 1, kA0, kA1, kA2, kA3);
    const int pf = (j + 2 < nt) ? j + 2 : nt - 1;
    load_k(kbase, KT(pf), kB0, kB1, kB2, kB3);
    sm_pv(s_prev, va, vb, vc, vd, acc0, acc1, l_run);
    s_prev = s_cur2;
  }
  if (j < nt) {
    load_v(vbase0, KT(j - 1), va, vb, vc, vd);
    f32x16 s_cur = QK(j, kB0, kB1, kB2, kB3);
    sm_pv(s_prev, va, vb, vc, vd, acc0, acc1, l_run);
    s_prev = s_cur;
  }
  load_v(vbase0, KT(nt - 1), va, vb, vc, vd);
  sm_pv(s_prev, va, vb, vc, vd, acc0, acc1, l_run);
  #undef QK
  #undef KT

  l_run += __shfl_xor(l_run, 32);

  if (hi == 0) red_l[wv][lo] = l_run;
  if (wv >= 1) {
    #pragma unroll
    for (int r = 0; r < 16; ++r) {
      const int row = (r & 3) + 8*(r >> 2) + 4*hi;
      red_acc[wv-1][row][lo]      = acc0[r];
      red_acc[wv-1][row][32 + lo] = acc1[r];
    }
  }
  __syncthreads();
  if (wv == 0) {
    const int b = bh / NH_, h = bh % NH_;
    #pragma unroll
    for (int r = 0; r < 16; ++r) {
      const int row = (r & 3) + 8*(r >> 2) + 4*hi;
      const float inv = 1.0f / (red_l[0][row] + red_l[1][row] +
                                red_l[2][row] + red_l[3][row]);
      const float o0 = (acc0[r] + red_acc[0][row][lo] +
                        red_acc[1][row][lo] + red_acc[2][row][lo]) * inv;
      const float o1 = (acc1[r] + red_acc[0][row][32+lo] +
                        red_acc[1][row][32+lo] + red_acc[2][row][32+lo]) * inv;
      const size_t qoff = ((size_t)bh * L_ + q0 + row) * DP_ + lo;
      const size_t ooff = ((size_t)(b * L_ + q0 + row)) * C_ + h * 64 + lo;
      Abf[ooff]      = f2bf(o0 + bf2f(Qp2[qoff]));
      Abf[ooff + 32] = f2bf(o1 + bf2f(Qp2[qoff + 32]));
    }
  }
}

// ---------------------------------------------------------------------------
extern "C" void kernel_launch(void* const* d_in, const int* in_sizes, int n_in,
                              void* d_out, int out_size, void* d_ws, size_t ws_size,
                              hipStream_t stream) {
  const float* x         = (const float*)d_in[0];
  const float* qkv_w     = (const float*)d_in[1];
  const float* out_w     = (const float*)d_in[2];
  const float* out_b     = (const float*)d_in[3];
  const float* q_pool_w  = (const float*)d_in[4];
  const float* k_pool_w  = (const float*)d_in[5];
  const float* v_pool_w  = (const float*)d_in[6];
  const float* q_ln_g    = (const float*)d_in[7];
  const float* q_ln_b    = (const float*)d_in[8];
  const float* k_ln_g    = (const float*)d_in[9];
  const float* k_ln_b    = (const float*)d_in[10];
  const float* v_ln_g    = (const float*)d_in[11];
  const float* v_ln_b    = (const float*)d_in[12];
  const float* rel_pos_h = (const float*)d_in[13];
  const float* rel_pos_w = (const float*)d_in[14];

  float* R = (float*)d_ws;
  const size_t NQ = (size_t)B_ * NH_ * L_ * HD_;   // 2,408,448 f32 slots
  float* q_raw = R;
  unsigned short* Abf = (unsigned short*)R;
  float* k_raw = R + NQ;
  unsigned short* VpT = (unsigned short*)(R + NQ);
  float* v_raw = R + 2*NQ;
  const size_t D_off = 3*NQ;
  unsigned short* Xbf = (unsigned short*)(R + D_off);
  unsigned short* Qp2 = (unsigned short*)(R + D_off);
  const size_t E_off = D_off + 3311616;
  unsigned short* Kp2a = (unsigned short*)(R + E_off);
  const size_t F_off = E_off + 1204224;
  unsigned short* Wbf  = (unsigned short*)(R + F_off);
  unsigned short* Vtmp = (unsigned short*)(R + F_off);
  const size_t G_off = F_off + 1204224;
  unsigned short* Wobf = (unsigned short*)(R + G_off);
  const size_t H_off = G_off + 294912;
  unsigned short* Rhb = (unsigned short*)(R + H_off);          // 4096 u16
  unsigned short* Rwb = (unsigned short*)(R + H_off + 2048);   // 4096 u16

  cvt_all<<<2328, 256, 0, stream>>>(x, 3136*768, Xbf,
                                    qkv_w, 2304*768, Wbf,
                                    out_w, 768*768, Wobf);
  cvt_rel<<<16, 256, 0, stream>>>(rel_pos_h, rel_pos_w, Rhb, Rwb);
  qkv_gemm_mfma<<<dim3(18, 25), 256, 0, stream>>>(Xbf, Wbf, q_raw, k_raw, v_raw);
  pool_ln_fused<<<dim3(9408, 3), 256, 0, stream>>>(
      q_raw, k_raw, v_raw, q_pool_w, k_pool_w, v_pool_w,
      q_ln_g, q_ln_b, k_ln_g, k_ln_b, v_ln_g, v_ln_b, Qp2, Kp2a, Vtmp);
  transpose_v<<<dim3(49, 24), 256, 0, stream>>>(Vtmp, VpT);
  relpos_mfma<<<dim3(49, 48), 64, 0, stream>>>(Qp2, Rhb, Rwb);
  attn_mfma<<<1176, 256, 0, stream>>>(Qp2, Kp2a, VpT, Abf);
  proj_gemm_mfma<<<dim3(6, 25), 256, 0, stream>>>(Abf, Wobf, out_b, (float*)d_out);
}

// Round 12
// 168.998 us; speedup vs baseline: 1.7174x; 1.0914x over previous
//
#include <hip/hip_runtime.h>
#include <math.h>

#define B_ 2
#define T_ 2
#define H_ 28
#define W_ 28
#define S_ (H_*W_)      /* 784  */
#define L_ (T_*S_)      /* 1568 */
#define C_ 768
#define NH_ 12
#define HD_ 64
#define LN_EPS 1e-5f
#define LOG2E 1.4426950408889634f
#define SCALE_K (0.125f * LOG2E)   /* hd^-0.5 * log2e folded into K' */

typedef unsigned int uint_;
typedef unsigned int u32x4 __attribute__((ext_vector_type(4)));
typedef __bf16 bf16x8 __attribute__((ext_vector_type(8)));
typedef float f32x4 __attribute__((ext_vector_type(4)));
typedef float f32x16 __attribute__((ext_vector_type(16)));

#define BC8(x) __builtin_bit_cast(bf16x8, (x))

__device__ __forceinline__ unsigned short f2bf(float f) {
  uint_ u = __builtin_bit_cast(uint_, f);
  u += 0x7FFFu + ((u >> 16) & 1u);
  return (unsigned short)(u >> 16);
}
__device__ __forceinline__ float bf2f(unsigned short h) {
  return __builtin_bit_cast(float, ((uint_)h) << 16);
}
__device__ __forceinline__ uint_ cvtpk(float a, float b) {
  uint_ r;
  asm("v_cvt_pk_bf16_f32 %0, %1, %2" : "=v"(r) : "v"(a), "v"(b));
  return r;
}
__device__ __forceinline__ void gload16(const void* g, void* l) {
  __builtin_amdgcn_global_load_lds(
      (const __attribute__((address_space(1))) unsigned int*)g,
      (__attribute__((address_space(3))) unsigned int*)l, 16, 0, 0);
}

// ---------------------------------------------------------------------------
// Fused f32 -> bf16 convert for x / qkv_w / out_w (range-dispatched)
// ---------------------------------------------------------------------------
__global__ __launch_bounds__(256) void cvt_all(
    const float* __restrict__ s0, int n0, unsigned short* __restrict__ d0,
    const float* __restrict__ s1, int n1, unsigned short* __restrict__ d1,
    const float* __restrict__ s2, int n2, unsigned short* __restrict__ d2) {
  int i = (blockIdx.x * 256 + threadIdx.x) * 8;
  const float* s; unsigned short* d;
  if (i < n0) { s = s0; d = d0; }
  else if (i < n0 + n1) { i -= n0; s = s1; d = d1; }
  else { i -= n0 + n1; if (i >= n2) return; s = s2; d = d2; }
  float4 a = *(const float4*)(s + i);
  float4 b = *(const float4*)(s + i + 4);
  u32x4 o;
  o.x = cvtpk(a.x, a.y); o.y = cvtpk(a.z, a.w);
  o.z = cvtpk(b.x, b.y); o.w = cvtpk(b.z, b.w);
  *(u32x4*)(d + i) = o;
}

// ---------------------------------------------------------------------------
// rel-pos tables -> bf16, LOG2E folded, padded to [64][64]
// ---------------------------------------------------------------------------
__global__ __launch_bounds__(256) void cvt_rel(
    const float* __restrict__ rph, const float* __restrict__ rpw,
    unsigned short* __restrict__ Rhb, unsigned short* __restrict__ Rwb) {
  const int i = blockIdx.x * 256 + threadIdx.x;   // 0..4095
  if (i >= 4096) return;
  const int j = i >> 6;
  const unsigned short vh = (j < 2*H_-1) ? f2bf(rph[i] * LOG2E) : 0;
  const unsigned short vw = (j < 2*W_-1) ? f2bf(rpw[i] * LOG2E) : 0;
  Rhb[i] = vh;
  Rwb[i] = vw;
}

// ---------------------------------------------------------------------------
// bf16 MFMA GEMM core: C = A * B^T, 128x128 tile, BK=32, 4 waves
// ---------------------------------------------------------------------------
__device__ __forceinline__ void gemm_core(
    const unsigned short* __restrict__ A, const unsigned short* __restrict__ Bm,
    int K, int m0, int n0, f32x4 (&acc)[4][4]) {
  __shared__ __align__(16) unsigned short As[128 * 32];
  __shared__ __align__(16) unsigned short Bs[128 * 32];
  const int tid = threadIdx.x;
  const int lane = tid & 63;
  const int wv = tid >> 6;
  const int wm = wv >> 1, wn = wv & 1;
  const int srow = tid >> 2, scol = (tid & 3) * 8;
  const int fr = lane & 15, fk = (lane >> 4) * 8;
  const unsigned short* ag = A + (size_t)(m0 + srow) * K + scol;
  const unsigned short* bg = Bm + (size_t)(n0 + srow) * K + scol;
  unsigned short* asd = As + tid * 8;
  unsigned short* bsd = Bs + tid * 8;
  const int arow = wm * 64 + fr;
  const int brow = wn * 64 + fr;
  for (int k0 = 0; k0 < K; k0 += 32) {
    __syncthreads();
    gload16(ag + k0, asd);
    gload16(ag + (size_t)64 * K + k0, asd + 2048);
    gload16(bg + k0, bsd);
    gload16(bg + (size_t)64 * K + k0, bsd + 2048);
    __syncthreads();
    bf16x8 af[4], bfr[4];
    #pragma unroll
    for (int m = 0; m < 4; ++m)
      af[m] = *(const bf16x8*)(As + (arow + m * 16) * 32 + fk);
    #pragma unroll
    for (int n = 0; n < 4; ++n)
      bfr[n] = *(const bf16x8*)(Bs + (brow + n * 16) * 32 + fk);
    #pragma unroll
    for (int m = 0; m < 4; ++m)
      #pragma unroll
      for (int n = 0; n < 4; ++n)
        acc[m][n] = __builtin_amdgcn_mfma_f32_16x16x32_bf16(af[m], bfr[n], acc[m][n], 0, 0, 0);
  }
}

// ---------------------------------------------------------------------------
// QKV GEMM: Xbf[3200][768] * Wbf[2304][768]^T -> scatter f32 q/k/v [B,NH,L,HD]
// ---------------------------------------------------------------------------
__global__ __launch_bounds__(256) void qkv_gemm_mfma(
    const unsigned short* __restrict__ Xbf, const unsigned short* __restrict__ Wbf,
    float* __restrict__ q_raw, float* __restrict__ k_raw, float* __restrict__ v_raw) {
  f32x4 acc[4][4] = {};
  const int m0 = blockIdx.y * 128;
  const int n0 = blockIdx.x * 128;
  gemm_core(Xbf, Wbf, C_, m0, n0, acc);
  const int lane = threadIdx.x & 63;
  const int wv = threadIdx.x >> 6;
  const int wm = wv >> 1, wn = wv & 1;
  const int fr = lane & 15, fj = (lane >> 4) * 4;
  #pragma unroll
  for (int n = 0; n < 4; ++n) {
    const int gn = n0 + wn * 64 + n * 16 + fr;
    const int which = (gn >= 2 * C_) ? 2 : ((gn >= C_) ? 1 : 0);
    const int rem = gn - which * C_;
    const int h = rem >> 6, d = rem & 63;
    float* dst = (which == 0) ? q_raw : ((which == 1) ? k_raw : v_raw);
    #pragma unroll
    for (int m = 0; m < 4; ++m) {
      #pragma unroll
      for (int j = 0; j < 4; ++j) {
        const int gm = m0 + wm * 64 + m * 16 + fj + j;
        if (gm < B_ * L_) {
          const int b = (gm >= L_) ? 1 : 0;
          const int l = gm - b * L_;
          dst[(((size_t)b * NH_ + h) * L_ + l) * HD_ + d] = acc[m][n][j];
        }
      }
    }
  }
}

// ---------------------------------------------------------------------------
// Proj GEMM: Abf[3200][768] * Wobf[768][768]^T + bo -> d_out f32
// ---------------------------------------------------------------------------
__global__ __launch_bounds__(256) void proj_gemm_mfma(
    const unsigned short* __restrict__ Abf, const unsigned short* __restrict__ Wobf,
    const float* __restrict__ bo, float* __restrict__ out) {
  f32x4 acc[4][4] = {};
  const int m0 = blockIdx.y * 128;
  const int n0 = blockIdx.x * 128;
  gemm_core(Abf, Wobf, C_, m0, n0, acc);
  const int lane = threadIdx.x & 63;
  const int wv = threadIdx.x >> 6;
  const int wm = wv >> 1, wn = wv & 1;
  const int fr = lane & 15, fj = (lane >> 4) * 4;
  #pragma unroll
  for (int n = 0; n < 4; ++n) {
    const int gn = n0 + wn * 64 + n * 16 + fr;
    const float bias = bo[gn];
    #pragma unroll
    for (int m = 0; m < 4; ++m) {
      #pragma unroll
      for (int j = 0; j < 4; ++j) {
        const int gm = m0 + wm * 64 + m * 16 + fj + j;
        if (gm < B_ * L_) out[(size_t)gm * C_ + gn] = acc[m][n][j] + bias;
      }
    }
  }
}

// ---------------------------------------------------------------------------
// Fused depthwise 3x3 conv + LayerNorm(64) for q/k/v (blockIdx.y selects).
// q -> Qmain row-major [bh][L][64]; k -> Kpack fragment-order; v -> Vtmp.
// ---------------------------------------------------------------------------
__global__ __launch_bounds__(256) void pool_ln_fused(
    const float* __restrict__ q_raw, const float* __restrict__ k_raw,
    const float* __restrict__ v_raw,
    const float* __restrict__ qw, const float* __restrict__ kw,
    const float* __restrict__ vw,
    const float* __restrict__ qg, const float* __restrict__ qb2,
    const float* __restrict__ kg, const float* __restrict__ kb2,
    const float* __restrict__ vg, const float* __restrict__ vb2,
    unsigned short* __restrict__ Qmain, unsigned short* __restrict__ Kpack,
    unsigned short* __restrict__ Vtmp) {
  const int which = blockIdx.y;
  const float* in = (which == 0) ? q_raw : (which == 1) ? k_raw : v_raw;
  const float* w  = (which == 0) ? qw : (which == 1) ? kw : vw;
  const float* g  = (which == 0) ? qg : (which == 1) ? kg : vg;
  const float* bb = (which == 0) ? qb2 : (which == 1) ? kb2 : vb2;
  const float scale = (which == 1) ? SCALE_K : 1.f;

  const int row = blockIdx.x * 4 + (threadIdx.x >> 6);
  const int d = threadIdx.x & 63;
  const int bh = row / L_;
  const int l  = row % L_;
  const int t  = l / S_;
  const int sq = l % S_;
  const int x = sq / W_, y = sq % W_;
  const float* base = in + ((size_t)bh * L_ + t * S_) * HD_;
  float acc = 0.f;
  #pragma unroll
  for (int dx = 0; dx < 3; ++dx) {
    const int xx = x + dx - 1;
    if (xx < 0 || xx >= H_) continue;
    #pragma unroll
    for (int dy = 0; dy < 3; ++dy) {
      const int yy = y + dy - 1;
      if (yy < 0 || yy >= W_) continue;
      acc += base[(size_t)(xx * W_ + yy) * HD_ + d] * w[(dx * 3 + dy) * HD_ + d];
    }
  }
  float s1 = acc, s2 = acc * acc;
  #pragma unroll
  for (int off = 32; off; off >>= 1) {
    s1 += __shfl_xor(s1, off);
    s2 += __shfl_xor(s2, off);
  }
  const float mu = s1 * (1.f / 64.f);
  const float var = s2 * (1.f / 64.f) - mu * mu;
  const unsigned short val = f2bf(((acc - mu) * rsqrtf(var + LN_EPS) * g[d] + bb[d]) * scale);
  if (which == 1) {
    // Kpack[(bh*49+kt)*4 + c][lane2][e]: value = K'[bh][kt*32+(lane2&31)][c*16+(lane2>>5)*8+e]
    const int kt = l >> 5;
    const int c = d >> 4;
    const int lane2 = (((d >> 3) & 1) << 5) | (l & 31);
    Kpack[((((size_t)bh * 49 + kt) * 4 + c) * 64 + lane2) * 8 + (d & 7)] = val;
  } else if (which == 0) {
    Qmain[(size_t)row * 64 + d] = val;
  } else {
    Vtmp[(size_t)row * 64 + d] = val;
  }
}

// ---------------------------------------------------------------------------
// V pack: Vtmp [bh][L][64] -> Vpack fragment-order (LDS transpose per 32-tile)
// Vpack[(bh*49+kt)*4 + c][lane][e] = V[kt*32 + (c&1)*16 + (lane>>5)*8 + e]
//                                     [(c>>1)*32 + (lane&31)]
// ---------------------------------------------------------------------------
__global__ __launch_bounds__(256) void vpack_kernel(
    const unsigned short* __restrict__ Vtmp, unsigned short* __restrict__ Vpack) {
  __shared__ unsigned short tile[32][72];
  const int bh = blockIdx.y;
  const int kt = blockIdx.x;
  const int l0 = kt * 32;
  const int t = threadIdx.x;
  {
    const int r = t >> 3, c8 = (t & 7) * 8;
    u32x4 v = *(const u32x4*)(Vtmp + ((size_t)bh * L_ + l0 + r) * 64 + c8);
    *(u32x4*)&tile[r][c8] = v;
  }
  __syncthreads();
  const int d = t >> 2, gq = t & 3;
  unsigned short o[8];
  #pragma unroll
  for (int i = 0; i < 8; ++i) o[i] = tile[gq*8 + i][d];
  u32x4 ov;
  ov.x = (uint_)o[0] | ((uint_)o[1] << 16);
  ov.y = (uint_)o[2] | ((uint_)o[3] << 16);
  ov.z = (uint_)o[4] | ((uint_)o[5] << 16);
  ov.w = (uint_)o[6] | ((uint_)o[7] << 16);
  const int c = ((d >> 5) << 1) | (gq >> 1);
  const int lane2 = ((gq & 1) << 5) | (d & 31);
  *(u32x4*)(Vpack + ((((size_t)bh * 49 + kt) * 4 + c) * 64 + lane2) * 8) = ov;
}

// ---------------------------------------------------------------------------
// rel-pos via MFMA: P_h = Q*Rhb^T, P_w = Q*Rwb^T; bias rows are contiguous
// reversed slices of P. Writes QbiasPack fragment-order (incl. zero T-block).
// QbiasPack[(bh*49+qt32)*7 + cb][lane][e] = bias[row: row&31=lane&31]
//                                            [cb*16 + (lane>>5)*8 + e]
// ---------------------------------------------------------------------------
__global__ __launch_bounds__(64) void relpos_mfma(
    const unsigned short* __restrict__ Qmain,
    const unsigned short* __restrict__ Rhb,
    const unsigned short* __restrict__ Rwb,
    unsigned short* __restrict__ QbiasPack) {
  __shared__ float P[16][128];
  const int qt16 = blockIdx.x;        // 0..48 (16-row tiles within (bh,t))
  const int bt = blockIdx.y;          // 0..47
  const int bh = bt >> 1, t = bt & 1;
  const int lane = threadIdx.x;
  const int fr = lane & 15, fk = (lane >> 4) * 8;

  const size_t rowbase = (size_t)bh * L_ + t * S_ + qt16 * 16;
  const unsigned short* arow = Qmain + (rowbase + fr) * 64 + fk;
  const bf16x8 a0 = *(const bf16x8*)(arow);
  const bf16x8 a1 = *(const bf16x8*)(arow + 32);

  f32x4 acch[4] = {}, accw[4] = {};
  #pragma unroll
  for (int n = 0; n < 4; ++n) {
    const unsigned short* bh_ = Rhb + (n * 16 + fr) * 64 + fk;
    const unsigned short* bw_ = Rwb + (n * 16 + fr) * 64 + fk;
    acch[n] = __builtin_amdgcn_mfma_f32_16x16x32_bf16(a0, *(const bf16x8*)bh_, acch[n], 0, 0, 0);
    acch[n] = __builtin_amdgcn_mfma_f32_16x16x32_bf16(a1, *(const bf16x8*)(bh_ + 32), acch[n], 0, 0, 0);
    accw[n] = __builtin_amdgcn_mfma_f32_16x16x32_bf16(a0, *(const bf16x8*)bw_, accw[n], 0, 0, 0);
    accw[n] = __builtin_amdgcn_mfma_f32_16x16x32_bf16(a1, *(const bf16x8*)(bw_ + 32), accw[n], 0, 0, 0);
  }
  #pragma unroll
  for (int n = 0; n < 4; ++n)
    #pragma unroll
    for (int j = 0; j < 4; ++j) {
      P[(lane >> 4) * 4 + j][n * 16 + fr]      = acch[n][j];
      P[(lane >> 4) * 4 + j][64 + n * 16 + fr] = accw[n][j];
    }
  __syncthreads();

  if (lane < 56) {
    const int e0 = lane * 2;          // bias element pair (e0, e0+1)
    const int tb = e0 / 56;
    const int tw0 = e0 % 56;
    const int cb = e0 >> 4;
    const int hi2 = (e0 >> 3) & 1;
    const int ee = e0 & 7;
    #pragma unroll
    for (int r = 0; r < 16; ++r) {
      const int gl = t * S_ + qt16 * 16 + r;    // global row 0..1567
      const int sq = qt16 * 16 + r;
      const int x = sq / W_, y = sq % W_;
      float v0 = 0.f, v1 = 0.f;
      if (tb == t) {
        if (tw0 < 28) {
          v0 = P[r][x - tw0 + 27];
          v1 = P[r][x - tw0 + 26];
        } else {
          const int k0 = tw0 - 28;
          v0 = P[r][64 + y - k0 + 27];
          v1 = P[r][64 + y - k0 + 26];
        }
      }
      const int lane2 = (hi2 << 5) | (gl & 31);
      unsigned short* dst = QbiasPack +
          ((((size_t)bh * 49 + (gl >> 5)) * 7 + cb) * 64 + lane2) * 8 + ee;
      *(uint_*)dst = cvtpk(v0, v1);
    }
  }
}

// ---------------------------------------------------------------------------
// MFMA flash attention. 256 thr (4 waves), grid 1176 (XCD-swizzled).
// All operands in fragment-packed layout -> every load fully coalesced.
// Fixed-base softmax; 2-tile pipeline.
// ---------------------------------------------------------------------------
__device__ __forceinline__ void load_k(
    const unsigned short* kbase, int kt,
    u32x4& k0, u32x4& k1, u32x4& k2, u32x4& k3) {
  const unsigned short* kp = kbase + (size_t)kt * 2048;
  k0 = *(const u32x4*)(kp);
  k1 = *(const u32x4*)(kp + 512);
  k2 = *(const u32x4*)(kp + 1024);
  k3 = *(const u32x4*)(kp + 1536);
}

__device__ __forceinline__ void load_v(
    const unsigned short* vbase, int kt,
    u32x4& va, u32x4& vb, u32x4& vc, u32x4& vd) {
  const unsigned short* vp = vbase + (size_t)kt * 2048;
  va = *(const u32x4*)(vp);
  vb = *(const u32x4*)(vp + 512);
  vc = *(const u32x4*)(vp + 1024);
  vd = *(const u32x4*)(vp + 1536);
}

template<bool BIAS>
__device__ __forceinline__ f32x16 qk_tile(
    int kt, int lo, int hi, const u32x4 (&qf)[4],
    const unsigned short* __restrict__ qbias,   // QbiasPack block base + lane*8
    u32x4 k0, u32x4 k1, u32x4 k2, u32x4 k3) {
  f32x16 s = {};
  s = __builtin_amdgcn_mfma_f32_32x32x16_bf16(BC8(k0), BC8(qf[0]), s, 0, 0, 0);
  s = __builtin_amdgcn_mfma_f32_32x32x16_bf16(BC8(k1), BC8(qf[1]), s, 0, 0, 0);
  s = __builtin_amdgcn_mfma_f32_32x32x16_bf16(BC8(k2), BC8(qf[2]), s, 0, 0, 0);
  s = __builtin_amdgcn_mfma_f32_32x32x16_bf16(BC8(k3), BC8(qf[3]), s, 0, 0, 0);
  if (BIAS) {
    const int kr = kt * 32 + lo;
    const int t = (kr >= S_) ? 1 : 0;
    const int sk = kr - t * S_;
    const int x = sk / W_, y = sk - x * W_;
    const int p1 = t*56 + x;          // bias-space index 0..111
    const int p2 = t*56 + 28 + y;
    const uint_ v1 = 0x3F80u << ((p1 & 1) << 4);
    const uint_ v2 = 0x3F80u << ((p2 & 1) << 4);
    const int g1 = p1 >> 3, g2 = p2 >> 3;
    const int w1 = (p1 >> 1) & 3, w2 = (p2 >> 1) & 3;
    #pragma unroll
    for (int c = 0; c < 7; ++c) {
      const int gg = 2*c + hi;
      u32x4 oh;
      oh.x = ((g1 == gg && w1 == 0) ? v1 : 0u) | ((g2 == gg && w2 == 0) ? v2 : 0u);
      oh.y = ((g1 == gg && w1 == 1) ? v1 : 0u) | ((g2 == gg && w2 == 1) ? v2 : 0u);
      oh.z = ((g1 == gg && w1 == 2) ? v1 : 0u) | ((g2 == gg && w2 == 2) ? v2 : 0u);
      oh.w = ((g1 == gg && w1 == 3) ? v1 : 0u) | ((g2 == gg && w2 == 3) ? v2 : 0u);
      const u32x4 qb = *(const u32x4*)(qbias + c * 512);
      s = __builtin_amdgcn_mfma_f32_32x32x16_bf16(BC8(oh), BC8(qb), s, 0, 0, 0);
    }
  }
  return s;
}

__device__ __forceinline__ void sm_pv(
    const f32x16& s,
    u32x4 va, u32x4 vb, u32x4 vc, u32x4 vd,
    f32x16& acc0, f32x16& acc1, float& l_run) {
  uint_ pw0, pw1, pw2, pw3, pw4, pw5, pw6, pw7;
  {
    float a, b;
    a = exp2f(s[0]);  b = exp2f(s[1]);  l_run += a+b; pw0 = cvtpk(a,b);
    a = exp2f(s[2]);  b = exp2f(s[3]);  l_run += a+b; pw1 = cvtpk(a,b);
    a = exp2f(s[4]);  b = exp2f(s[5]);  l_run += a+b; pw2 = cvtpk(a,b);
    a = exp2f(s[6]);  b = exp2f(s[7]);  l_run += a+b; pw3 = cvtpk(a,b);
    a = exp2f(s[8]);  b = exp2f(s[9]);  l_run += a+b; pw4 = cvtpk(a,b);
    a = exp2f(s[10]); b = exp2f(s[11]); l_run += a+b; pw5 = cvtpk(a,b);
    a = exp2f(s[12]); b = exp2f(s[13]); l_run += a+b; pw6 = cvtpk(a,b);
    a = exp2f(s[14]); b = exp2f(s[15]); l_run += a+b; pw7 = cvtpk(a,b);
  }
  auto sA = __builtin_amdgcn_permlane32_swap(pw0, pw2, false, false);
  auto sB = __builtin_amdgcn_permlane32_swap(pw1, pw3, false, false);
  auto sC = __builtin_amdgcn_permlane32_swap(pw4, pw6, false, false);
  auto sD = __builtin_amdgcn_permlane32_swap(pw5, pw7, false, false);
  u32x4 pa0, pa1;
  pa0.x = sA[0]; pa0.y = sB[0]; pa0.z = sA[1]; pa0.w = sB[1];
  pa1.x = sC[0]; pa1.y = sD[0]; pa1.z = sC[1]; pa1.w = sD[1];

  acc0 = __builtin_amdgcn_mfma_f32_32x32x16_bf16(BC8(pa0), BC8(va), acc0, 0, 0, 0);
  acc0 = __builtin_amdgcn_mfma_f32_32x32x16_bf16(BC8(pa1), BC8(vb), acc0, 0, 0, 0);
  acc1 = __builtin_amdgcn_mfma_f32_32x32x16_bf16(BC8(pa0), BC8(vc), acc1, 0, 0, 0);
  acc1 = __builtin_amdgcn_mfma_f32_32x32x16_bf16(BC8(pa1), BC8(vd), acc1, 0, 0, 0);
}

__device__ __forceinline__ bool bias_needed(int kt, int qt) {
  const int kmin = (kt * 32 >= S_) ? 1 : 0;
  const int kmax = (kt * 32 + 31 >= S_) ? 1 : 0;
  const int qmin = (qt * 32 >= S_) ? 1 : 0;
  const int qmax = (qt * 32 + 31 >= S_) ? 1 : 0;
  return (kmin <= qmax) && (qmin <= kmax);
}

__global__ __launch_bounds__(256) void attn_mfma(
    const unsigned short* __restrict__ Qmain, const unsigned short* __restrict__ QbiasPack,
    const unsigned short* __restrict__ Kpack, const unsigned short* __restrict__ Vpack,
    unsigned short* __restrict__ Abf) {
  __shared__ float red_acc[3][32][64];
  __shared__ float red_l[4][32];

  const int id0 = blockIdx.x;                  // 1176 = 8 * 147
  const int swz = (id0 & 7) * 147 + (id0 >> 3);
  const int qt = swz % 49;
  const int bh = swz / 49;

  const int lane = threadIdx.x & 63;
  const int wv = threadIdx.x >> 6;             // 0..3
  const int lo = lane & 31, hi = lane >> 5;
  const int q0 = qt * 32;

  const unsigned short* qrow = Qmain + ((size_t)bh * L_ + q0 + lo) * 64 + hi * 8;
  u32x4 qf[4];
  #pragma unroll
  for (int c = 0; c < 4; ++c) qf[c] = *(const u32x4*)(qrow + c * 16);
  const unsigned short* qbias = QbiasPack + ((size_t)bh * 49 + qt) * 3584 + lane * 8;

  const unsigned short* kbase = Kpack + (size_t)bh * 49 * 2048 + lane * 8;
  const unsigned short* vbase = Vpack + (size_t)bh * 49 * 2048 + lane * 8;

  f32x16 acc0 = {}, acc1 = {};
  float l_run = 0.f;
  const int nt = (49 - wv + 3) >> 2;           // wave wv: tiles kt = wv + 4*j

  #define KT(j) (wv + 4 * (j))
  #define QK(j, K0, K1, K2, K3) \
    (bias_needed(KT(j), qt) \
      ? qk_tile<true>(KT(j), lo, hi, qf, qbias, K0, K1, K2, K3) \
      : qk_tile<false>(KT(j), lo, hi, qf, qbias, K0, K1, K2, K3))

  u32x4 kA0, kA1, kA2, kA3, kB0, kB1, kB2, kB3;
  u32x4 va, vb, vc, vd;

  load_k(kbase, KT(0), kA0, kA1, kA2, kA3);
  load_k(kbase, KT(1), kB0, kB1, kB2, kB3);
  f32x16 s_prev = QK(0, kA0, kA1, kA2, kA3);

  int j = 1;
  for (; j + 1 < nt; j += 2) {
    load_v(vbase, KT(j - 1), va, vb, vc, vd);
    f32x16 s_cur = QK(j, kB0, kB1, kB2, kB3);
    load_k(kbase, KT(j + 1), kA0, kA1, kA2, kA3);
    sm_pv(s_prev, va, vb, vc, vd, acc0, acc1, l_run);
    s_prev = s_cur;
    load_v(vbase, KT(j), va, vb, vc, vd);
    f32x16 s_cur2 = QK(j + 1, kA0, kA1, kA2, kA3);
    const int pf = (j + 2 < nt) ? j + 2 : nt - 1;
    load_k(kbase, KT(pf), kB0, kB1, kB2, kB3);
    sm_pv(s_prev, va, vb, vc, vd, acc0, acc1, l_run);
    s_prev = s_cur2;
  }
  if (j < nt) {
    load_v(vbase, KT(j - 1), va, vb, vc, vd);
    f32x16 s_cur = QK(j, kB0, kB1, kB2, kB3);
    sm_pv(s_prev, va, vb, vc, vd, acc0, acc1, l_run);
    s_prev = s_cur;
  }
  load_v(vbase, KT(nt - 1), va, vb, vc, vd);
  sm_pv(s_prev, va, vb, vc, vd, acc0, acc1, l_run);
  #undef QK
  #undef KT

  l_run += __shfl_xor(l_run, 32);

  if (hi == 0) red_l[wv][lo] = l_run;
  if (wv >= 1) {
    #pragma unroll
    for (int r = 0; r < 16; ++r) {
      const int row = (r & 3) + 8*(r >> 2) + 4*hi;
      red_acc[wv-1][row][lo]      = acc0[r];
      red_acc[wv-1][row][32 + lo] = acc1[r];
    }
  }
  __syncthreads();
  if (wv == 0) {
    const int b = bh / NH_, h = bh % NH_;
    #pragma unroll
    for (int r = 0; r < 16; ++r) {
      const int row = (r & 3) + 8*(r >> 2) + 4*hi;
      const float inv = 1.0f / (red_l[0][row] + red_l[1][row] +
                                red_l[2][row] + red_l[3][row]);
      const float o0 = (acc0[r] + red_acc[0][row][lo] +
                        red_acc[1][row][lo] + red_acc[2][row][lo]) * inv;
      const float o1 = (acc1[r] + red_acc[0][row][32+lo] +
                        red_acc[1][row][32+lo] + red_acc[2][row][32+lo]) * inv;
      const size_t qoff = ((size_t)bh * L_ + q0 + row) * 64 + lo;
      const size_t ooff = ((size_t)(b * L_ + q0 + row)) * C_ + h * 64 + lo;
      Abf[ooff]      = f2bf(o0 + bf2f(Qmain[qoff]));
      Abf[ooff + 32] = f2bf(o1 + bf2f(Qmain[qoff + 32]));
    }
  }
}

// ---------------------------------------------------------------------------
extern "C" void kernel_launch(void* const* d_in, const int* in_sizes, int n_in,
                              void* d_out, int out_size, void* d_ws, size_t ws_size,
                              hipStream_t stream) {
  const float* x         = (const float*)d_in[0];
  const float* qkv_w     = (const float*)d_in[1];
  const float* out_w     = (const float*)d_in[2];
  const float* out_b     = (const float*)d_in[3];
  const float* q_pool_w  = (const float*)d_in[4];
  const float* k_pool_w  = (const float*)d_in[5];
  const float* v_pool_w  = (const float*)d_in[6];
  const float* q_ln_g    = (const float*)d_in[7];
  const float* q_ln_b    = (const float*)d_in[8];
  const float* k_ln_g    = (const float*)d_in[9];
  const float* k_ln_b    = (const float*)d_in[10];
  const float* v_ln_g    = (const float*)d_in[11];
  const float* v_ln_b    = (const float*)d_in[12];
  const float* rel_pos_h = (const float*)d_in[13];
  const float* rel_pos_w = (const float*)d_in[14];

  float* R = (float*)d_ws;
  const size_t NQ = (size_t)B_ * NH_ * L_ * HD_;   // 2,408,448 f32 slots
  // A [0,NQ): q_raw -> Abf          B [NQ,2NQ): k_raw -> Vpack
  // C [2NQ,3NQ): v_raw
  // D [3NQ, +1228800): Xbf -> Qmain (1,204,224)
  // E: Kpack (1,204,224)            F: Wbf -> Vtmp (1,204,224)
  // G: Wobf (294,912)               H: QbiasPack (2,107,392)  I: Rhb/Rwb
  float* q_raw = R;
  unsigned short* Abf = (unsigned short*)R;
  float* k_raw = R + NQ;
  unsigned short* Vpack = (unsigned short*)(R + NQ);
  float* v_raw = R + 2*NQ;
  const size_t D_off = 3*NQ;
  unsigned short* Xbf   = (unsigned short*)(R + D_off);
  unsigned short* Qmain = (unsigned short*)(R + D_off);
  const size_t E_off = D_off + 1228800;
  unsigned short* Kpack = (unsigned short*)(R + E_off);
  const size_t F_off = E_off + 1204224;
  unsigned short* Wbf  = (unsigned short*)(R + F_off);
  unsigned short* Vtmp = (unsigned short*)(R + F_off);
  const size_t G_off = F_off + 1204224;
  unsigned short* Wobf = (unsigned short*)(R + G_off);
  const size_t H_off = G_off + 294912;
  unsigned short* QbiasPack = (unsigned short*)(R + H_off);
  const size_t I_off = H_off + 2107392;
  unsigned short* Rhb = (unsigned short*)(R + I_off);
  unsigned short* Rwb = (unsigned short*)(R + I_off + 2048);

  cvt_all<<<2328, 256, 0, stream>>>(x, 3136*768, Xbf,
                                    qkv_w, 2304*768, Wbf,
                                    out_w, 768*768, Wobf);
  cvt_rel<<<16, 256, 0, stream>>>(rel_pos_h, rel_pos_w, Rhb, Rwb);
  qkv_gemm_mfma<<<dim3(18, 25), 256, 0, stream>>>(Xbf, Wbf, q_raw, k_raw, v_raw);
  pool_ln_fused<<<dim3(9408, 3), 256, 0, stream>>>(
      q_raw, k_raw, v_raw, q_pool_w, k_pool_w, v_pool_w,
      q_ln_g, q_ln_b, k_ln_g, k_ln_b, v_ln_g, v_ln_b, Qmain, Kpack, Vtmp);
  vpack_kernel<<<dim3(49, 24), 256, 0, stream>>>(Vtmp, Vpack);
  relpos_mfma<<<dim3(49, 48), 64, 0, stream>>>(Qmain, Rhb, Rwb, QbiasPack);
  attn_mfma<<<1176, 256, 0, stream>>>(Qmain, QbiasPack, Kpack, Vpack, Abf);
  proj_gemm_mfma<<<dim3(6, 25), 256, 0, stream>>>(Abf, Wobf, out_b, (float*)d_out);
}

// Round 13
// 139.716 us; speedup vs baseline: 2.0773x; 1.2096x over previous
//
#include <hip/hip_runtime.h>
#include <math.h>

#define B_ 2
#define T_ 2
#define H_ 28
#define W_ 28
#define S_ (H_*W_)      /* 784  */
#define L_ (T_*S_)      /* 1568 */
#define C_ 768
#define NH_ 12
#define HD_ 64
#define LN_EPS 1e-5f
#define LOG2E 1.4426950408889634f
#define SCALE_K (0.125f * LOG2E)   /* hd^-0.5 * log2e folded into K' */

typedef unsigned int uint_;
typedef unsigned int u32x4 __attribute__((ext_vector_type(4)));
typedef __bf16 bf16x8 __attribute__((ext_vector_type(8)));
typedef float f32x4 __attribute__((ext_vector_type(4)));
typedef float f32x16 __attribute__((ext_vector_type(16)));

#define BC8(x) __builtin_bit_cast(bf16x8, (x))

__device__ __forceinline__ unsigned short f2bf(float f) {
  uint_ u = __builtin_bit_cast(uint_, f);
  u += 0x7FFFu + ((u >> 16) & 1u);
  return (unsigned short)(u >> 16);
}
__device__ __forceinline__ float bf2f(unsigned short h) {
  return __builtin_bit_cast(float, ((uint_)h) << 16);
}
__device__ __forceinline__ uint_ cvtpk(float a, float b) {
  uint_ r;
  asm("v_cvt_pk_bf16_f32 %0, %1, %2" : "=v"(r) : "v"(a), "v"(b));
  return r;
}
__device__ __forceinline__ void gload16(const void* g, void* l) {
  __builtin_amdgcn_global_load_lds(
      (const __attribute__((address_space(1))) unsigned int*)g,
      (__attribute__((address_space(3))) unsigned int*)l, 16, 0, 0);
}

// ---------------------------------------------------------------------------
// Fused f32 -> bf16 convert for x / qkv_w / out_w (range-dispatched)
// ---------------------------------------------------------------------------
__global__ __launch_bounds__(256) void cvt_all(
    const float* __restrict__ s0, int n0, unsigned short* __restrict__ d0,
    const float* __restrict__ s1, int n1, unsigned short* __restrict__ d1,
    const float* __restrict__ s2, int n2, unsigned short* __restrict__ d2) {
  int i = (blockIdx.x * 256 + threadIdx.x) * 8;
  const float* s; unsigned short* d;
  if (i < n0) { s = s0; d = d0; }
  else if (i < n0 + n1) { i -= n0; s = s1; d = d1; }
  else { i -= n0 + n1; if (i >= n2) return; s = s2; d = d2; }
  float4 a = *(const float4*)(s + i);
  float4 b = *(const float4*)(s + i + 4);
  u32x4 o;
  o.x = cvtpk(a.x, a.y); o.y = cvtpk(a.z, a.w);
  o.z = cvtpk(b.x, b.y); o.w = cvtpk(b.z, b.w);
  *(u32x4*)(d + i) = o;
}

// ---------------------------------------------------------------------------
// rel-pos tables -> bf16, LOG2E folded, padded to [64][64]
// ---------------------------------------------------------------------------
__global__ __launch_bounds__(256) void cvt_rel(
    const float* __restrict__ rph, const float* __restrict__ rpw,
    unsigned short* __restrict__ Rhb, unsigned short* __restrict__ Rwb) {
  const int i = blockIdx.x * 256 + threadIdx.x;   // 0..4095
  if (i >= 4096) return;
  const int j = i >> 6;
  const unsigned short vh = (j < 2*H_-1) ? f2bf(rph[i] * LOG2E) : 0;
  const unsigned short vw = (j < 2*W_-1) ? f2bf(rpw[i] * LOG2E) : 0;
  Rhb[i] = vh;
  Rwb[i] = vw;
}

// ---------------------------------------------------------------------------
// bf16 MFMA GEMM core: C = A * B^T, 128x128 tile, BK=32, 4 waves
// ---------------------------------------------------------------------------
__device__ __forceinline__ void gemm_core(
    const unsigned short* __restrict__ A, const unsigned short* __restrict__ Bm,
    int K, int m0, int n0, f32x4 (&acc)[4][4]) {
  __shared__ __align__(16) unsigned short As[128 * 32];
  __shared__ __align__(16) unsigned short Bs[128 * 32];
  const int tid = threadIdx.x;
  const int lane = tid & 63;
  const int wv = tid >> 6;
  const int wm = wv >> 1, wn = wv & 1;
  const int srow = tid >> 2, scol = (tid & 3) * 8;
  const int fr = lane & 15, fk = (lane >> 4) * 8;
  const unsigned short* ag = A + (size_t)(m0 + srow) * K + scol;
  const unsigned short* bg = Bm + (size_t)(n0 + srow) * K + scol;
  unsigned short* asd = As + tid * 8;
  unsigned short* bsd = Bs + tid * 8;
  const int arow = wm * 64 + fr;
  const int brow = wn * 64 + fr;
  for (int k0 = 0; k0 < K; k0 += 32) {
    __syncthreads();
    gload16(ag + k0, asd);
    gload16(ag + (size_t)64 * K + k0, asd + 2048);
    gload16(bg + k0, bsd);
    gload16(bg + (size_t)64 * K + k0, bsd + 2048);
    __syncthreads();
    bf16x8 af[4], bfr[4];
    #pragma unroll
    for (int m = 0; m < 4; ++m)
      af[m] = *(const bf16x8*)(As + (arow + m * 16) * 32 + fk);
    #pragma unroll
    for (int n = 0; n < 4; ++n)
      bfr[n] = *(const bf16x8*)(Bs + (brow + n * 16) * 32 + fk);
    #pragma unroll
    for (int m = 0; m < 4; ++m)
      #pragma unroll
      for (int n = 0; n < 4; ++n)
        acc[m][n] = __builtin_amdgcn_mfma_f32_16x16x32_bf16(af[m], bfr[n], acc[m][n], 0, 0, 0);
  }
}

// ---------------------------------------------------------------------------
// QKV GEMM: Xbf[3200][768] * Wbf[2304][768]^T -> scatter f32 q/k/v [B,NH,L,HD]
// ---------------------------------------------------------------------------
__global__ __launch_bounds__(256) void qkv_gemm_mfma(
    const unsigned short* __restrict__ Xbf, const unsigned short* __restrict__ Wbf,
    float* __restrict__ q_raw, float* __restrict__ k_raw, float* __restrict__ v_raw) {
  f32x4 acc[4][4] = {};
  const int m0 = blockIdx.y * 128;
  const int n0 = blockIdx.x * 128;
  gemm_core(Xbf, Wbf, C_, m0, n0, acc);
  const int lane = threadIdx.x & 63;
  const int wv = threadIdx.x >> 6;
  const int wm = wv >> 1, wn = wv & 1;
  const int fr = lane & 15, fj = (lane >> 4) * 4;
  #pragma unroll
  for (int n = 0; n < 4; ++n) {
    const int gn = n0 + wn * 64 + n * 16 + fr;
    const int which = (gn >= 2 * C_) ? 2 : ((gn >= C_) ? 1 : 0);
    const int rem = gn - which * C_;
    const int h = rem >> 6, d = rem & 63;
    float* dst = (which == 0) ? q_raw : ((which == 1) ? k_raw : v_raw);
    #pragma unroll
    for (int m = 0; m < 4; ++m) {
      #pragma unroll
      for (int j = 0; j < 4; ++j) {
        const int gm = m0 + wm * 64 + m * 16 + fj + j;
        if (gm < B_ * L_) {
          const int b = (gm >= L_) ? 1 : 0;
          const int l = gm - b * L_;
          dst[(((size_t)b * NH_ + h) * L_ + l) * HD_ + d] = acc[m][n][j];
        }
      }
    }
  }
}

// ---------------------------------------------------------------------------
// Proj GEMM: Abf[3200][768] * Wobf[768][768]^T + bo -> d_out f32
// ---------------------------------------------------------------------------
__global__ __launch_bounds__(256) void proj_gemm_mfma(
    const unsigned short* __restrict__ Abf, const unsigned short* __restrict__ Wobf,
    const float* __restrict__ bo, float* __restrict__ out) {
  f32x4 acc[4][4] = {};
  const int m0 = blockIdx.y * 128;
  const int n0 = blockIdx.x * 128;
  gemm_core(Abf, Wobf, C_, m0, n0, acc);
  const int lane = threadIdx.x & 63;
  const int wv = threadIdx.x >> 6;
  const int wm = wv >> 1, wn = wv & 1;
  const int fr = lane & 15, fj = (lane >> 4) * 4;
  #pragma unroll
  for (int n = 0; n < 4; ++n) {
    const int gn = n0 + wn * 64 + n * 16 + fr;
    const float bias = bo[gn];
    #pragma unroll
    for (int m = 0; m < 4; ++m) {
      #pragma unroll
      for (int j = 0; j < 4; ++j) {
        const int gm = m0 + wm * 64 + m * 16 + fj + j;
        if (gm < B_ * L_) out[(size_t)gm * C_ + gn] = acc[m][n][j] + bias;
      }
    }
  }
}

// ---------------------------------------------------------------------------
// Fused depthwise 3x3 conv + LayerNorm(64), TWO rows per wave (y, y+1 share x
// since W is even; stencils overlap 6/9 taps). blockIdx.y selects q/k/v.
// ---------------------------------------------------------------------------
__global__ __launch_bounds__(256) void pool_ln_fused(
    const float* __restrict__ q_raw, const float* __restrict__ k_raw,
    const float* __restrict__ v_raw,
    const float* __restrict__ qw, const float* __restrict__ kw,
    const float* __restrict__ vw,
    const float* __restrict__ qg, const float* __restrict__ qb2,
    const float* __restrict__ kg, const float* __restrict__ kb2,
    const float* __restrict__ vg, const float* __restrict__ vb2,
    unsigned short* __restrict__ Qmain, unsigned short* __restrict__ Kpack,
    unsigned short* __restrict__ Vtmp) {
  const int which = blockIdx.y;
  const float* in = (which == 0) ? q_raw : (which == 1) ? k_raw : v_raw;
  const float* w  = (which == 0) ? qw : (which == 1) ? kw : vw;
  const float* g  = (which == 0) ? qg : (which == 1) ? kg : vg;
  const float* bb = (which == 0) ? qb2 : (which == 1) ? kb2 : vb2;
  const float scale = (which == 1) ? SCALE_K : 1.f;

  const int pair = blockIdx.x * 4 + (threadIdx.x >> 6);  // 0..18815
  const int d = threadIdx.x & 63;
  const int row0 = pair * 2;
  const int bh = row0 / L_;
  const int l0  = row0 % L_;           // even
  const int t  = l0 / S_;
  const int sq = l0 % S_;
  const int x = sq / W_, y = sq % W_;  // y even
  const float* base = in + ((size_t)bh * L_ + t * S_) * HD_ + d;

  float acc0 = 0.f, acc1 = 0.f;
  #pragma unroll
  for (int dx = 0; dx < 3; ++dx) {
    const int xx = x + dx - 1;
    if (xx < 0 || xx >= H_) continue;
    const float* rb = base + (size_t)xx * W_ * HD_;
    const float w0 = w[(dx*3 + 0) * HD_ + d];
    const float w1 = w[(dx*3 + 1) * HD_ + d];
    const float w2 = w[(dx*3 + 2) * HD_ + d];
    const float cm1 = (y > 0)      ? rb[(y-1) * HD_] : 0.f;
    const float c0  = rb[y * HD_];
    const float cp1 = rb[(y+1) * HD_];
    const float cp2 = (y+2 < W_)   ? rb[(y+2) * HD_] : 0.f;
    acc0 += cm1*w0 + c0*w1 + cp1*w2;
    acc1 += c0*w0 + cp1*w1 + cp2*w2;
  }
  // dual LayerNorm: 4 interleaved shuffle chains
  float a1 = acc0, a2 = acc0*acc0, b1 = acc1, b2 = acc1*acc1;
  #pragma unroll
  for (int off = 32; off; off >>= 1) {
    a1 += __shfl_xor(a1, off);
    a2 += __shfl_xor(a2, off);
    b1 += __shfl_xor(b1, off);
    b2 += __shfl_xor(b2, off);
  }
  const float mu0 = a1 * (1.f / 64.f);
  const float var0 = a2 * (1.f / 64.f) - mu0 * mu0;
  const float mu1 = b1 * (1.f / 64.f);
  const float var1 = b2 * (1.f / 64.f) - mu1 * mu1;
  const float gd = g[d], bd = bb[d];
  const unsigned short v0 = f2bf(((acc0 - mu0) * rsqrtf(var0 + LN_EPS) * gd + bd) * scale);
  const unsigned short v1 = f2bf(((acc1 - mu1) * rsqrtf(var1 + LN_EPS) * gd + bd) * scale);

  if (which == 1) {
    // Kpack[(bh*49+kt)*4 + c][lane2][e]; rows l0, l0+1 -> lane2, lane2+1
    const int kt = l0 >> 5;
    const int c = d >> 4;
    const int lane2 = (((d >> 3) & 1) << 5) | (l0 & 31);
    unsigned short* kp = Kpack + ((((size_t)bh * 49 + kt) * 4 + c) * 64 + lane2) * 8 + (d & 7);
    kp[0] = v0;
    kp[8] = v1;
  } else if (which == 0) {
    Qmain[(size_t)row0 * 64 + d]       = v0;
    Qmain[(size_t)(row0 + 1) * 64 + d] = v1;
  } else {
    Vtmp[(size_t)row0 * 64 + d]       = v0;
    Vtmp[(size_t)(row0 + 1) * 64 + d] = v1;
  }
}

// ---------------------------------------------------------------------------
// V pack: Vtmp [bh][L][64] -> Vpack fragment-order (LDS transpose per 32-tile)
// ---------------------------------------------------------------------------
__global__ __launch_bounds__(256) void vpack_kernel(
    const unsigned short* __restrict__ Vtmp, unsigned short* __restrict__ Vpack) {
  __shared__ unsigned short tile[32][72];
  const int bh = blockIdx.y;
  const int kt = blockIdx.x;
  const int l0 = kt * 32;
  const int t = threadIdx.x;
  {
    const int r = t >> 3, c8 = (t & 7) * 8;
    u32x4 v = *(const u32x4*)(Vtmp + ((size_t)bh * L_ + l0 + r) * 64 + c8);
    *(u32x4*)&tile[r][c8] = v;
  }
  __syncthreads();
  const int d = t >> 2, gq = t & 3;
  unsigned short o[8];
  #pragma unroll
  for (int i = 0; i < 8; ++i) o[i] = tile[gq*8 + i][d];
  u32x4 ov;
  ov.x = (uint_)o[0] | ((uint_)o[1] << 16);
  ov.y = (uint_)o[2] | ((uint_)o[3] << 16);
  ov.z = (uint_)o[4] | ((uint_)o[5] << 16);
  ov.w = (uint_)o[6] | ((uint_)o[7] << 16);
  const int c = ((d >> 5) << 1) | (gq >> 1);
  const int lane2 = ((gq & 1) << 5) | (d & 31);
  *(u32x4*)(Vpack + ((((size_t)bh * 49 + kt) * 4 + c) * 64 + lane2) * 8) = ov;
}

// ---------------------------------------------------------------------------
// rel-pos via MFMA: P_h = Q*Rhb^T, P_w = Q*Rwb^T; bias rows are contiguous
// reversed slices of P. Writes QbiasPack fragment-order (incl. zero T-block).
// ---------------------------------------------------------------------------
__global__ __launch_bounds__(64) void relpos_mfma(
    const unsigned short* __restrict__ Qmain,
    const unsigned short* __restrict__ Rhb,
    const unsigned short* __restrict__ Rwb,
    unsigned short* __restrict__ QbiasPack) {
  __shared__ float P[16][128];
  const int qt16 = blockIdx.x;        // 0..48
  const int bt = blockIdx.y;          // 0..47
  const int bh = bt >> 1, t = bt & 1;
  const int lane = threadIdx.x;
  const int fr = lane & 15, fk = (lane >> 4) * 8;

  const size_t rowbase = (size_t)bh * L_ + t * S_ + qt16 * 16;
  const unsigned short* arow = Qmain + (rowbase + fr) * 64 + fk;
  const bf16x8 a0 = *(const bf16x8*)(arow);
  const bf16x8 a1 = *(const bf16x8*)(arow + 32);

  f32x4 acch[4] = {}, accw[4] = {};
  #pragma unroll
  for (int n = 0; n < 4; ++n) {
    const unsigned short* bh_ = Rhb + (n * 16 + fr) * 64 + fk;
    const unsigned short* bw_ = Rwb + (n * 16 + fr) * 64 + fk;
    acch[n] = __builtin_amdgcn_mfma_f32_16x16x32_bf16(a0, *(const bf16x8*)bh_, acch[n], 0, 0, 0);
    acch[n] = __builtin_amdgcn_mfma_f32_16x16x32_bf16(a1, *(const bf16x8*)(bh_ + 32), acch[n], 0, 0, 0);
    accw[n] = __builtin_amdgcn_mfma_f32_16x16x32_bf16(a0, *(const bf16x8*)bw_, accw[n], 0, 0, 0);
    accw[n] = __builtin_amdgcn_mfma_f32_16x16x32_bf16(a1, *(const bf16x8*)(bw_ + 32), accw[n], 0, 0, 0);
  }
  #pragma unroll
  for (int n = 0; n < 4; ++n)
    #pragma unroll
    for (int j = 0; j < 4; ++j) {
      P[(lane >> 4) * 4 + j][n * 16 + fr]      = acch[n][j];
      P[(lane >> 4) * 4 + j][64 + n * 16 + fr] = accw[n][j];
    }
  __syncthreads();

  if (lane < 56) {
    const int e0 = lane * 2;          // bias element pair
    const int tb = e0 / 56;
    const int tw0 = e0 % 56;
    const int cb = e0 >> 4;
    const int hi2 = (e0 >> 3) & 1;
    const int ee = e0 & 7;
    #pragma unroll
    for (int r = 0; r < 16; ++r) {
      const int gl = t * S_ + qt16 * 16 + r;
      const int sq = qt16 * 16 + r;
      const int x = sq / W_, y = sq % W_;
      float v0 = 0.f, v1 = 0.f;
      if (tb == t) {
        if (tw0 < 28) {
          v0 = P[r][x - tw0 + 27];
          v1 = P[r][x - tw0 + 26];
        } else {
          const int k0 = tw0 - 28;
          v0 = P[r][64 + y - k0 + 27];
          v1 = P[r][64 + y - k0 + 26];
        }
      }
      const int lane2 = (hi2 << 5) | (gl & 31);
      unsigned short* dst = QbiasPack +
          ((((size_t)bh * 49 + (gl >> 5)) * 7 + cb) * 64 + lane2) * 8 + ee;
      *(uint_*)dst = cvtpk(v0, v1);
    }
  }
}

// ---------------------------------------------------------------------------
// MFMA flash attention. 256 thr (4 waves), grid 1176 (XCD-swizzled).
// All operands fragment-packed -> fully coalesced loads. Fixed-base softmax.
// ---------------------------------------------------------------------------
__device__ __forceinline__ void load_k(
    const unsigned short* kbase, int kt,
    u32x4& k0, u32x4& k1, u32x4& k2, u32x4& k3) {
  const unsigned short* kp = kbase + (size_t)kt * 2048;
  k0 = *(const u32x4*)(kp);
  k1 = *(const u32x4*)(kp + 512);
  k2 = *(const u32x4*)(kp + 1024);
  k3 = *(const u32x4*)(kp + 1536);
}

__device__ __forceinline__ void load_v(
    const unsigned short* vbase, int kt,
    u32x4& va, u32x4& vb, u32x4& vc, u32x4& vd) {
  const unsigned short* vp = vbase + (size_t)kt * 2048;
  va = *(const u32x4*)(vp);
  vb = *(const u32x4*)(vp + 512);
  vc = *(const u32x4*)(vp + 1024);
  vd = *(const u32x4*)(vp + 1536);
}

template<bool BIAS>
__device__ __forceinline__ f32x16 qk_tile(
    int kt, int lo, int hi, const u32x4 (&qf)[4],
    const unsigned short* __restrict__ qbias,
    u32x4 k0, u32x4 k1, u32x4 k2, u32x4 k3) {
  f32x16 s = {};
  s = __builtin_amdgcn_mfma_f32_32x32x16_bf16(BC8(k0), BC8(qf[0]), s, 0, 0, 0);
  s = __builtin_amdgcn_mfma_f32_32x32x16_bf16(BC8(k1), BC8(qf[1]), s, 0, 0, 0);
  s = __builtin_amdgcn_mfma_f32_32x32x16_bf16(BC8(k2), BC8(qf[2]), s, 0, 0, 0);
  s = __builtin_amdgcn_mfma_f32_32x32x16_bf16(BC8(k3), BC8(qf[3]), s, 0, 0, 0);
  if (BIAS) {
    const int kr = kt * 32 + lo;
    const int t = (kr >= S_) ? 1 : 0;
    const int sk = kr - t * S_;
    const int x = sk / W_, y = sk - x * W_;
    const int p1 = t*56 + x;
    const int p2 = t*56 + 28 + y;
    const uint_ v1 = 0x3F80u << ((p1 & 1) << 4);
    const uint_ v2 = 0x3F80u << ((p2 & 1) << 4);
    const int g1 = p1 >> 3, g2 = p2 >> 3;
    const int w1 = (p1 >> 1) & 3, w2 = (p2 >> 1) & 3;
    #pragma unroll
    for (int c = 0; c < 7; ++c) {
      const int gg = 2*c + hi;
      u32x4 oh;
      oh.x = ((g1 == gg && w1 == 0) ? v1 : 0u) | ((g2 == gg && w2 == 0) ? v2 : 0u);
      oh.y = ((g1 == gg && w1 == 1) ? v1 : 0u) | ((g2 == gg && w2 == 1) ? v2 : 0u);
      oh.z = ((g1 == gg && w1 == 2) ? v1 : 0u) | ((g2 == gg && w2 == 2) ? v2 : 0u);
      oh.w = ((g1 == gg && w1 == 3) ? v1 : 0u) | ((g2 == gg && w2 == 3) ? v2 : 0u);
      const u32x4 qb = *(const u32x4*)(qbias + c * 512);
      s = __builtin_amdgcn_mfma_f32_32x32x16_bf16(BC8(oh), BC8(qb), s, 0, 0, 0);
    }
  }
  return s;
}

__device__ __forceinline__ void sm_pv(
    const f32x16& s,
    u32x4 va, u32x4 vb, u32x4 vc, u32x4 vd,
    f32x16& acc0, f32x16& acc1, float& l_run) {
  uint_ pw0, pw1, pw2, pw3, pw4, pw5, pw6, pw7;
  {
    float a, b;
    a = exp2f(s[0]);  b = exp2f(s[1]);  l_run += a+b; pw0 = cvtpk(a,b);
    a = exp2f(s[2]);  b = exp2f(s[3]);  l_run += a+b; pw1 = cvtpk(a,b);
    a = exp2f(s[4]);  b = exp2f(s[5]);  l_run += a+b; pw2 = cvtpk(a,b);
    a = exp2f(s[6]);  b = exp2f(s[7]);  l_run += a+b; pw3 = cvtpk(a,b);
    a = exp2f(s[8]);  b = exp2f(s[9]);  l_run += a+b; pw4 = cvtpk(a,b);
    a = exp2f(s[10]); b = exp2f(s[11]); l_run += a+b; pw5 = cvtpk(a,b);
    a = exp2f(s[12]); b = exp2f(s[13]); l_run += a+b; pw6 = cvtpk(a,b);
    a = exp2f(s[14]); b = exp2f(s[15]); l_run += a+b; pw7 = cvtpk(a,b);
  }
  auto sA = __builtin_amdgcn_permlane32_swap(pw0, pw2, false, false);
  auto sB = __builtin_amdgcn_permlane32_swap(pw1, pw3, false, false);
  auto sC = __builtin_amdgcn_permlane32_swap(pw4, pw6, false, false);
  auto sD = __builtin_amdgcn_permlane32_swap(pw5, pw7, false, false);
  u32x4 pa0, pa1;
  pa0.x = sA[0]; pa0.y = sB[0]; pa0.z = sA[1]; pa0.w = sB[1];
  pa1.x = sC[0]; pa1.y = sD[0]; pa1.z = sC[1]; pa1.w = sD[1];

  acc0 = __builtin_amdgcn_mfma_f32_32x32x16_bf16(BC8(pa0), BC8(va), acc0, 0, 0, 0);
  acc0 = __builtin_amdgcn_mfma_f32_32x32x16_bf16(BC8(pa1), BC8(vb), acc0, 0, 0, 0);
  acc1 = __builtin_amdgcn_mfma_f32_32x32x16_bf16(BC8(pa0), BC8(vc), acc1, 0, 0, 0);
  acc1 = __builtin_amdgcn_mfma_f32_32x32x16_bf16(BC8(pa1), BC8(vd), acc1, 0, 0, 0);
}

__device__ __forceinline__ bool bias_needed(int kt, int qt) {
  const int kmin = (kt * 32 >= S_) ? 1 : 0;
  const int kmax = (kt * 32 + 31 >= S_) ? 1 : 0;
  const int qmin = (qt * 32 >= S_) ? 1 : 0;
  const int qmax = (qt * 32 + 31 >= S_) ? 1 : 0;
  return (kmin <= qmax) && (qmin <= kmax);
}

__global__ __launch_bounds__(256) void attn_mfma(
    const unsigned short* __restrict__ Qmain, const unsigned short* __restrict__ QbiasPack,
    const unsigned short* __restrict__ Kpack, const unsigned short* __restrict__ Vpack,
    unsigned short* __restrict__ Abf) {
  __shared__ float red_acc[3][32][64];
  __shared__ float red_l[4][32];

  const int id0 = blockIdx.x;                  // 1176 = 8 * 147
  const int swz = (id0 & 7) * 147 + (id0 >> 3);
  const int qt = swz % 49;
  const int bh = swz / 49;

  const int lane = threadIdx.x & 63;
  const int wv = threadIdx.x >> 6;             // 0..3
  const int lo = lane & 31, hi = lane >> 5;
  const int q0 = qt * 32;

  const unsigned short* qrow = Qmain + ((size_t)bh * L_ + q0 + lo) * 64 + hi * 8;
  u32x4 qf[4];
  #pragma unroll
  for (int c = 0; c < 4; ++c) qf[c] = *(const u32x4*)(qrow + c * 16);
  const unsigned short* qbias = QbiasPack + ((size_t)bh * 49 + qt) * 3584 + lane * 8;

  const unsigned short* kbase = Kpack + (size_t)bh * 49 * 2048 + lane * 8;
  const unsigned short* vbase = Vpack + (size_t)bh * 49 * 2048 + lane * 8;

  f32x16 acc0 = {}, acc1 = {};
  float l_run = 0.f;
  const int nt = (49 - wv + 3) >> 2;           // wave wv: tiles kt = wv + 4*j

  #define KT(j) (wv + 4 * (j))
  #define QK(j, K0, K1, K2, K3) \
    (bias_needed(KT(j), qt) \
      ? qk_tile<true>(KT(j), lo, hi, qf, qbias, K0, K1, K2, K3) \
      : qk_tile<false>(KT(j), lo, hi, qf, qbias, K0, K1, K2, K3))

  u32x4 kA0, kA1, kA2, kA3, kB0, kB1, kB2, kB3;
  u32x4 va, vb, vc, vd;

  load_k(kbase, KT(0), kA0, kA1, kA2, kA3);
  load_k(kbase, KT(1), kB0, kB1, kB2, kB3);
  f32x16 s_prev = QK(0, kA0, kA1, kA2, kA3);

  int j = 1;
  for (; j + 1 < nt; j += 2) {
    load_v(vbase, KT(j - 1), va, vb, vc, vd);
    f32x16 s_cur = QK(j, kB0, kB1, kB2, kB3);
    load_k(kbase, KT(j + 1), kA0, kA1, kA2, kA3);
    sm_pv(s_prev, va, vb, vc, vd, acc0, acc1, l_run);
    s_prev = s_cur;
    load_v(vbase, KT(j), va, vb, vc, vd);
    f32x16 s_cur2 = QK(j + 1, kA0, kA1, kA2, kA3);
    const int pf = (j + 2 < nt) ? j + 2 : nt - 1;
    load_k(kbase, KT(pf), kB0, kB1, kB2, kB3);
    sm_pv(s_prev, va, vb, vc, vd, acc0, acc1, l_run);
    s_prev = s_cur2;
  }
  if (j < nt) {
    load_v(vbase, KT(j - 1), va, vb, vc, vd);
    f32x16 s_cur = QK(j, kB0, kB1, kB2, kB3);
    sm_pv(s_prev, va, vb, vc, vd, acc0, acc1, l_run);
    s_prev = s_cur;
  }
  load_v(vbase, KT(nt - 1), va, vb, vc, vd);
  sm_pv(s_prev, va, vb, vc, vd, acc0, acc1, l_run);
  #undef QK
  #undef KT

  l_run += __shfl_xor(l_run, 32);

  if (hi == 0) red_l[wv][lo] = l_run;
  if (wv >= 1) {
    #pragma unroll
    for (int r = 0; r < 16; ++r) {
      const int row = (r & 3) + 8*(r >> 2) + 4*hi;
      red_acc[wv-1][row][lo]      = acc0[r];
      red_acc[wv-1][row][32 + lo] = acc1[r];
    }
  }
  __syncthreads();
  if (wv == 0) {
    const int b = bh / NH_, h = bh % NH_;
    #pragma unroll
    for (int r = 0; r < 16; ++r) {
      const int row = (r & 3) + 8*(r >> 2) + 4*hi;
      const float inv = 1.0f / (red_l[0][row] + red_l[1][row] +
                                red_l[2][row] + red_l[3][row]);
      const float o0 = (acc0[r] + red_acc[0][row][lo] +
                        red_acc[1][row][lo] + red_acc[2][row][lo]) * inv;
      const float o1 = (acc1[r] + red_acc[0][row][32+lo] +
                        red_acc[1][row][32+lo] + red_acc[2][row][32+lo]) * inv;
      const size_t qoff = ((size_t)bh * L_ + q0 + row) * 64 + lo;
      const size_t ooff = ((size_t)(b * L_ + q0 + row)) * C_ + h * 64 + lo;
      Abf[ooff]      = f2bf(o0 + bf2f(Qmain[qoff]));
      Abf[ooff + 32] = f2bf(o1 + bf2f(Qmain[qoff + 32]));
    }
  }
}

// ---------------------------------------------------------------------------
extern "C" void kernel_launch(void* const* d_in, const int* in_sizes, int n_in,
                              void* d_out, int out_size, void* d_ws, size_t ws_size,
                              hipStream_t stream) {
  const float* x         = (const float*)d_in[0];
  const float* qkv_w     = (const float*)d_in[1];
  const float* out_w     = (const float*)d_in[2];
  const float* out_b     = (const float*)d_in[3];
  const float* q_pool_w  = (const float*)d_in[4];
  const float* k_pool_w  = (const float*)d_in[5];
  const float* v_pool_w  = (const float*)d_in[6];
  const float* q_ln_g    = (const float*)d_in[7];
  const float* q_ln_b    = (const float*)d_in[8];
  const float* k_ln_g    = (const float*)d_in[9];
  const float* k_ln_b    = (const float*)d_in[10];
  const float* v_ln_g    = (const float*)d_in[11];
  const float* v_ln_b    = (const float*)d_in[12];
  const float* rel_pos_h = (const float*)d_in[13];
  const float* rel_pos_w = (const float*)d_in[14];

  float* R = (float*)d_ws;
  const size_t NQ = (size_t)B_ * NH_ * L_ * HD_;   // 2,408,448 f32 slots
  float* q_raw = R;
  unsigned short* Abf = (unsigned short*)R;
  float* k_raw = R + NQ;
  unsigned short* Vpack = (unsigned short*)(R + NQ);
  float* v_raw = R + 2*NQ;
  const size_t D_off = 3*NQ;
  unsigned short* Xbf   = (unsigned short*)(R + D_off);
  unsigned short* Qmain = (unsigned short*)(R + D_off);
  const size_t E_off = D_off + 1228800;
  unsigned short* Kpack = (unsigned short*)(R + E_off);
  const size_t F_off = E_off + 1204224;
  unsigned short* Wbf  = (unsigned short*)(R + F_off);
  unsigned short* Vtmp = (unsigned short*)(R + F_off);
  const size_t G_off = F_off + 1204224;
  unsigned short* Wobf = (unsigned short*)(R + G_off);
  const size_t H_off = G_off + 294912;
  unsigned short* QbiasPack = (unsigned short*)(R + H_off);
  const size_t I_off = H_off + 2107392;
  unsigned short* Rhb = (unsigned short*)(R + I_off);
  unsigned short* Rwb = (unsigned short*)(R + I_off + 2048);

  cvt_all<<<2328, 256, 0, stream>>>(x, 3136*768, Xbf,
                                    qkv_w, 2304*768, Wbf,
                                    out_w, 768*768, Wobf);
  cvt_rel<<<16, 256, 0, stream>>>(rel_pos_h, rel_pos_w, Rhb, Rwb);
  qkv_gemm_mfma<<<dim3(18, 25), 256, 0, stream>>>(Xbf, Wbf, q_raw, k_raw, v_raw);
  pool_ln_fused<<<dim3(4704, 3), 256, 0, stream>>>(
      q_raw, k_raw, v_raw, q_pool_w, k_pool_w, v_pool_w,
      q_ln_g, q_ln_b, k_ln_g, k_ln_b, v_ln_g, v_ln_b, Qmain, Kpack, Vtmp);
  vpack_kernel<<<dim3(49, 24), 256, 0, stream>>>(Vtmp, Vpack);
  relpos_mfma<<<dim3(49, 48), 64, 0, stream>>>(Qmain, Rhb, Rwb, QbiasPack);
  attn_mfma<<<1176, 256, 0, stream>>>(Qmain, QbiasPack, Kpack, Vpack, Abf);
  proj_gemm_mfma<<<dim3(6, 25), 256, 0, stream>>>(Abf, Wobf, out_b, (float*)d_out);
}